// Round 2
// baseline (3381.603 us; speedup 1.0000x reference)
//
#include <hip/hip_runtime.h>
#include <hip/hip_bf16.h>

#define N_NODES 6144
#define MASK_WORDS 192  // 6144/32

// ---------------------------------------------------------------- bitpack
// adj [N][N] int32 -> bits [N][192] u32 (bit j of word j>>5 = adj>0)
__global__ __launch_bounds__(256) void bitpack_kernel(const int* __restrict__ adj,
                                                      unsigned int* __restrict__ bits) {
  int row = blockIdx.x;
  int wave = threadIdx.x >> 6, lane = threadIdx.x & 63;
  const int* p = adj + (long)row * N_NODES;
  for (int base = wave * 64; base < N_NODES; base += 256) {
    unsigned long long m = __ballot(p[base + lane] > 0);
    if (lane == 0) {
      bits[row * MASK_WORDS + (base >> 5)] = (unsigned int)m;
      bits[row * MASK_WORDS + (base >> 5) + 1] = (unsigned int)(m >> 32);
    }
  }
}

// ---------------------------------------------------------------- W repack
// W [H][Fin][Fp] -> B [Fin][H*Fp]
__global__ __launch_bounds__(256) void repack_W_kernel(const float* __restrict__ W,
                                                       float* __restrict__ B,
                                                       int H, int Fin, int Fp) {
  int idx = blockIdx.x * blockDim.x + threadIdx.x;
  int total = H * Fin * Fp;
  if (idx >= total) return;
  int h = idx / (Fin * Fp);
  int rem = idx - h * (Fin * Fp);
  int k = rem / Fp, c = rem - k * Fp;
  B[k * (H * Fp) + h * Fp + c] = W[idx];
}

// ---------------------------------------------------------------- GEMM
// C[M,Nc] = A[M,K] @ B[K,Nc]  (+bias, act: 0 none, 1 relu). M multiple of 64.
__global__ __launch_bounds__(256) void gemm_kernel(const float* __restrict__ A,
                                                   const float* __restrict__ B,
                                                   float* __restrict__ C,
                                                   int K, int Nc,
                                                   const float* __restrict__ bias,
                                                   int act) {
  __shared__ float As[16][68];
  __shared__ float Bs[16][68];
  int tx = threadIdx.x & 15, ty = threadIdx.x >> 4;
  int m0 = blockIdx.y * 64, n0 = blockIdx.x * 64;
  float acc[4][4] = {};
  for (int k0 = 0; k0 < K; k0 += 16) {
    for (int t = threadIdx.x; t < 1024; t += 256) {
      int k = t & 15, m = t >> 4;
      As[k][m] = A[(long)(m0 + m) * K + k0 + k];
    }
    for (int t = threadIdx.x; t < 1024; t += 256) {
      int k = t >> 6, n = t & 63;
      int col = n0 + n;
      Bs[k][n] = (col < Nc) ? B[(long)(k0 + k) * Nc + col] : 0.0f;
    }
    __syncthreads();
#pragma unroll
    for (int k = 0; k < 16; ++k) {
      float4 a = *reinterpret_cast<const float4*>(&As[k][ty * 4]);
      float4 b = *reinterpret_cast<const float4*>(&Bs[k][tx * 4]);
      float av[4] = {a.x, a.y, a.z, a.w};
      float bv[4] = {b.x, b.y, b.z, b.w};
#pragma unroll
      for (int i = 0; i < 4; ++i)
#pragma unroll
        for (int j = 0; j < 4; ++j) acc[i][j] += av[i] * bv[j];
    }
    __syncthreads();
  }
  for (int i = 0; i < 4; ++i) {
    int m = m0 + ty * 4 + i;
    for (int j = 0; j < 4; ++j) {
      int n = n0 + tx * 4 + j;
      if (n < Nc) {
        float v = acc[i][j];
        if (bias) v += bias[n];
        if (act == 1) v = fmaxf(v, 0.0f);
        C[(long)m * Nc + n] = v;
      }
    }
  }
}

// ---------------------------------------------------------------- f1/f2
// f1[h*N+n] = dot(Wh[n, h*Fp : h*Fp+Fp], a[h][0:Fp]); f2 with a[h][Fp:2Fp]
// grid: H*N/4 blocks of 256 (4 waves, one (h,n) per wave)
__global__ __launch_bounds__(256) void f1f2_kernel(const float* __restrict__ Wh,
                                                   const float* __restrict__ a,
                                                   float* __restrict__ f1,
                                                   float* __restrict__ f2,
                                                   int H, int Fp) {
  int g = blockIdx.x * 4 + (threadIdx.x >> 6);
  int lane = threadIdx.x & 63;
  if (g >= H * N_NODES) return;
  int h = g / N_NODES, n = g - h * N_NODES;
  int Ftot = H * Fp;
  const float* row = Wh + (long)n * Ftot + h * Fp;
  const float* av1 = a + h * 2 * Fp;
  const float* av2 = av1 + Fp;
  float s1 = 0.f, s2 = 0.f;
  for (int c = lane; c < Fp; c += 64) {
    float w = row[c];
    s1 += w * av1[c];
    s2 += w * av2[c];
  }
  for (int off = 32; off > 0; off >>= 1) {
    s1 += __shfl_down(s1, off);
    s2 += __shfl_down(s2, off);
  }
  if (lane == 0) { f1[g] = s1; f2[g] = s2; }
}

// ---------------------------------------------------------------- softmax stats
// per (h,i): m = max_j masked LR(f1+f2); linv = 1/sum exp(e-m)
__global__ __launch_bounds__(256) void stats_kernel(const float* __restrict__ f1,
                                                    const float* __restrict__ f2,
                                                    const unsigned int* __restrict__ bits,
                                                    float* __restrict__ mrow,
                                                    float* __restrict__ linv,
                                                    int H) {
  int g = blockIdx.x * 4 + (threadIdx.x >> 6);
  int lane = threadIdx.x & 63;
  if (g >= H * N_NODES) return;
  int h = g / N_NODES, i = g - h * N_NODES;
  float fi = f1[g];
  const float* f2h = f2 + h * N_NODES;
  const unsigned int* brow = bits + (long)i * MASK_WORDS;
  float m = -3.0e38f, l = 0.0f;
  for (int j = lane; j < N_NODES; j += 64) {
    unsigned int w = brow[j >> 5];
    if ((w >> (j & 31)) & 1u) {
      float e = fi + f2h[j];
      e = e > 0.0f ? e : 0.2f * e;
      if (e > m) {
        l = l * __expf(m - e) + 1.0f;
        m = e;
      } else {
        l += __expf(e - m);
      }
    }
  }
  for (int off = 1; off < 64; off <<= 1) {
    float m2 = __shfl_xor(m, off);
    float l2 = __shfl_xor(l, off);
    float mn = fmaxf(m, m2);
    l = l * __expf(m - mn) + l2 * __expf(m2 - mn);
    m = mn;
  }
  if (lane == 0) {
    mrow[g] = m;
    linv[g] = 1.0f / l;
  }
}

// ---------------------------------------------------------------- attention PV
// out[i, h*Fp+c] = act( sum_j p_ij * Wh[j, h*Fp+c] ),  p recomputed on the fly.
// act: 0 = elu, 1 = sigmoid(elu(.))
// grid: (ceil(Fp/64), N/64, H), block 256
__global__ __launch_bounds__(256) void pv_kernel(const float* __restrict__ f1,
                                                 const float* __restrict__ f2,
                                                 const float* __restrict__ mrow,
                                                 const float* __restrict__ linv,
                                                 const unsigned int* __restrict__ bits,
                                                 const float* __restrict__ Wh,
                                                 float* __restrict__ out,
                                                 int H, int Fp, int act) {
  __shared__ float PsT[32][68];  // [j][row]
  __shared__ float Ws[32][68];   // [j][col]
  __shared__ float F1s[64], Ms[64], Ls[64];
  int h = blockIdx.z;
  int i0 = blockIdx.y * 64;
  int cb = blockIdx.x;
  int Ftot = H * Fp;
  int tx = threadIdx.x & 15, ty = threadIdx.x >> 4;
  int lane_r = threadIdx.x & 63;   // row this thread computes p for
  int w4 = threadIdx.x >> 6;       // wave id 0..3

  if (threadIdx.x < 64) {
    int g = h * N_NODES + i0 + threadIdx.x;
    F1s[threadIdx.x] = f1[g];
    Ms[threadIdx.x] = mrow[g];
    Ls[threadIdx.x] = linv[g];
  }
  __syncthreads();

  const float* f2h = f2 + h * N_NODES;
  float acc[4][4] = {};

  for (int j0 = 0; j0 < N_NODES; j0 += 32) {
    // ---- stage P^T tile [32 j][64 rows]
    unsigned int word = bits[(long)(i0 + lane_r) * MASK_WORDS + (j0 >> 5)];
    float fi = F1s[lane_r], mm = Ms[lane_r], li = Ls[lane_r];
#pragma unroll
    for (int it = 0; it < 8; ++it) {
      int jj = w4 + it * 4;
      float p = 0.0f;
      if ((word >> jj) & 1u) {
        float e = fi + f2h[j0 + jj];
        e = e > 0.0f ? e : 0.2f * e;
        p = __expf(e - mm) * li;
      }
      PsT[jj][lane_r] = p;
    }
    // ---- stage Wh tile [32 j][64 cols]
#pragma unroll
    for (int t = threadIdx.x; t < 2048; t += 256) {
      int jj = t >> 6, c = t & 63;
      int cih = cb * 64 + c;
      Ws[jj][c] = (cih < Fp) ? Wh[(long)(j0 + jj) * Ftot + h * Fp + cih] : 0.0f;
    }
    __syncthreads();
#pragma unroll
    for (int k = 0; k < 32; ++k) {
      float4 a = *reinterpret_cast<const float4*>(&PsT[k][ty * 4]);
      float4 b = *reinterpret_cast<const float4*>(&Ws[k][tx * 4]);
      float av[4] = {a.x, a.y, a.z, a.w};
      float bv[4] = {b.x, b.y, b.z, b.w};
#pragma unroll
      for (int i = 0; i < 4; ++i)
#pragma unroll
        for (int j = 0; j < 4; ++j) acc[i][j] += av[i] * bv[j];
    }
    __syncthreads();
  }

  for (int i = 0; i < 4; ++i) {
    int r = i0 + ty * 4 + i;
    for (int j = 0; j < 4; ++j) {
      int cih = cb * 64 + tx * 4 + j;
      if (cih < Fp) {
        float v = acc[i][j];
        v = v > 0.0f ? v : __expf(v) - 1.0f;               // elu
        if (act == 1) v = 1.0f / (1.0f + __expf(-v));      // sigmoid(elu)
        out[(long)r * Ftot + h * Fp + cih] = v;
      }
    }
  }
}

// ---------------------------------------------------------------- host
extern "C" void kernel_launch(void* const* d_in, const int* in_sizes, int n_in,
                              void* d_out, int out_size, void* d_ws, size_t ws_size,
                              hipStream_t stream) {
  const float* x     = (const float*)d_in[0];
  const int*   adj   = (const int*)d_in[1];
  const float* W1    = (const float*)d_in[2];
  const float* a1    = (const float*)d_in[3];
  const float* Wo    = (const float*)d_in[4];
  const float* ao    = (const float*)d_in[5];
  const float* W2    = (const float*)d_in[6];
  const float* a2    = (const float*)d_in[7];
  const float* Wo2   = (const float*)d_in[8];
  const float* ao2   = (const float*)d_in[9];
  const float* lin_w = (const float*)d_in[10];
  const float* lin_b = (const float*)d_in[11];
  float* out = (float*)d_out;

  float* ws = (float*)d_ws;
  unsigned int* bits = (unsigned int*)ws;            // 1,179,648 u32
  float* Wh   = ws + 1179648;                        // up to 6144*256
  float* bufA = Wh + 1572864;
  float* bufB = bufA + 1572864;
  float* Bcat = bufB + 1572864;                      // 65536
  float* f1   = Bcat + 65536;                        // 24576
  float* f2   = f1 + 24576;
  float* mrow = f2 + 24576;
  float* linv = mrow + 24576;

  dim3 b256(256);

  // mask bitpack
  bitpack_kernel<<<N_NODES, b256, 0, stream>>>(adj, bits);

  // ================= layer 1 multi-head (H=4, Fin=256, Fp=64), elu concat
  repack_W_kernel<<<(4 * 256 * 64 + 255) / 256, b256, 0, stream>>>(W1, Bcat, 4, 256, 64);
  gemm_kernel<<<dim3(4, 96), b256, 0, stream>>>(x, Bcat, Wh, 256, 256, nullptr, 0);
  f1f2_kernel<<<(4 * N_NODES) / 4, b256, 0, stream>>>(Wh, a1, f1, f2, 4, 64);
  stats_kernel<<<(4 * N_NODES) / 4, b256, 0, stream>>>(f1, f2, bits, mrow, linv, 4);
  pv_kernel<<<dim3(1, 96, 4), b256, 0, stream>>>(f1, f2, mrow, linv, bits, Wh, bufA, 4, 64, 0);

  // ================= out-attention 1 (H=1, Fp=256), sigmoid(elu)
  gemm_kernel<<<dim3(4, 96), b256, 0, stream>>>(bufA, Wo, Wh, 256, 256, nullptr, 0);
  f1f2_kernel<<<(N_NODES) / 4, b256, 0, stream>>>(Wh, ao, f1, f2, 1, 256);
  stats_kernel<<<(N_NODES) / 4, b256, 0, stream>>>(f1, f2, bits, mrow, linv, 1);
  pv_kernel<<<dim3(4, 96, 1), b256, 0, stream>>>(f1, f2, mrow, linv, bits, Wh, bufB, 1, 256, 1);

  // ================= layer 2 multi-head (H=4, Fin=256, Fp=32), elu concat
  repack_W_kernel<<<(4 * 256 * 32 + 255) / 256, b256, 0, stream>>>(W2, Bcat, 4, 256, 32);
  gemm_kernel<<<dim3(2, 96), b256, 0, stream>>>(bufB, Bcat, Wh, 256, 128, nullptr, 0);
  f1f2_kernel<<<(4 * N_NODES) / 4, b256, 0, stream>>>(Wh, a2, f1, f2, 4, 32);
  stats_kernel<<<(4 * N_NODES) / 4, b256, 0, stream>>>(f1, f2, bits, mrow, linv, 4);
  pv_kernel<<<dim3(1, 96, 4), b256, 0, stream>>>(f1, f2, mrow, linv, bits, Wh, bufA, 4, 32, 0);

  // ================= out-attention 2 (H=1, Fp=128), sigmoid(elu)
  gemm_kernel<<<dim3(2, 96), b256, 0, stream>>>(bufA, Wo2, Wh, 128, 128, nullptr, 0);
  f1f2_kernel<<<(N_NODES) / 4, b256, 0, stream>>>(Wh, ao2, f1, f2, 1, 128);
  stats_kernel<<<(N_NODES) / 4, b256, 0, stream>>>(f1, f2, bits, mrow, linv, 1);
  pv_kernel<<<dim3(2, 96, 1), b256, 0, stream>>>(f1, f2, mrow, linv, bits, Wh, bufB, 1, 128, 1);

  // ================= final linear + relu
  gemm_kernel<<<dim3(6, 96), b256, 0, stream>>>(bufB, lin_w, out, 128, 379, lin_b, 1);
}

// Round 3
// 1743.495 us; speedup vs baseline: 1.9396x; 1.9396x over previous
//
#include <hip/hip_runtime.h>
#include <hip/hip_bf16.h>

#define N_NODES 6144
#define MASK_WORDS 192  // 6144/32

using short8 = __attribute__((ext_vector_type(8))) short;
using f32x4  = __attribute__((ext_vector_type(4))) float;

// f32 -> bf16 bits, round-to-nearest-even
__device__ inline short f2bf(float f) {
  unsigned u = __builtin_bit_cast(unsigned, f);
  u += 0x7fff + ((u >> 16) & 1);
  return (short)(u >> 16);
}

// ---------------------------------------------------------------- bitpack
__global__ __launch_bounds__(256) void bitpack_kernel(const int* __restrict__ adj,
                                                      unsigned int* __restrict__ bits) {
  int row = blockIdx.x;
  int wave = threadIdx.x >> 6, lane = threadIdx.x & 63;
  const int* p = adj + (long)row * N_NODES;
  for (int base = wave * 64; base < N_NODES; base += 256) {
    unsigned long long m = __ballot(p[base + lane] > 0);
    if (lane == 0) {
      bits[row * MASK_WORDS + (base >> 5)] = (unsigned int)m;
      bits[row * MASK_WORDS + (base >> 5) + 1] = (unsigned int)(m >> 32);
    }
  }
}

// ---------------------------------------------------------------- W repack
// W [H][Fin][Fp] -> B [Fin][H*Fp]
__global__ __launch_bounds__(256) void repack_W_kernel(const float* __restrict__ W,
                                                       float* __restrict__ B,
                                                       int H, int Fin, int Fp) {
  int idx = blockIdx.x * blockDim.x + threadIdx.x;
  int total = H * Fin * Fp;
  if (idx >= total) return;
  int h = idx / (Fin * Fp);
  int rem = idx - h * (Fin * Fp);
  int k = rem / Fp, c = rem - k * Fp;
  B[k * (H * Fp) + h * Fp + c] = W[idx];
}

// ---------------------------------------------------------------- GEMM (fp32)
__global__ __launch_bounds__(256) void gemm_kernel(const float* __restrict__ A,
                                                   const float* __restrict__ B,
                                                   float* __restrict__ C,
                                                   int K, int Nc,
                                                   const float* __restrict__ bias,
                                                   int act) {
  __shared__ float As[16][68];
  __shared__ float Bs[16][68];
  int tx = threadIdx.x & 15, ty = threadIdx.x >> 4;
  int m0 = blockIdx.y * 64, n0 = blockIdx.x * 64;
  float acc[4][4] = {};
  for (int k0 = 0; k0 < K; k0 += 16) {
    for (int t = threadIdx.x; t < 1024; t += 256) {
      int k = t & 15, m = t >> 4;
      As[k][m] = A[(long)(m0 + m) * K + k0 + k];
    }
    for (int t = threadIdx.x; t < 1024; t += 256) {
      int k = t >> 6, n = t & 63;
      int col = n0 + n;
      Bs[k][n] = (col < Nc) ? B[(long)(k0 + k) * Nc + col] : 0.0f;
    }
    __syncthreads();
#pragma unroll
    for (int k = 0; k < 16; ++k) {
      float4 a = *reinterpret_cast<const float4*>(&As[k][ty * 4]);
      float4 b = *reinterpret_cast<const float4*>(&Bs[k][tx * 4]);
      float av[4] = {a.x, a.y, a.z, a.w};
      float bv[4] = {b.x, b.y, b.z, b.w};
#pragma unroll
      for (int i = 0; i < 4; ++i)
#pragma unroll
        for (int j = 0; j < 4; ++j) acc[i][j] += av[i] * bv[j];
    }
    __syncthreads();
  }
  for (int i = 0; i < 4; ++i) {
    int m = m0 + ty * 4 + i;
    for (int j = 0; j < 4; ++j) {
      int n = n0 + tx * 4 + j;
      if (n < Nc) {
        float v = acc[i][j];
        if (bias) v += bias[n];
        if (act == 1) v = fmaxf(v, 0.0f);
        C[(long)m * Nc + n] = v;
      }
    }
  }
}

// ---------------------------------------------------------------- f1/f2
__global__ __launch_bounds__(256) void f1f2_kernel(const float* __restrict__ Wh,
                                                   const float* __restrict__ a,
                                                   float* __restrict__ f1,
                                                   float* __restrict__ f2,
                                                   int H, int Fp) {
  int g = blockIdx.x * 4 + (threadIdx.x >> 6);
  int lane = threadIdx.x & 63;
  if (g >= H * N_NODES) return;
  int h = g / N_NODES, n = g - h * N_NODES;
  int Ftot = H * Fp;
  const float* row = Wh + (long)n * Ftot + h * Fp;
  const float* av1 = a + h * 2 * Fp;
  const float* av2 = av1 + Fp;
  float s1 = 0.f, s2 = 0.f;
  for (int c = lane; c < Fp; c += 64) {
    float w = row[c];
    s1 += w * av1[c];
    s2 += w * av2[c];
  }
  for (int off = 32; off > 0; off >>= 1) {
    s1 += __shfl_down(s1, off);
    s2 += __shfl_down(s2, off);
  }
  if (lane == 0) { f1[g] = s1; f2[g] = s2; }
}

// ---------------------------------------------------------------- softmax stats
__global__ __launch_bounds__(256) void stats_kernel(const float* __restrict__ f1,
                                                    const float* __restrict__ f2,
                                                    const unsigned int* __restrict__ bits,
                                                    float* __restrict__ mrow,
                                                    float* __restrict__ linv,
                                                    int H) {
  int g = blockIdx.x * 4 + (threadIdx.x >> 6);
  int lane = threadIdx.x & 63;
  if (g >= H * N_NODES) return;
  int h = g / N_NODES, i = g - h * N_NODES;
  float fi = f1[g];
  const float* f2h = f2 + h * N_NODES;
  const unsigned int* brow = bits + (long)i * MASK_WORDS;
  float m = -3.0e38f, l = 0.0f;
  for (int j = lane; j < N_NODES; j += 64) {
    unsigned int w = brow[j >> 5];
    if ((w >> (j & 31)) & 1u) {
      float e = fi + f2h[j];
      e = e > 0.0f ? e : 0.2f * e;
      if (e > m) {
        l = l * __expf(m - e) + 1.0f;
        m = e;
      } else {
        l += __expf(e - m);
      }
    }
  }
  for (int off = 1; off < 64; off <<= 1) {
    float m2 = __shfl_xor(m, off);
    float l2 = __shfl_xor(l, off);
    float mn = fmaxf(m, m2);
    l = l * __expf(m - mn) + l2 * __expf(m2 - mn);
    m = mn;
  }
  if (lane == 0) {
    mrow[g] = m;
    linv[g] = 1.0f / l;
  }
}

// ---------------------------------------------------------------- transpose Wh -> WhT bf16
// A [N][Ftot] f32 -> At [Ftot][N] bf16 bits
__global__ __launch_bounds__(256) void transpose_bf16_kernel(const float* __restrict__ A,
                                                             short* __restrict__ At,
                                                             int Ftot) {
  __shared__ short t[32][33];
  int c0 = blockIdx.x * 32, n0 = blockIdx.y * 32;
  int tx = threadIdx.x & 31, ty = threadIdx.x >> 5;
  for (int r = ty; r < 32; r += 8)
    t[tx][r] = f2bf(A[(size_t)(n0 + r) * Ftot + c0 + tx]);
  __syncthreads();
  for (int r = ty; r < 32; r += 8)
    At[(size_t)(c0 + r) * N_NODES + n0 + tx] = t[r][tx];
}

// ---------------------------------------------------------------- attention PV via MFMA
// out[i, h*Fp+c] = act( sum_j P[i,j] * V[j,c] ), P recomputed in registers.
// A-frag (P): lane holds P[i0+w*16+(l&15)][j0+(l>>4)*8+e], e=0..7
// B-frag (V): lane holds V[j0+(l>>4)*8+e][c0+n*16+(l&15)] = WhT[col][j...] contiguous
// grid: (ceil(Fp/64), N/64, H), block 256 (4 waves), no LDS, no barriers.
__global__ __launch_bounds__(256) void pv_mfma_kernel(const float* __restrict__ f1,
                                                      const float* __restrict__ f2,
                                                      const float* __restrict__ mrow,
                                                      const float* __restrict__ linv,
                                                      const unsigned int* __restrict__ bits,
                                                      const short* __restrict__ WhT,
                                                      float* __restrict__ out,
                                                      int H, int Fp, int act) {
  int h = blockIdx.z;
  int i0 = blockIdx.y * 64;
  int cb0 = blockIdx.x * 64;
  int Ftot = H * Fp;
  int hFp = h * Fp;
  int w = threadIdx.x >> 6;
  int l = threadIdx.x & 63;
  int row_l = l & 15, grp = l >> 4;

  int i = i0 + w * 16 + row_l;            // row this lane's A-frag serves
  int g = h * N_NODES + i;
  float fi = f1[g], mi = mrow[g], li = linv[g];

  int nf = (Fp - cb0) >> 4; if (nf > 4) nf = 4;   // 16-col frags: {2,4}

  const unsigned int* brow = bits + (size_t)i * MASK_WORDS;
  const float* f2p = f2 + h * N_NODES + grp * 8;

  const short* vtb[4];
#pragma unroll
  for (int n = 0; n < 4; ++n) {
    int col = cb0 + n * 16 + row_l;
    vtb[n] = WhT + (size_t)(hFp + (col < Fp ? col : 0)) * N_NODES + grp * 8;
  }

  f32x4 acc[4] = {f32x4{0,0,0,0}, f32x4{0,0,0,0}, f32x4{0,0,0,0}, f32x4{0,0,0,0}};

  for (int j0 = 0; j0 < N_NODES; j0 += 32) {
    unsigned wb = (brow[j0 >> 5] >> (grp * 8)) & 0xffu;
    f32x4 fA = *reinterpret_cast<const f32x4*>(f2p + j0);
    f32x4 fB = *reinterpret_cast<const f32x4*>(f2p + j0 + 4);
    short8 a;
#pragma unroll
    for (int e = 0; e < 8; ++e) {
      float ev = fi + (e < 4 ? fA[e] : fB[e - 4]);
      ev = ev > 0.0f ? ev : 0.2f * ev;
      float p = __expf(ev - mi) * li;
      a[e] = ((wb >> e) & 1u) ? f2bf(p) : (short)0;
    }
    for (int n = 0; n < nf; ++n) {
      short8 b = *reinterpret_cast<const short8*>(vtb[n] + j0);
      acc[n] = __builtin_amdgcn_mfma_f32_16x16x32_bf16(a, b, acc[n], 0, 0, 0);
    }
  }

  // C/D layout: col = lane&15, row = (lane>>4)*4 + reg
  int orow = i0 + w * 16 + grp * 4;
  for (int n = 0; n < nf; ++n) {
    int col = hFp + cb0 + n * 16 + row_l;
#pragma unroll
    for (int r = 0; r < 4; ++r) {
      float v = acc[n][r];
      v = v > 0.0f ? v : __expf(v) - 1.0f;            // elu
      if (act == 1) v = 1.0f / (1.0f + __expf(-v));   // sigmoid(elu)
      out[(size_t)(orow + r) * Ftot + col] = v;
    }
  }
}

// ---------------------------------------------------------------- host
extern "C" void kernel_launch(void* const* d_in, const int* in_sizes, int n_in,
                              void* d_out, int out_size, void* d_ws, size_t ws_size,
                              hipStream_t stream) {
  const float* x     = (const float*)d_in[0];
  const int*   adj   = (const int*)d_in[1];
  const float* W1    = (const float*)d_in[2];
  const float* a1    = (const float*)d_in[3];
  const float* Wo    = (const float*)d_in[4];
  const float* ao    = (const float*)d_in[5];
  const float* W2    = (const float*)d_in[6];
  const float* a2    = (const float*)d_in[7];
  const float* Wo2   = (const float*)d_in[8];
  const float* ao2   = (const float*)d_in[9];
  const float* lin_w = (const float*)d_in[10];
  const float* lin_b = (const float*)d_in[11];
  float* out = (float*)d_out;

  float* ws = (float*)d_ws;
  unsigned int* bits = (unsigned int*)ws;            // 1,179,648 u32
  float* Wh   = ws + 1179648;                        // 6144*256
  float* bufA = Wh + 1572864;
  float* bufB = bufA + 1572864;
  float* Bcat = bufB + 1572864;                      // 65536
  float* f1   = Bcat + 65536;                        // 24576
  float* f2   = f1 + 24576;
  float* mrow = f2 + 24576;
  float* linv = mrow + 24576;
  short* WhT  = (short*)(linv + 24576);              // 6144*256 bf16

  dim3 b256(256);

  bitpack_kernel<<<N_NODES, b256, 0, stream>>>(adj, bits);

  // ================= layer 1 multi-head (H=4, Fp=64), elu concat
  repack_W_kernel<<<(4 * 256 * 64 + 255) / 256, b256, 0, stream>>>(W1, Bcat, 4, 256, 64);
  gemm_kernel<<<dim3(4, 96), b256, 0, stream>>>(x, Bcat, Wh, 256, 256, nullptr, 0);
  f1f2_kernel<<<(4 * N_NODES) / 4, b256, 0, stream>>>(Wh, a1, f1, f2, 4, 64);
  transpose_bf16_kernel<<<dim3(8, 192), b256, 0, stream>>>(Wh, WhT, 256);
  stats_kernel<<<(4 * N_NODES) / 4, b256, 0, stream>>>(f1, f2, bits, mrow, linv, 4);
  pv_mfma_kernel<<<dim3(1, 96, 4), b256, 0, stream>>>(f1, f2, mrow, linv, bits, WhT, bufA, 4, 64, 0);

  // ================= out-attention 1 (H=1, Fp=256), sigmoid(elu)
  gemm_kernel<<<dim3(4, 96), b256, 0, stream>>>(bufA, Wo, Wh, 256, 256, nullptr, 0);
  f1f2_kernel<<<(N_NODES) / 4, b256, 0, stream>>>(Wh, ao, f1, f2, 1, 256);
  transpose_bf16_kernel<<<dim3(8, 192), b256, 0, stream>>>(Wh, WhT, 256);
  stats_kernel<<<(N_NODES) / 4, b256, 0, stream>>>(f1, f2, bits, mrow, linv, 1);
  pv_mfma_kernel<<<dim3(4, 96, 1), b256, 0, stream>>>(f1, f2, mrow, linv, bits, WhT, bufB, 1, 256, 1);

  // ================= layer 2 multi-head (H=4, Fp=32), elu concat
  repack_W_kernel<<<(4 * 256 * 32 + 255) / 256, b256, 0, stream>>>(W2, Bcat, 4, 256, 32);
  gemm_kernel<<<dim3(2, 96), b256, 0, stream>>>(bufB, Bcat, Wh, 256, 128, nullptr, 0);
  f1f2_kernel<<<(4 * N_NODES) / 4, b256, 0, stream>>>(Wh, a2, f1, f2, 4, 32);
  transpose_bf16_kernel<<<dim3(4, 192), b256, 0, stream>>>(Wh, WhT, 128);
  stats_kernel<<<(4 * N_NODES) / 4, b256, 0, stream>>>(f1, f2, bits, mrow, linv, 4);
  pv_mfma_kernel<<<dim3(1, 96, 4), b256, 0, stream>>>(f1, f2, mrow, linv, bits, WhT, bufA, 4, 32, 0);

  // ================= out-attention 2 (H=1, Fp=128), sigmoid(elu)
  gemm_kernel<<<dim3(2, 96), b256, 0, stream>>>(bufA, Wo2, Wh, 128, 128, nullptr, 0);
  f1f2_kernel<<<(N_NODES) / 4, b256, 0, stream>>>(Wh, ao2, f1, f2, 1, 128);
  transpose_bf16_kernel<<<dim3(4, 192), b256, 0, stream>>>(Wh, WhT, 128);
  stats_kernel<<<(N_NODES) / 4, b256, 0, stream>>>(f1, f2, bits, mrow, linv, 1);
  pv_mfma_kernel<<<dim3(2, 96, 1), b256, 0, stream>>>(f1, f2, mrow, linv, bits, WhT, bufB, 1, 128, 1);

  // ================= final linear + relu
  gemm_kernel<<<dim3(6, 96), b256, 0, stream>>>(bufB, lin_w, out, 128, 379, lin_b, 1);
}

// Round 5
// 1249.114 us; speedup vs baseline: 2.7072x; 1.3958x over previous
//
#include <hip/hip_runtime.h>
#include <hip/hip_bf16.h>

#define N_NODES 6144
#define MASK_WORDS 192  // 6144/32
#define LOG2E 1.44269504088896f

using short8 = __attribute__((ext_vector_type(8))) short;
using f32x4  = __attribute__((ext_vector_type(4))) float;

// f32 -> bf16 bits, round-to-nearest-even
__device__ inline unsigned f2bf_u(float f) {
  unsigned u = __builtin_bit_cast(unsigned, f);
  u += 0x7fff + ((u >> 16) & 1);
  return u >> 16;
}
__device__ inline short f2bf(float f) { return (short)f2bf_u(f); }

// ---------------------------------------------------------------- bitpack
__global__ __launch_bounds__(256) void bitpack_kernel(const int* __restrict__ adj,
                                                      unsigned int* __restrict__ bits) {
  int row = blockIdx.x;
  int wave = threadIdx.x >> 6, lane = threadIdx.x & 63;
  const int* p = adj + (long)row * N_NODES;
  for (int base = wave * 64; base < N_NODES; base += 256) {
    unsigned long long m = __ballot(p[base + lane] > 0);
    if (lane == 0) {
      bits[row * MASK_WORDS + (base >> 5)] = (unsigned int)m;
      bits[row * MASK_WORDS + (base >> 5) + 1] = (unsigned int)(m >> 32);
    }
  }
}

// ---------------------------------------------------------------- W repack
// W [H][Fin][Fp] -> B [Fin][H*Fp]
__global__ __launch_bounds__(256) void repack_W_kernel(const float* __restrict__ W,
                                                       float* __restrict__ B,
                                                       int H, int Fin, int Fp) {
  int idx = blockIdx.x * blockDim.x + threadIdx.x;
  int total = H * Fin * Fp;
  if (idx >= total) return;
  int h = idx / (Fin * Fp);
  int rem = idx - h * (Fin * Fp);
  int k = rem / Fp, c = rem - k * Fp;
  B[k * (H * Fp) + h * Fp + c] = W[idx];
}

// ---------------------------------------------------------------- GEMM (fp32)
__global__ __launch_bounds__(256) void gemm_kernel(const float* __restrict__ A,
                                                   const float* __restrict__ B,
                                                   float* __restrict__ C,
                                                   int K, int Nc,
                                                   const float* __restrict__ bias,
                                                   int act) {
  __shared__ float As[16][68];
  __shared__ float Bs[16][68];
  int tx = threadIdx.x & 15, ty = threadIdx.x >> 4;
  int m0 = blockIdx.y * 64, n0 = blockIdx.x * 64;
  float acc[4][4] = {};
  for (int k0 = 0; k0 < K; k0 += 16) {
    for (int t = threadIdx.x; t < 1024; t += 256) {
      int k = t & 15, m = t >> 4;
      As[k][m] = A[(long)(m0 + m) * K + k0 + k];
    }
    for (int t = threadIdx.x; t < 1024; t += 256) {
      int k = t >> 6, n = t & 63;
      int col = n0 + n;
      Bs[k][n] = (col < Nc) ? B[(long)(k0 + k) * Nc + col] : 0.0f;
    }
    __syncthreads();
#pragma unroll
    for (int k = 0; k < 16; ++k) {
      float4 a = *reinterpret_cast<const float4*>(&As[k][ty * 4]);
      float4 b = *reinterpret_cast<const float4*>(&Bs[k][tx * 4]);
      float av[4] = {a.x, a.y, a.z, a.w};
      float bv[4] = {b.x, b.y, b.z, b.w};
#pragma unroll
      for (int i = 0; i < 4; ++i)
#pragma unroll
        for (int j = 0; j < 4; ++j) acc[i][j] += av[i] * bv[j];
    }
    __syncthreads();
  }
  for (int i = 0; i < 4; ++i) {
    int m = m0 + ty * 4 + i;
    for (int j = 0; j < 4; ++j) {
      int n = n0 + tx * 4 + j;
      if (n < Nc) {
        float v = acc[i][j];
        if (bias) v += bias[n];
        if (act == 1) v = fmaxf(v, 0.0f);
        C[(long)m * Nc + n] = v;
      }
    }
  }
}

// ---------------------------------------------------------------- f1/f2 (scaled by log2 e)
__global__ __launch_bounds__(256) void f1f2_kernel(const float* __restrict__ Wh,
                                                   const float* __restrict__ a,
                                                   float* __restrict__ f1,
                                                   float* __restrict__ f2,
                                                   int H, int Fp) {
  int g = blockIdx.x * 4 + (threadIdx.x >> 6);
  int lane = threadIdx.x & 63;
  if (g >= H * N_NODES) return;
  int h = g / N_NODES, n = g - h * N_NODES;
  int Ftot = H * Fp;
  const float* row = Wh + (long)n * Ftot + h * Fp;
  const float* av1 = a + h * 2 * Fp;
  const float* av2 = av1 + Fp;
  float s1 = 0.f, s2 = 0.f;
  for (int c = lane; c < Fp; c += 64) {
    float w = row[c];
    s1 += w * av1[c];
    s2 += w * av2[c];
  }
  for (int off = 32; off > 0; off >>= 1) {
    s1 += __shfl_down(s1, off);
    s2 += __shfl_down(s2, off);
  }
  if (lane == 0) { f1[g] = s1 * LOG2E; f2[g] = s2 * LOG2E; }
}

// ---------------------------------------------------------------- softmax stats (log2 domain)
// per (h,i): brow = m2 + log2(sum exp2(e2 - m2)), e2 = LR(f1s+f2s) (pre-scaled)
__global__ __launch_bounds__(256) void stats_kernel(const float* __restrict__ f1,
                                                    const float* __restrict__ f2,
                                                    const unsigned int* __restrict__ bits,
                                                    float* __restrict__ brow,
                                                    int H) {
  int g = blockIdx.x * 4 + (threadIdx.x >> 6);
  int lane = threadIdx.x & 63;
  if (g >= H * N_NODES) return;
  int h = g / N_NODES, i = g - h * N_NODES;
  float fi = f1[g];
  const float* f2h = f2 + h * N_NODES;
  const unsigned int* br = bits + (long)i * MASK_WORDS;
  float m = -3.0e38f, l = 0.0f;
  for (int j = lane; j < N_NODES; j += 64) {
    unsigned int w = br[j >> 5];
    if ((w >> (j & 31)) & 1u) {
      float e = fi + f2h[j];
      e = fmaxf(e, 0.2f * e);
      if (e > m) {
        l = l * exp2f(m - e) + 1.0f;
        m = e;
      } else {
        l += exp2f(e - m);
      }
    }
  }
  for (int off = 1; off < 64; off <<= 1) {
    float m2 = __shfl_xor(m, off);
    float l2 = __shfl_xor(l, off);
    float mn = fmaxf(m, m2);
    l = l * exp2f(m - mn) + l2 * exp2f(m2 - mn);
    m = mn;
  }
  if (lane == 0) brow[g] = m + log2f(l);
}

// ---------------------------------------------------------------- transpose Wh -> WhT bf16
__global__ __launch_bounds__(256) void transpose_bf16_kernel(const float* __restrict__ A,
                                                             short* __restrict__ At,
                                                             int Ftot) {
  __shared__ short t[32][33];
  int c0 = blockIdx.x * 32, n0 = blockIdx.y * 32;
  int tx = threadIdx.x & 31, ty = threadIdx.x >> 5;
  for (int r = ty; r < 32; r += 8)
    t[tx][r] = f2bf(A[(size_t)(n0 + r) * Ftot + c0 + tx]);
  __syncthreads();
  for (int r = ty; r < 32; r += 8)
    At[(size_t)(c0 + r) * N_NODES + n0 + tx] = t[r][tx];
}

// ---------------------------------------------------------------- attention PV via MFMA
// 1024 threads = 16 waves = 4 row-strips x 4 j-quarters. Partial accs reduced in LDS.
// P recomputed in registers: p = exp2(LR(f1s_i + f2s_j) - brow_i), masked -> 0.
// grid: (ceil(Fp/64), N/64, H)
__global__ __launch_bounds__(1024) void pv_mfma_kernel(const float* __restrict__ f1s,
                                                       const float* __restrict__ f2s,
                                                       const float* __restrict__ brow,
                                                       const unsigned int* __restrict__ bits,
                                                       const short* __restrict__ WhT,
                                                       float* __restrict__ out,
                                                       int H, int Fp, int act) {
  __shared__ float f2sh[N_NODES];     // 24 KB
  __shared__ float red[4][16][68];    // 17 KB: [strip][row][col]
  int h = blockIdx.z;
  int i0 = blockIdx.y * 64;
  int cb0 = blockIdx.x * 64;
  int Ftot = H * Fp, hFp = h * Fp;
  int hN = h * N_NODES;
  int tid = threadIdx.x;
  int w = tid >> 6, l = tid & 63;
  int strip = w & 3, jq = w >> 2;
  int row_l = l & 15, grp = l >> 4;

  for (int idx = tid; idx < N_NODES; idx += 1024)
    f2sh[idx] = f2s[hN + idx];
  __syncthreads();

  int i = i0 + strip * 16 + row_l;
  float fi = f1s[hN + i];
  float bi = brow[hN + i];
  const unsigned int* brow_bits = bits + (size_t)i * MASK_WORDS;

  int nf = (Fp - cb0) >> 4; if (nf > 4) nf = 4;   // 16-col frags: 2 or 4

  const short* vtb[4];
#pragma unroll
  for (int n = 0; n < 4; ++n) {
    int col = cb0 + n * 16 + row_l;
    vtb[n] = WhT + (size_t)(hFp + (col < Fp ? col : 0)) * N_NODES + grp * 8;
  }

  f32x4 acc[4] = {f32x4{0,0,0,0}, f32x4{0,0,0,0}, f32x4{0,0,0,0}, f32x4{0,0,0,0}};

  const int JQ_LEN = N_NODES / 4;   // 1536
  int jbeg = jq * JQ_LEN;
#pragma unroll 2
  for (int js = 0; js < JQ_LEN; js += 32) {
    int j0 = jbeg + js;
    unsigned word = brow_bits[j0 >> 5];
    unsigned wb = (word >> (grp * 8)) & 0xffu;
    const float* fp = &f2sh[j0 + grp * 8];
    f32x4 fA = *reinterpret_cast<const f32x4*>(fp);
    f32x4 fB = *reinterpret_cast<const f32x4*>(fp + 4);
    float p[8];
#pragma unroll
    for (int e = 0; e < 8; ++e) {
      float s = fi + (e < 4 ? fA[e] : fB[e - 4]);
      float t = fmaxf(s, 0.2f * s) - bi;
      t = ((wb >> e) & 1u) ? t : -1.0e30f;
      p[e] = exp2f(t);
    }
    union { short8 s8; unsigned u32[4]; } au;
#pragma unroll
    for (int ep = 0; ep < 4; ++ep)
      au.u32[ep] = f2bf_u(p[2 * ep]) | (f2bf_u(p[2 * ep + 1]) << 16);
#pragma unroll
    for (int n = 0; n < 4; ++n) {
      if (n < nf) {
        short8 b = *reinterpret_cast<const short8*>(vtb[n] + j0);
        acc[n] = __builtin_amdgcn_mfma_f32_16x16x32_bf16(au.s8, b, acc[n], 0, 0, 0);
      }
    }
  }

  // ---- reduce j-quarters in LDS (C/D layout: col=lane&15, row=grp*4+reg)
#pragma unroll
  for (int r = 0; r < 4; ++r) {
    if (jq == r) {
#pragma unroll
      for (int n = 0; n < 4; ++n) {
        if (n < nf) {
#pragma unroll
          for (int k = 0; k < 4; ++k) {
            if (r == 0)
              red[strip][grp * 4 + k][n * 16 + row_l] = acc[n][k];
            else
              red[strip][grp * 4 + k][n * 16 + row_l] += acc[n][k];
          }
        }
      }
    }
    __syncthreads();
  }

  // ---- activation + store
  int tc_shift = (nf == 4) ? 6 : 5;
  int totc = nf * 16;
  int tot = 64 * totc;
  for (int t = tid; t < tot; t += 1024) {
    int rr = t >> tc_shift, cc = t & (totc - 1);
    float v = red[rr >> 4][rr & 15][cc];
    v = v > 0.0f ? v : exp2f(v * LOG2E) - 1.0f;            // elu
    if (act == 1) v = 1.0f / (1.0f + exp2f(-v * LOG2E));   // sigmoid(elu)
    out[(size_t)(i0 + rr) * Ftot + hFp + cb0 + cc] = v;
  }
}

// ---------------------------------------------------------------- host
extern "C" void kernel_launch(void* const* d_in, const int* in_sizes, int n_in,
                              void* d_out, int out_size, void* d_ws, size_t ws_size,
                              hipStream_t stream) {
  const float* x     = (const float*)d_in[0];
  const int*   adj   = (const int*)d_in[1];
  const float* W1    = (const float*)d_in[2];
  const float* a1    = (const float*)d_in[3];
  const float* Wo    = (const float*)d_in[4];
  const float* ao    = (const float*)d_in[5];
  const float* W2    = (const float*)d_in[6];
  const float* a2    = (const float*)d_in[7];
  const float* Wo2   = (const float*)d_in[8];
  const float* ao2   = (const float*)d_in[9];
  const float* lin_w = (const float*)d_in[10];
  const float* lin_b = (const float*)d_in[11];
  float* out = (float*)d_out;

  float* ws = (float*)d_ws;
  unsigned int* bits = (unsigned int*)ws;            // 1,179,648 u32
  float* Wh   = ws + 1179648;                        // 6144*256
  float* bufA = Wh + 1572864;
  float* bufB = bufA + 1572864;
  float* Bcat = bufB + 1572864;                      // 65536
  float* f1   = Bcat + 65536;                        // 24576
  float* f2   = f1 + 24576;
  float* brow = f2 + 24576;
  short* WhT  = (short*)(brow + 24576);              // 6144*256 bf16

  dim3 b256(256);
  dim3 b1k(1024);

  bitpack_kernel<<<N_NODES, b256, 0, stream>>>(adj, bits);

  // ================= layer 1 multi-head (H=4, Fp=64), elu concat
  repack_W_kernel<<<(4 * 256 * 64 + 255) / 256, b256, 0, stream>>>(W1, Bcat, 4, 256, 64);
  gemm_kernel<<<dim3(4, 96), b256, 0, stream>>>(x, Bcat, Wh, 256, 256, nullptr, 0);
  f1f2_kernel<<<(4 * N_NODES) / 4, b256, 0, stream>>>(Wh, a1, f1, f2, 4, 64);
  transpose_bf16_kernel<<<dim3(8, 192), b256, 0, stream>>>(Wh, WhT, 256);
  stats_kernel<<<(4 * N_NODES) / 4, b256, 0, stream>>>(f1, f2, bits, brow, 4);
  pv_mfma_kernel<<<dim3(1, 96, 4), b1k, 0, stream>>>(f1, f2, brow, bits, WhT, bufA, 4, 64, 0);

  // ================= out-attention 1 (H=1, Fp=256), sigmoid(elu)
  gemm_kernel<<<dim3(4, 96), b256, 0, stream>>>(bufA, Wo, Wh, 256, 256, nullptr, 0);
  f1f2_kernel<<<(N_NODES) / 4, b256, 0, stream>>>(Wh, ao, f1, f2, 1, 256);
  transpose_bf16_kernel<<<dim3(8, 192), b256, 0, stream>>>(Wh, WhT, 256);
  stats_kernel<<<(N_NODES) / 4, b256, 0, stream>>>(f1, f2, bits, brow, 1);
  pv_mfma_kernel<<<dim3(4, 96, 1), b1k, 0, stream>>>(f1, f2, brow, bits, WhT, bufB, 1, 256, 1);

  // ================= layer 2 multi-head (H=4, Fp=32), elu concat
  repack_W_kernel<<<(4 * 256 * 32 + 255) / 256, b256, 0, stream>>>(W2, Bcat, 4, 256, 32);
  gemm_kernel<<<dim3(2, 96), b256, 0, stream>>>(bufB, Bcat, Wh, 256, 128, nullptr, 0);
  f1f2_kernel<<<(4 * N_NODES) / 4, b256, 0, stream>>>(Wh, a2, f1, f2, 4, 32);
  transpose_bf16_kernel<<<dim3(4, 192), b256, 0, stream>>>(Wh, WhT, 128);
  stats_kernel<<<(4 * N_NODES) / 4, b256, 0, stream>>>(f1, f2, bits, brow, 4);
  pv_mfma_kernel<<<dim3(1, 96, 4), b1k, 0, stream>>>(f1, f2, brow, bits, WhT, bufA, 4, 32, 0);

  // ================= out-attention 2 (H=1, Fp=128), sigmoid(elu)
  gemm_kernel<<<dim3(2, 96), b256, 0, stream>>>(bufA, Wo2, Wh, 128, 128, nullptr, 0);
  f1f2_kernel<<<(N_NODES) / 4, b256, 0, stream>>>(Wh, ao2, f1, f2, 1, 128);
  transpose_bf16_kernel<<<dim3(4, 192), b256, 0, stream>>>(Wh, WhT, 128);
  stats_kernel<<<(N_NODES) / 4, b256, 0, stream>>>(f1, f2, bits, brow, 1);
  pv_mfma_kernel<<<dim3(2, 96, 1), b1k, 0, stream>>>(f1, f2, brow, bits, WhT, bufB, 1, 128, 1);

  // ================= final linear + relu
  gemm_kernel<<<dim3(6, 96), b256, 0, stream>>>(bufB, lin_w, out, 128, 379, lin_b, 1);
}

// Round 6
// 1114.065 us; speedup vs baseline: 3.0354x; 1.1212x over previous
//
#include <hip/hip_runtime.h>
#include <hip/hip_bf16.h>

#define N_NODES 6144
#define MASK_WORDS 192  // 6144/32
#define LOG2E 1.44269504088896f

using short8 = __attribute__((ext_vector_type(8))) short;
using f32x4  = __attribute__((ext_vector_type(4))) float;

// f32 -> bf16 bits, round-to-nearest-even (setup-path quality)
__device__ inline unsigned f2bf_u(float f) {
  unsigned u = __builtin_bit_cast(unsigned, f);
  u += 0x7fff + ((u >> 16) & 1);
  return u >> 16;
}
__device__ inline short f2bf(float f) { return (short)f2bf_u(f); }

// ---------------------------------------------------------------- bitpack
__global__ __launch_bounds__(256) void bitpack_kernel(const int* __restrict__ adj,
                                                      unsigned int* __restrict__ bits) {
  int row = blockIdx.x;
  int wave = threadIdx.x >> 6, lane = threadIdx.x & 63;
  const int* p = adj + (long)row * N_NODES;
  for (int base = wave * 64; base < N_NODES; base += 256) {
    unsigned long long m = __ballot(p[base + lane] > 0);
    if (lane == 0) {
      bits[row * MASK_WORDS + (base >> 5)] = (unsigned int)m;
      bits[row * MASK_WORDS + (base >> 5) + 1] = (unsigned int)(m >> 32);
    }
  }
}

// ---------------------------------------------------------------- W repack
// W [H][Fin][Fp] -> B [Fin][H*Fp]
__global__ __launch_bounds__(256) void repack_W_kernel(const float* __restrict__ W,
                                                       float* __restrict__ B,
                                                       int H, int Fin, int Fp) {
  int idx = blockIdx.x * blockDim.x + threadIdx.x;
  int total = H * Fin * Fp;
  if (idx >= total) return;
  int h = idx / (Fin * Fp);
  int rem = idx - h * (Fin * Fp);
  int k = rem / Fp, c = rem - k * Fp;
  B[k * (H * Fp) + h * Fp + c] = W[idx];
}

// ---------------------------------------------------------------- GEMM (fp32)
__global__ __launch_bounds__(256) void gemm_kernel(const float* __restrict__ A,
                                                   const float* __restrict__ B,
                                                   float* __restrict__ C,
                                                   int K, int Nc,
                                                   const float* __restrict__ bias,
                                                   int act) {
  __shared__ float As[16][68];
  __shared__ float Bs[16][68];
  int tx = threadIdx.x & 15, ty = threadIdx.x >> 4;
  int m0 = blockIdx.y * 64, n0 = blockIdx.x * 64;
  float acc[4][4] = {};
  for (int k0 = 0; k0 < K; k0 += 16) {
    for (int t = threadIdx.x; t < 1024; t += 256) {
      int k = t & 15, m = t >> 4;
      As[k][m] = A[(long)(m0 + m) * K + k0 + k];
    }
    for (int t = threadIdx.x; t < 1024; t += 256) {
      int k = t >> 6, n = t & 63;
      int col = n0 + n;
      Bs[k][n] = (col < Nc) ? B[(long)(k0 + k) * Nc + col] : 0.0f;
    }
    __syncthreads();
#pragma unroll
    for (int k = 0; k < 16; ++k) {
      float4 a = *reinterpret_cast<const float4*>(&As[k][ty * 4]);
      float4 b = *reinterpret_cast<const float4*>(&Bs[k][tx * 4]);
      float av[4] = {a.x, a.y, a.z, a.w};
      float bv[4] = {b.x, b.y, b.z, b.w};
#pragma unroll
      for (int i = 0; i < 4; ++i)
#pragma unroll
        for (int j = 0; j < 4; ++j) acc[i][j] += av[i] * bv[j];
    }
    __syncthreads();
  }
  for (int i = 0; i < 4; ++i) {
    int m = m0 + ty * 4 + i;
    for (int j = 0; j < 4; ++j) {
      int n = n0 + tx * 4 + j;
      if (n < Nc) {
        float v = acc[i][j];
        if (bias) v += bias[n];
        if (act == 1) v = fmaxf(v, 0.0f);
        C[(long)m * Nc + n] = v;
      }
    }
  }
}

// ---------------------------------------------------------------- f1/f2 (scaled by log2 e)
__global__ __launch_bounds__(256) void f1f2_kernel(const float* __restrict__ Wh,
                                                   const float* __restrict__ a,
                                                   float* __restrict__ f1,
                                                   float* __restrict__ f2,
                                                   int H, int Fp) {
  int g = blockIdx.x * 4 + (threadIdx.x >> 6);
  int lane = threadIdx.x & 63;
  if (g >= H * N_NODES) return;
  int h = g / N_NODES, n = g - h * N_NODES;
  int Ftot = H * Fp;
  const float* row = Wh + (long)n * Ftot + h * Fp;
  const float* av1 = a + h * 2 * Fp;
  const float* av2 = av1 + Fp;
  float s1 = 0.f, s2 = 0.f;
  for (int c = lane; c < Fp; c += 64) {
    float w = row[c];
    s1 += w * av1[c];
    s2 += w * av2[c];
  }
  for (int off = 32; off > 0; off >>= 1) {
    s1 += __shfl_down(s1, off);
    s2 += __shfl_down(s2, off);
  }
  if (lane == 0) { f1[g] = s1 * LOG2E; f2[g] = s2 * LOG2E; }
}

// ---------------------------------------------------------------- softmax stats (log2 domain)
__global__ __launch_bounds__(256) void stats_kernel(const float* __restrict__ f1,
                                                    const float* __restrict__ f2,
                                                    const unsigned int* __restrict__ bits,
                                                    float* __restrict__ brow,
                                                    int H) {
  int g = blockIdx.x * 4 + (threadIdx.x >> 6);
  int lane = threadIdx.x & 63;
  if (g >= H * N_NODES) return;
  int h = g / N_NODES, i = g - h * N_NODES;
  float fi = f1[g];
  const float* f2h = f2 + h * N_NODES;
  const unsigned int* br = bits + (long)i * MASK_WORDS;
  float m = -3.0e38f, l = 0.0f;
  for (int j = lane; j < N_NODES; j += 64) {
    unsigned int w = br[j >> 5];
    if ((w >> (j & 31)) & 1u) {
      float e = fi + f2h[j];
      e = fmaxf(e, 0.2f * e);
      if (e > m) {
        l = l * exp2f(m - e) + 1.0f;
        m = e;
      } else {
        l += exp2f(e - m);
      }
    }
  }
  for (int off = 1; off < 64; off <<= 1) {
    float m2 = __shfl_xor(m, off);
    float l2 = __shfl_xor(l, off);
    float mn = fmaxf(m, m2);
    l = l * exp2f(m - mn) + l2 * exp2f(m2 - mn);
    m = mn;
  }
  if (lane == 0) brow[g] = m + log2f(l);
}

// ---------------------------------------------------------------- transpose Wh -> WhT bf16
__global__ __launch_bounds__(256) void transpose_bf16_kernel(const float* __restrict__ A,
                                                             short* __restrict__ At,
                                                             int Ftot) {
  __shared__ short t[32][33];
  int c0 = blockIdx.x * 32, n0 = blockIdx.y * 32;
  int tx = threadIdx.x & 31, ty = threadIdx.x >> 5;
  for (int r = ty; r < 32; r += 8)
    t[tx][r] = f2bf(A[(size_t)(n0 + r) * Ftot + c0 + tx]);
  __syncthreads();
  for (int r = ty; r < 32; r += 8)
    At[(size_t)(c0 + r) * N_NODES + n0 + tx] = t[r][tx];
}

// ---------------------------------------------------------------- attention PV via MFMA
// 1024 threads = 16 waves = 2 row-strips x 8 j-eighths. Block covers 32 rows x 64 cols.
// P recomputed in registers: p = exp2(LR(f1s_i + f2s_j) - brow_i), masked -> 0.
// red[8][2][16][68] ALIASES f2sh (f2sh dead after main loop; barrier separates).
// grid: (ceil(Fp/64), N/32, H)
__global__ __launch_bounds__(1024) void pv_mfma_kernel(const float* __restrict__ f1s,
                                                       const float* __restrict__ f2s,
                                                       const float* __restrict__ brow,
                                                       const unsigned int* __restrict__ bits,
                                                       const short* __restrict__ WhT,
                                                       float* __restrict__ out,
                                                       int H, int Fp, int act) {
  __shared__ float shmem[8 * 2 * 16 * 68];   // 68 KB; also holds f2sh[6144] (24 KB)
  float* f2sh = shmem;
  typedef float red_t[2][16][68];
  red_t* red = reinterpret_cast<red_t*>(shmem);

  int h = blockIdx.z;
  int i0 = blockIdx.y * 32;
  int cb0 = blockIdx.x * 64;
  int Ftot = H * Fp, hFp = h * Fp;
  int hN = h * N_NODES;
  int tid = threadIdx.x;
  int w = tid >> 6, l = tid & 63;
  int strip = w & 1, jq = w >> 1;
  int row_l = l & 15, grp = l >> 4;

  // stage f2 (vectorized: 1536 float4)
  {
    const float4* src = reinterpret_cast<const float4*>(f2s + hN);
    float4* dst = reinterpret_cast<float4*>(f2sh);
    for (int idx = tid; idx < N_NODES / 4; idx += 1024) dst[idx] = src[idx];
  }
  __syncthreads();

  int i = i0 + strip * 16 + row_l;
  float fi = f1s[hN + i];
  float bi = brow[hN + i];
  float c1 = fi - bi;
  float c2 = 0.2f * fi - bi;
  const unsigned int* brow_bits = bits + (size_t)i * MASK_WORDS;

  int nf = (Fp - cb0) >> 4; if (nf > 4) nf = 4;   // 16-col frags: 2 or 4

  const short* vtb[4];
#pragma unroll
  for (int n = 0; n < 4; ++n) {
    int col = cb0 + n * 16 + row_l;
    vtb[n] = WhT + (size_t)(hFp + (col < Fp ? col : 0)) * N_NODES + grp * 8;
  }

  f32x4 acc[4] = {f32x4{0,0,0,0}, f32x4{0,0,0,0}, f32x4{0,0,0,0}, f32x4{0,0,0,0}};

  const int JQ_LEN = N_NODES / 8;   // 768
  int jbeg = jq * JQ_LEN;
#pragma unroll 2
  for (int js = 0; js < JQ_LEN; js += 32) {
    int j0 = jbeg + js;
    unsigned word = brow_bits[j0 >> 5];
    unsigned wb = (word >> (grp * 8)) & 0xffu;
    const float* fp = &f2sh[j0 + grp * 8];
    f32x4 fA = *reinterpret_cast<const f32x4*>(fp);
    f32x4 fB = *reinterpret_cast<const f32x4*>(fp + 4);
    float p[8];
#pragma unroll
    for (int e = 0; e < 8; ++e) {
      float f = (e < 4 ? fA[e] : fB[e - 4]);
      float t = fmaxf(f + c1, f * 0.2f + c2);
      t = ((wb >> e) & 1u) ? t : -1.0e30f;
      p[e] = exp2f(t);
    }
    union { short8 s8; unsigned u32[4]; } au;
#pragma unroll
    for (int ep = 0; ep < 4; ++ep) {
      unsigned ue = __builtin_bit_cast(unsigned, p[2 * ep]);
      unsigned uo = __builtin_bit_cast(unsigned, p[2 * ep + 1]);
      au.u32[ep] = (ue >> 16) | (uo & 0xffff0000u);   // truncation pack
    }
#pragma unroll
    for (int n = 0; n < 4; ++n) {
      if (n < nf) {
        short8 b = *reinterpret_cast<const short8*>(vtb[n] + j0);
        acc[n] = __builtin_amdgcn_mfma_f32_16x16x32_bf16(au.s8, b, acc[n], 0, 0, 0);
      }
    }
  }

  // ---- parallel reduction over 8 j-eighths (red aliases f2sh)
  __syncthreads();   // everyone done reading f2sh
#pragma unroll
  for (int n = 0; n < 4; ++n) {
    if (n < nf) {
#pragma unroll
      for (int k = 0; k < 4; ++k)
        red[jq][strip][grp * 4 + k][n * 16 + row_l] = acc[n][k];
    }
  }
  __syncthreads();

  // ---- sum 8 partials + activation + store (32 rows x nf*16 cols)
  int totc = nf * 16;
  int tc_shift = (nf == 4) ? 6 : 5;
  int tot = 32 * totc;
  for (int t = tid; t < tot; t += 1024) {
    int rr = t >> tc_shift, cc = t & (totc - 1);
    float v = 0.0f;
#pragma unroll
    for (int q = 0; q < 8; ++q) v += red[q][rr >> 4][rr & 15][cc];
    v = v > 0.0f ? v : exp2f(v * LOG2E) - 1.0f;            // elu
    if (act == 1) v = 1.0f / (1.0f + exp2f(-v * LOG2E));   // sigmoid(elu)
    out[(size_t)(i0 + rr) * Ftot + hFp + cb0 + cc] = v;
  }
}

// ---------------------------------------------------------------- host
extern "C" void kernel_launch(void* const* d_in, const int* in_sizes, int n_in,
                              void* d_out, int out_size, void* d_ws, size_t ws_size,
                              hipStream_t stream) {
  const float* x     = (const float*)d_in[0];
  const int*   adj   = (const int*)d_in[1];
  const float* W1    = (const float*)d_in[2];
  const float* a1    = (const float*)d_in[3];
  const float* Wo    = (const float*)d_in[4];
  const float* ao    = (const float*)d_in[5];
  const float* W2    = (const float*)d_in[6];
  const float* a2    = (const float*)d_in[7];
  const float* Wo2   = (const float*)d_in[8];
  const float* ao2   = (const float*)d_in[9];
  const float* lin_w = (const float*)d_in[10];
  const float* lin_b = (const float*)d_in[11];
  float* out = (float*)d_out;

  float* ws = (float*)d_ws;
  unsigned int* bits = (unsigned int*)ws;            // 1,179,648 u32
  float* Wh   = ws + 1179648;                        // 6144*256
  float* bufA = Wh + 1572864;
  float* bufB = bufA + 1572864;
  float* Bcat = bufB + 1572864;                      // 65536
  float* f1   = Bcat + 65536;                        // 24576
  float* f2   = f1 + 24576;
  float* brow = f2 + 24576;
  short* WhT  = (short*)(brow + 24576);              // 6144*256 bf16

  dim3 b256(256);
  dim3 b1k(1024);

  bitpack_kernel<<<N_NODES, b256, 0, stream>>>(adj, bits);

  // ================= layer 1 multi-head (H=4, Fp=64), elu concat
  repack_W_kernel<<<(4 * 256 * 64 + 255) / 256, b256, 0, stream>>>(W1, Bcat, 4, 256, 64);
  gemm_kernel<<<dim3(4, 96), b256, 0, stream>>>(x, Bcat, Wh, 256, 256, nullptr, 0);
  f1f2_kernel<<<(4 * N_NODES) / 4, b256, 0, stream>>>(Wh, a1, f1, f2, 4, 64);
  transpose_bf16_kernel<<<dim3(8, 192), b256, 0, stream>>>(Wh, WhT, 256);
  stats_kernel<<<(4 * N_NODES) / 4, b256, 0, stream>>>(f1, f2, bits, brow, 4);
  pv_mfma_kernel<<<dim3(1, 192, 4), b1k, 0, stream>>>(f1, f2, brow, bits, WhT, bufA, 4, 64, 0);

  // ================= out-attention 1 (H=1, Fp=256), sigmoid(elu)
  gemm_kernel<<<dim3(4, 96), b256, 0, stream>>>(bufA, Wo, Wh, 256, 256, nullptr, 0);
  f1f2_kernel<<<(N_NODES) / 4, b256, 0, stream>>>(Wh, ao, f1, f2, 1, 256);
  transpose_bf16_kernel<<<dim3(8, 192), b256, 0, stream>>>(Wh, WhT, 256);
  stats_kernel<<<(N_NODES) / 4, b256, 0, stream>>>(f1, f2, bits, brow, 1);
  pv_mfma_kernel<<<dim3(4, 192, 1), b1k, 0, stream>>>(f1, f2, brow, bits, WhT, bufB, 1, 256, 1);

  // ================= layer 2 multi-head (H=4, Fp=32), elu concat
  repack_W_kernel<<<(4 * 256 * 32 + 255) / 256, b256, 0, stream>>>(W2, Bcat, 4, 256, 32);
  gemm_kernel<<<dim3(2, 96), b256, 0, stream>>>(bufB, Bcat, Wh, 256, 128, nullptr, 0);
  f1f2_kernel<<<(4 * N_NODES) / 4, b256, 0, stream>>>(Wh, a2, f1, f2, 4, 32);
  transpose_bf16_kernel<<<dim3(4, 192), b256, 0, stream>>>(Wh, WhT, 128);
  stats_kernel<<<(4 * N_NODES) / 4, b256, 0, stream>>>(f1, f2, bits, brow, 4);
  pv_mfma_kernel<<<dim3(1, 192, 4), b1k, 0, stream>>>(f1, f2, brow, bits, WhT, bufA, 4, 32, 0);

  // ================= out-attention 2 (H=1, Fp=128), sigmoid(elu)
  gemm_kernel<<<dim3(2, 96), b256, 0, stream>>>(bufA, Wo2, Wh, 128, 128, nullptr, 0);
  f1f2_kernel<<<(N_NODES) / 4, b256, 0, stream>>>(Wh, ao2, f1, f2, 1, 128);
  transpose_bf16_kernel<<<dim3(4, 192), b256, 0, stream>>>(Wh, WhT, 128);
  stats_kernel<<<(N_NODES) / 4, b256, 0, stream>>>(f1, f2, bits, brow, 1);
  pv_mfma_kernel<<<dim3(2, 192, 1), b1k, 0, stream>>>(f1, f2, brow, bits, WhT, bufB, 1, 128, 1);

  // ================= final linear + relu
  gemm_kernel<<<dim3(6, 96), b256, 0, stream>>>(bufB, lin_w, out, 128, 379, lin_b, 1);
}

// Round 7
// 1062.753 us; speedup vs baseline: 3.1819x; 1.0483x over previous
//
#include <hip/hip_runtime.h>
#include <hip/hip_bf16.h>

#define N_NODES 6144
#define MASK_WORDS 192  // 6144/32
#define LOG2E 1.44269504088896f

using short8 = __attribute__((ext_vector_type(8))) short;
using f32x4  = __attribute__((ext_vector_type(4))) float;

// f32 -> bf16 bits, round-to-nearest-even (setup-path quality)
__device__ inline unsigned f2bf_u(float f) {
  unsigned u = __builtin_bit_cast(unsigned, f);
  u += 0x7fff + ((u >> 16) & 1);
  return u >> 16;
}
__device__ inline short f2bf(float f) { return (short)f2bf_u(f); }

// ---------------------------------------------------------------- bitpack
__global__ __launch_bounds__(256) void bitpack_kernel(const int* __restrict__ adj,
                                                      unsigned int* __restrict__ bits) {
  int row = blockIdx.x;
  int wave = threadIdx.x >> 6, lane = threadIdx.x & 63;
  const int* p = adj + (long)row * N_NODES;
  for (int base = wave * 64; base < N_NODES; base += 256) {
    unsigned long long m = __ballot(p[base + lane] > 0);
    if (lane == 0) {
      bits[row * MASK_WORDS + (base >> 5)] = (unsigned int)m;
      bits[row * MASK_WORDS + (base >> 5) + 1] = (unsigned int)(m >> 32);
    }
  }
}

// ---------------------------------------------------------------- W repack
// W [H][Fin][Fp] -> B [Fin][H*Fp]
__global__ __launch_bounds__(256) void repack_W_kernel(const float* __restrict__ W,
                                                       float* __restrict__ B,
                                                       int H, int Fin, int Fp) {
  int idx = blockIdx.x * blockDim.x + threadIdx.x;
  int total = H * Fin * Fp;
  if (idx >= total) return;
  int h = idx / (Fin * Fp);
  int rem = idx - h * (Fin * Fp);
  int k = rem / Fp, c = rem - k * Fp;
  B[k * (H * Fp) + h * Fp + c] = W[idx];
}

// ---------------------------------------------------------------- GEMM (fp32)
__global__ __launch_bounds__(256) void gemm_kernel(const float* __restrict__ A,
                                                   const float* __restrict__ B,
                                                   float* __restrict__ C,
                                                   int K, int Nc,
                                                   const float* __restrict__ bias,
                                                   int act) {
  __shared__ float As[16][68];
  __shared__ float Bs[16][68];
  int tx = threadIdx.x & 15, ty = threadIdx.x >> 4;
  int m0 = blockIdx.y * 64, n0 = blockIdx.x * 64;
  float acc[4][4] = {};
  for (int k0 = 0; k0 < K; k0 += 16) {
    for (int t = threadIdx.x; t < 1024; t += 256) {
      int k = t & 15, m = t >> 4;
      As[k][m] = A[(long)(m0 + m) * K + k0 + k];
    }
    for (int t = threadIdx.x; t < 1024; t += 256) {
      int k = t >> 6, n = t & 63;
      int col = n0 + n;
      Bs[k][n] = (col < Nc) ? B[(long)(k0 + k) * Nc + col] : 0.0f;
    }
    __syncthreads();
#pragma unroll
    for (int k = 0; k < 16; ++k) {
      float4 a = *reinterpret_cast<const float4*>(&As[k][ty * 4]);
      float4 b = *reinterpret_cast<const float4*>(&Bs[k][tx * 4]);
      float av[4] = {a.x, a.y, a.z, a.w};
      float bv[4] = {b.x, b.y, b.z, b.w};
#pragma unroll
      for (int i = 0; i < 4; ++i)
#pragma unroll
        for (int j = 0; j < 4; ++j) acc[i][j] += av[i] * bv[j];
    }
    __syncthreads();
  }
  for (int i = 0; i < 4; ++i) {
    int m = m0 + ty * 4 + i;
    for (int j = 0; j < 4; ++j) {
      int n = n0 + tx * 4 + j;
      if (n < Nc) {
        float v = acc[i][j];
        if (bias) v += bias[n];
        if (act == 1) v = fmaxf(v, 0.0f);
        C[(long)m * Nc + n] = v;
      }
    }
  }
}

// ---------------------------------------------------------------- f1/f2 (scaled by log2 e)
__global__ __launch_bounds__(256) void f1f2_kernel(const float* __restrict__ Wh,
                                                   const float* __restrict__ a,
                                                   float* __restrict__ f1,
                                                   float* __restrict__ f2,
                                                   int H, int Fp) {
  int g = blockIdx.x * 4 + (threadIdx.x >> 6);
  int lane = threadIdx.x & 63;
  if (g >= H * N_NODES) return;
  int h = g / N_NODES, n = g - h * N_NODES;
  int Ftot = H * Fp;
  const float* row = Wh + (long)n * Ftot + h * Fp;
  const float* av1 = a + h * 2 * Fp;
  const float* av2 = av1 + Fp;
  float s1 = 0.f, s2 = 0.f;
  for (int c = lane; c < Fp; c += 64) {
    float w = row[c];
    s1 += w * av1[c];
    s2 += w * av2[c];
  }
  for (int off = 32; off > 0; off >>= 1) {
    s1 += __shfl_down(s1, off);
    s2 += __shfl_down(s2, off);
  }
  if (lane == 0) { f1[g] = s1 * LOG2E; f2[g] = s2 * LOG2E; }
}

// ---------------------------------------------------------------- softmax stats (log2 domain)
__global__ __launch_bounds__(256) void stats_kernel(const float* __restrict__ f1,
                                                    const float* __restrict__ f2,
                                                    const unsigned int* __restrict__ bits,
                                                    float* __restrict__ brow,
                                                    int H) {
  int g = blockIdx.x * 4 + (threadIdx.x >> 6);
  int lane = threadIdx.x & 63;
  if (g >= H * N_NODES) return;
  int h = g / N_NODES, i = g - h * N_NODES;
  float fi = f1[g];
  const float* f2h = f2 + h * N_NODES;
  const unsigned int* br = bits + (long)i * MASK_WORDS;
  float m = -3.0e38f, l = 0.0f;
  for (int j = lane; j < N_NODES; j += 64) {
    unsigned int w = br[j >> 5];
    if ((w >> (j & 31)) & 1u) {
      float e = fi + f2h[j];
      e = fmaxf(e, 0.2f * e);
      if (e > m) {
        l = l * exp2f(m - e) + 1.0f;
        m = e;
      } else {
        l += exp2f(e - m);
      }
    }
  }
  for (int off = 1; off < 64; off <<= 1) {
    float m2 = __shfl_xor(m, off);
    float l2 = __shfl_xor(l, off);
    float mn = fmaxf(m, m2);
    l = l * exp2f(m - mn) + l2 * exp2f(m2 - mn);
    m = mn;
  }
  if (lane == 0) brow[g] = m + log2f(l);
}

// ---------------------------------------------------------------- transpose Wh -> WhT bf16
__global__ __launch_bounds__(256) void transpose_bf16_kernel(const float* __restrict__ A,
                                                             short* __restrict__ At,
                                                             int Ftot) {
  __shared__ short t[32][33];
  int c0 = blockIdx.x * 32, n0 = blockIdx.y * 32;
  int tx = threadIdx.x & 31, ty = threadIdx.x >> 5;
  for (int r = ty; r < 32; r += 8)
    t[tx][r] = f2bf(A[(size_t)(n0 + r) * Ftot + c0 + tx]);
  __syncthreads();
  for (int r = ty; r < 32; r += 8)
    At[(size_t)(c0 + r) * N_NODES + n0 + tx] = t[r][tx];
}

// ---------------------------------------------------------------- attention PV via MFMA
// Block = STRIPS*JSPLIT waves; wave (strip,jq) computes rows [i0+strip*16,+16) over
// j-range [jq*JQ_LEN, +JQ_LEN) for NF 16-col fragments. Mask words preloaded to
// registers in chunks of 12 (3x uint4). Partials reduced in LDS:
//   STRIPS==2 -> parallel red[JSPLIT][2][16][CPAD]
//   STRIPS==1 -> serialized rounds into red[16][CPAD] (LDS stays 24 KB)
// red aliases f2sh (f2sh dead after main loop).
template<int NF, int STRIPS, int JSPLIT>
__global__ __launch_bounds__(STRIPS * JSPLIT * 64)
void pv_mfma_kernel(const float* __restrict__ f1s,
                    const float* __restrict__ f2s,
                    const float* __restrict__ brow,
                    const unsigned int* __restrict__ bits,
                    const short* __restrict__ WhT,
                    float* __restrict__ out,
                    int H, int Fp, int act) {
  constexpr int WAVES   = STRIPS * JSPLIT;
  constexpr int THREADS = WAVES * 64;
  constexpr int JQ_LEN  = N_NODES / JSPLIT;
  constexpr int NSTEPS  = JQ_LEN / 32;
  constexpr int MCHUNK  = 12;
  constexpr int NCHUNKS = NSTEPS / MCHUNK;
  constexpr int ROWS    = STRIPS * 16;
  constexpr int CPAD    = NF * 16 + 4;
  constexpr bool PARRED = (STRIPS == 2);
  constexpr int REDQ    = PARRED ? JSPLIT : 1;
  constexpr int RED_FLOATS = REDQ * STRIPS * 16 * CPAD;
  constexpr int SH_FLOATS  = (RED_FLOATS > N_NODES) ? RED_FLOATS : N_NODES;
  constexpr int CSH = (NF == 2) ? 5 : (NF == 4) ? 6 : 7;   // log2(NF*16)

  __shared__ float shmem[SH_FLOATS];
  float* f2sh = shmem;

  int h = blockIdx.z;
  int i0 = blockIdx.y * ROWS;
  int cb0 = blockIdx.x * (NF * 16);
  int Ftot = H * Fp, hFp = h * Fp;
  int hN = h * N_NODES;
  int tid = threadIdx.x;
  int w = tid >> 6, l = tid & 63;
  int strip = (STRIPS == 2) ? (w & 1) : 0;
  int jq = (STRIPS == 2) ? (w >> 1) : w;
  int row_l = l & 15, grp = l >> 4;

  // stage f2 (vectorized)
  {
    const float4* src = reinterpret_cast<const float4*>(f2s + hN);
    float4* dst = reinterpret_cast<float4*>(f2sh);
    for (int idx = tid; idx < N_NODES / 4; idx += THREADS) dst[idx] = src[idx];
  }
  __syncthreads();

  int i = i0 + strip * 16 + row_l;
  float fi = f1s[hN + i];
  float bi = brow[hN + i];
  float c1 = fi - bi;
  float c2 = 0.2f * fi - bi;

  // mask words for this lane's row, this wave's j-range: contiguous
  const unsigned int* mbase = bits + (size_t)i * MASK_WORDS + jq * NSTEPS;

  // V fragment bases: uniform part in SGPRs, per-lane index in one VGPR
  size_t ub[NF];
#pragma unroll
  for (int n = 0; n < NF; ++n)
    ub[n] = (size_t)(hFp + cb0 + n * 16) * N_NODES;
  int vidx = row_l * N_NODES + grp * 8;

  f32x4 acc[NF];
#pragma unroll
  for (int n = 0; n < NF; ++n) acc[n] = f32x4{0, 0, 0, 0};

  int jbeg = jq * JQ_LEN;
#pragma unroll 1
  for (int ch = 0; ch < NCHUNKS; ++ch) {
    unsigned mw[MCHUNK];
    {
      const uint4* mp = reinterpret_cast<const uint4*>(mbase + ch * MCHUNK);
#pragma unroll
      for (int q = 0; q < MCHUNK / 4; ++q) {
        uint4 m = mp[q];
        mw[q * 4 + 0] = m.x; mw[q * 4 + 1] = m.y;
        mw[q * 4 + 2] = m.z; mw[q * 4 + 3] = m.w;
      }
    }
#pragma unroll
    for (int s = 0; s < MCHUNK; ++s) {
      int j0 = jbeg + (ch * MCHUNK + s) * 32;
      unsigned wb = (mw[s] >> (grp * 8)) & 0xffu;
      const float* fp = &f2sh[j0 + grp * 8];
      f32x4 fA = *reinterpret_cast<const f32x4*>(fp);
      f32x4 fB = *reinterpret_cast<const f32x4*>(fp + 4);
      float p[8];
#pragma unroll
      for (int e = 0; e < 8; ++e) {
        float f = (e < 4 ? fA[e] : fB[e - 4]);
        float t = fmaxf(f + c1, f * 0.2f + c2);
        t = ((wb >> e) & 1u) ? t : -1.0e30f;
        p[e] = exp2f(t);
      }
      union { short8 s8; unsigned u32[4]; } au;
#pragma unroll
      for (int ep = 0; ep < 4; ++ep) {
        unsigned ue = __builtin_bit_cast(unsigned, p[2 * ep]);
        unsigned uo = __builtin_bit_cast(unsigned, p[2 * ep + 1]);
        au.u32[ep] = (ue >> 16) | (uo & 0xffff0000u);   // truncation pack
      }
#pragma unroll
      for (int n = 0; n < NF; ++n) {
        short8 b = *reinterpret_cast<const short8*>(WhT + ub[n] + vidx + j0);
        acc[n] = __builtin_amdgcn_mfma_f32_16x16x32_bf16(au.s8, b, acc[n], 0, 0, 0);
      }
    }
  }

  // ---- reduce partials in LDS (aliases f2sh; f2sh dead now)
  __syncthreads();
  if (PARRED) {
#pragma unroll
    for (int n = 0; n < NF; ++n)
#pragma unroll
      for (int k = 0; k < 4; ++k)
        shmem[(((jq * STRIPS + strip) * 16) + grp * 4 + k) * CPAD + n * 16 + row_l] = acc[n][k];
    __syncthreads();
  } else {
#pragma unroll 1
    for (int r = 0; r < JSPLIT; ++r) {
      if (jq == r) {
#pragma unroll
        for (int n = 0; n < NF; ++n)
#pragma unroll
          for (int k = 0; k < 4; ++k) {
            int off = (grp * 4 + k) * CPAD + n * 16 + row_l;
            if (r == 0) shmem[off] = acc[n][k];
            else        shmem[off] += acc[n][k];
          }
      }
      __syncthreads();
    }
  }

  // ---- sum partials + activation + store (ROWS x NF*16)
  constexpr int TOTC = NF * 16;
  constexpr int TOT = ROWS * TOTC;
  for (int t = tid; t < TOT; t += THREADS) {
    int rr = t >> CSH, cc = t & (TOTC - 1);
    float v;
    if (PARRED) {
      v = 0.0f;
#pragma unroll
      for (int q = 0; q < REDQ; ++q)
        v += shmem[(((q * STRIPS + (rr >> 4)) * 16) + (rr & 15)) * CPAD + cc];
    } else {
      v = shmem[((rr & 15)) * CPAD + cc];
    }
    v = v > 0.0f ? v : exp2f(v * LOG2E) - 1.0f;            // elu
    if (act == 1) v = 1.0f / (1.0f + exp2f(-v * LOG2E));   // sigmoid(elu)
    out[(size_t)(i0 + rr) * Ftot + hFp + cb0 + cc] = v;
  }
}

// ---------------------------------------------------------------- host
extern "C" void kernel_launch(void* const* d_in, const int* in_sizes, int n_in,
                              void* d_out, int out_size, void* d_ws, size_t ws_size,
                              hipStream_t stream) {
  const float* x     = (const float*)d_in[0];
  const int*   adj   = (const int*)d_in[1];
  const float* W1    = (const float*)d_in[2];
  const float* a1    = (const float*)d_in[3];
  const float* Wo    = (const float*)d_in[4];
  const float* ao    = (const float*)d_in[5];
  const float* W2    = (const float*)d_in[6];
  const float* a2    = (const float*)d_in[7];
  const float* Wo2   = (const float*)d_in[8];
  const float* ao2   = (const float*)d_in[9];
  const float* lin_w = (const float*)d_in[10];
  const float* lin_b = (const float*)d_in[11];
  float* out = (float*)d_out;

  float* ws = (float*)d_ws;
  unsigned int* bits = (unsigned int*)ws;            // 1,179,648 u32
  float* Wh   = ws + 1179648;                        // 6144*256
  float* bufA = Wh + 1572864;
  float* bufB = bufA + 1572864;
  float* Bcat = bufB + 1572864;                      // 65536
  float* f1   = Bcat + 65536;                        // 24576
  float* f2   = f1 + 24576;
  float* brow = f2 + 24576;
  short* WhT  = (short*)(brow + 24576);              // 6144*256 bf16

  dim3 b256(256);
  dim3 b512(512);

  bitpack_kernel<<<N_NODES, b256, 0, stream>>>(adj, bits);

  // ================= layer 1 multi-head (H=4, Fp=64), elu concat
  repack_W_kernel<<<(4 * 256 * 64 + 255) / 256, b256, 0, stream>>>(W1, Bcat, 4, 256, 64);
  gemm_kernel<<<dim3(4, 96), b256, 0, stream>>>(x, Bcat, Wh, 256, 256, nullptr, 0);
  f1f2_kernel<<<(4 * N_NODES) / 4, b256, 0, stream>>>(Wh, a1, f1, f2, 4, 64);
  transpose_bf16_kernel<<<dim3(8, 192), b256, 0, stream>>>(Wh, WhT, 256);
  stats_kernel<<<(4 * N_NODES) / 4, b256, 0, stream>>>(f1, f2, bits, brow, 4);
  pv_mfma_kernel<4, 2, 4><<<dim3(1, 192, 4), b512, 0, stream>>>(f1, f2, brow, bits, WhT, bufA, 4, 64, 0);

  // ================= out-attention 1 (H=1, Fp=256), sigmoid(elu)
  gemm_kernel<<<dim3(4, 96), b256, 0, stream>>>(bufA, Wo, Wh, 256, 256, nullptr, 0);
  f1f2_kernel<<<(N_NODES) / 4, b256, 0, stream>>>(Wh, ao, f1, f2, 1, 256);
  transpose_bf16_kernel<<<dim3(8, 192), b256, 0, stream>>>(Wh, WhT, 256);
  stats_kernel<<<(N_NODES) / 4, b256, 0, stream>>>(f1, f2, bits, brow, 1);
  pv_mfma_kernel<8, 1, 8><<<dim3(2, 384, 1), b512, 0, stream>>>(f1, f2, brow, bits, WhT, bufB, 1, 256, 1);

  // ================= layer 2 multi-head (H=4, Fp=32), elu concat
  repack_W_kernel<<<(4 * 256 * 32 + 255) / 256, b256, 0, stream>>>(W2, Bcat, 4, 256, 32);
  gemm_kernel<<<dim3(2, 96), b256, 0, stream>>>(bufB, Bcat, Wh, 256, 128, nullptr, 0);
  f1f2_kernel<<<(4 * N_NODES) / 4, b256, 0, stream>>>(Wh, a2, f1, f2, 4, 32);
  transpose_bf16_kernel<<<dim3(4, 192), b256, 0, stream>>>(Wh, WhT, 128);
  stats_kernel<<<(4 * N_NODES) / 4, b256, 0, stream>>>(f1, f2, bits, brow, 4);
  pv_mfma_kernel<2, 2, 4><<<dim3(1, 192, 4), b512, 0, stream>>>(f1, f2, brow, bits, WhT, bufA, 4, 32, 0);

  // ================= out-attention 2 (H=1, Fp=128), sigmoid(elu)
  gemm_kernel<<<dim3(2, 96), b256, 0, stream>>>(bufA, Wo2, Wh, 128, 128, nullptr, 0);
  f1f2_kernel<<<(N_NODES) / 4, b256, 0, stream>>>(Wh, ao2, f1, f2, 1, 128);
  transpose_bf16_kernel<<<dim3(4, 192), b256, 0, stream>>>(Wh, WhT, 128);
  stats_kernel<<<(N_NODES) / 4, b256, 0, stream>>>(f1, f2, bits, brow, 1);
  pv_mfma_kernel<8, 1, 8><<<dim3(1, 384, 1), b512, 0, stream>>>(f1, f2, brow, bits, WhT, bufB, 1, 128, 1);

  // ================= final linear + relu
  gemm_kernel<<<dim3(6, 96), b256, 0, stream>>>(bufB, lin_w, out, 128, 379, lin_b, 1);
}

// Round 8
// 875.395 us; speedup vs baseline: 3.8629x; 1.2140x over previous
//
#include <hip/hip_runtime.h>
#include <hip/hip_bf16.h>

#define N_NODES 6144
#define MASK_WORDS 192  // 6144/32
#define LOG2E 1.44269504088896f

using short8 = __attribute__((ext_vector_type(8))) short;
using f32x4  = __attribute__((ext_vector_type(4))) float;

// f32 -> bf16 bits, round-to-nearest-even (setup-path quality)
__device__ inline unsigned f2bf_u(float f) {
  unsigned u = __builtin_bit_cast(unsigned, f);
  u += 0x7fff + ((u >> 16) & 1);
  return u >> 16;
}
__device__ inline short f2bf(float f) { return (short)f2bf_u(f); }

// ---------------------------------------------------------------- bitpack
__global__ __launch_bounds__(256) void bitpack_kernel(const int* __restrict__ adj,
                                                      unsigned int* __restrict__ bits) {
  int row = blockIdx.x;
  int wave = threadIdx.x >> 6, lane = threadIdx.x & 63;
  const int* p = adj + (long)row * N_NODES;
  for (int base = wave * 64; base < N_NODES; base += 256) {
    unsigned long long m = __ballot(p[base + lane] > 0);
    if (lane == 0) {
      bits[row * MASK_WORDS + (base >> 5)] = (unsigned int)m;
      bits[row * MASK_WORDS + (base >> 5) + 1] = (unsigned int)(m >> 32);
    }
  }
}

// ---------------------------------------------------------------- W repack
// W [H][Fin][Fp] -> B [Fin][H*Fp]
__global__ __launch_bounds__(256) void repack_W_kernel(const float* __restrict__ W,
                                                       float* __restrict__ B,
                                                       int H, int Fin, int Fp) {
  int idx = blockIdx.x * blockDim.x + threadIdx.x;
  int total = H * Fin * Fp;
  if (idx >= total) return;
  int h = idx / (Fin * Fp);
  int rem = idx - h * (Fin * Fp);
  int k = rem / Fp, c = rem - k * Fp;
  B[k * (H * Fp) + h * Fp + c] = W[idx];
}

// ---------------------------------------------------------------- GEMM (fp32)
__global__ __launch_bounds__(256) void gemm_kernel(const float* __restrict__ A,
                                                   const float* __restrict__ B,
                                                   float* __restrict__ C,
                                                   int K, int Nc,
                                                   const float* __restrict__ bias,
                                                   int act) {
  __shared__ float As[16][68];
  __shared__ float Bs[16][68];
  int tx = threadIdx.x & 15, ty = threadIdx.x >> 4;
  int m0 = blockIdx.y * 64, n0 = blockIdx.x * 64;
  float acc[4][4] = {};
  for (int k0 = 0; k0 < K; k0 += 16) {
    for (int t = threadIdx.x; t < 1024; t += 256) {
      int k = t & 15, m = t >> 4;
      As[k][m] = A[(long)(m0 + m) * K + k0 + k];
    }
    for (int t = threadIdx.x; t < 1024; t += 256) {
      int k = t >> 6, n = t & 63;
      int col = n0 + n;
      Bs[k][n] = (col < Nc) ? B[(long)(k0 + k) * Nc + col] : 0.0f;
    }
    __syncthreads();
#pragma unroll
    for (int k = 0; k < 16; ++k) {
      float4 a = *reinterpret_cast<const float4*>(&As[k][ty * 4]);
      float4 b = *reinterpret_cast<const float4*>(&Bs[k][tx * 4]);
      float av[4] = {a.x, a.y, a.z, a.w};
      float bv[4] = {b.x, b.y, b.z, b.w};
#pragma unroll
      for (int i = 0; i < 4; ++i)
#pragma unroll
        for (int j = 0; j < 4; ++j) acc[i][j] += av[i] * bv[j];
    }
    __syncthreads();
  }
  for (int i = 0; i < 4; ++i) {
    int m = m0 + ty * 4 + i;
    for (int j = 0; j < 4; ++j) {
      int n = n0 + tx * 4 + j;
      if (n < Nc) {
        float v = acc[i][j];
        if (bias) v += bias[n];
        if (act == 1) v = fmaxf(v, 0.0f);
        C[(long)m * Nc + n] = v;
      }
    }
  }
}

// ---------------------------------------------------------------- f1/f2 (scaled by log2 e)
__global__ __launch_bounds__(256) void f1f2_kernel(const float* __restrict__ Wh,
                                                   const float* __restrict__ a,
                                                   float* __restrict__ f1,
                                                   float* __restrict__ f2,
                                                   int H, int Fp) {
  int g = blockIdx.x * 4 + (threadIdx.x >> 6);
  int lane = threadIdx.x & 63;
  if (g >= H * N_NODES) return;
  int h = g / N_NODES, n = g - h * N_NODES;
  int Ftot = H * Fp;
  const float* row = Wh + (long)n * Ftot + h * Fp;
  const float* av1 = a + h * 2 * Fp;
  const float* av2 = av1 + Fp;
  float s1 = 0.f, s2 = 0.f;
  for (int c = lane; c < Fp; c += 64) {
    float w = row[c];
    s1 += w * av1[c];
    s2 += w * av2[c];
  }
  for (int off = 32; off > 0; off >>= 1) {
    s1 += __shfl_down(s1, off);
    s2 += __shfl_down(s2, off);
  }
  if (lane == 0) { f1[g] = s1 * LOG2E; f2[g] = s2 * LOG2E; }
}

// ---------------------------------------------------------------- softmax stats (log2 domain)
__global__ __launch_bounds__(256) void stats_kernel(const float* __restrict__ f1,
                                                    const float* __restrict__ f2,
                                                    const unsigned int* __restrict__ bits,
                                                    float* __restrict__ brow,
                                                    int H) {
  int g = blockIdx.x * 4 + (threadIdx.x >> 6);
  int lane = threadIdx.x & 63;
  if (g >= H * N_NODES) return;
  int h = g / N_NODES, i = g - h * N_NODES;
  float fi = f1[g];
  const float* f2h = f2 + h * N_NODES;
  const unsigned int* br = bits + (long)i * MASK_WORDS;
  float m = -3.0e38f, l = 0.0f;
  for (int j = lane; j < N_NODES; j += 64) {
    unsigned int w = br[j >> 5];
    if ((w >> (j & 31)) & 1u) {
      float e = fi + f2h[j];
      e = fmaxf(e, 0.2f * e);
      if (e > m) {
        l = l * exp2f(m - e) + 1.0f;
        m = e;
      } else {
        l += exp2f(e - m);
      }
    }
  }
  for (int off = 1; off < 64; off <<= 1) {
    float m2 = __shfl_xor(m, off);
    float l2 = __shfl_xor(l, off);
    float mn = fmaxf(m, m2);
    l = l * exp2f(m - mn) + l2 * exp2f(m2 - mn);
    m = mn;
  }
  if (lane == 0) brow[g] = m + log2f(l);
}

// ---------------------------------------------------------------- transpose Wh -> WhT bf16
__global__ __launch_bounds__(256) void transpose_bf16_kernel(const float* __restrict__ A,
                                                             short* __restrict__ At,
                                                             int Ftot) {
  __shared__ short t[32][33];
  int c0 = blockIdx.x * 32, n0 = blockIdx.y * 32;
  int tx = threadIdx.x & 31, ty = threadIdx.x >> 5;
  for (int r = ty; r < 32; r += 8)
    t[tx][r] = f2bf(A[(size_t)(n0 + r) * Ftot + c0 + tx]);
  __syncthreads();
  for (int r = ty; r < 32; r += 8)
    At[(size_t)(c0 + r) * N_NODES + n0 + tx] = t[r][tx];
}

// ---------------------------------------------------------------- attention PV, LDS-staged V
// Block: 256 thr = 4 waves = 4 row-strips (64 rows) x NF*16 cols, j-chunk of N/JC.
// Per 64-j step: cooperatively stage V tile (coalesced global -> LDS), then each wave
// computes P in-reg and MFMAs from ds_read_b128 fragments. Partial sums are
// atomicAdd'ed (f32) into a pre-zeroed accumulator; activation applied by act_kernel.
// grid: (Fp/(NF*16), 96*JC, H); blockIdx.y: rb = y%96, jc = y/96.
template<int NF, int JC>
__global__ __launch_bounds__(256)
void pv_stage_kernel(const float* __restrict__ f1s,
                     const float* __restrict__ f2s,
                     const float* __restrict__ brow,
                     const unsigned int* __restrict__ bits,
                     const short* __restrict__ WhT,
                     float* __restrict__ out,
                     int H, int Fp) {
  constexpr int CH = N_NODES / JC;     // j-chunk length
  constexpr int NCH = CH / 384;        // outer chunks (12 mask words = 384 j each)
  constexpr int COLS = NF * 16;
  static_assert(NCH * 384 == CH, "chunking");

  __shared__ float f2sh[CH];
  __shared__ short Vt[COLS][72];       // 144 B stride: 16-B aligned, bank-even

  int h = blockIdx.z;
  int cb0 = blockIdx.x * COLS;
  int rb = blockIdx.y % 96;
  int jc = blockIdx.y / 96;
  int i0 = rb * 64;
  int hN = h * N_NODES, hFp = h * Fp;
  int Ftot = H * Fp;
  int tid = threadIdx.x;
  int w = tid >> 6, l = tid & 63;
  int row_l = l & 15, grp = l >> 4;

  // stage f2 chunk
  {
    const float4* src = reinterpret_cast<const float4*>(f2s + hN + jc * CH);
    float4* dst = reinterpret_cast<float4*>(f2sh);
    for (int idx = tid; idx < CH / 4; idx += 256) dst[idx] = src[idx];
  }

  int i = i0 + w * 16 + row_l;
  float fi = f1s[hN + i];
  float bi = brow[hN + i];
  float c1 = fi - bi;
  float c2 = 0.2f * fi - bi;
  const unsigned int* mbase = bits + (size_t)i * MASK_WORDS + jc * (CH / 32);

  int vcol = hFp + cb0;
  const short* Wbase = WhT + (size_t)vcol * N_NODES;

  f32x4 acc[NF];
#pragma unroll
  for (int n = 0; n < NF; ++n) acc[n] = f32x4{0, 0, 0, 0};

#pragma unroll 1
  for (int ch = 0; ch < NCH; ++ch) {
    unsigned mw[12];
    {
      const uint4* mp = reinterpret_cast<const uint4*>(mbase + ch * 12);
#pragma unroll
      for (int q = 0; q < 3; ++q) {
        uint4 m = mp[q];
        mw[q * 4 + 0] = m.x; mw[q * 4 + 1] = m.y;
        mw[q * 4 + 2] = m.z; mw[q * 4 + 3] = m.w;
      }
    }
#pragma unroll 1
    for (int ss = 0; ss < 6; ++ss) {
      int j0 = jc * CH + ch * 384 + ss * 64;   // global j of this 64-tile
      __syncthreads();                         // Vt free (prev step's reads done)
#pragma unroll
      for (int idx = tid; idx < COLS * 8; idx += 256) {
        int c = idx >> 3, sl = idx & 7;
        *reinterpret_cast<short8*>(&Vt[c][sl * 8]) =
            *reinterpret_cast<const short8*>(Wbase + (size_t)c * N_NODES + j0 + sl * 8);
      }
      __syncthreads();                         // Vt ready
#pragma unroll
      for (int hh = 0; hh < 2; ++hh) {
        unsigned wb = (mw[ss * 2 + hh] >> (grp * 8)) & 0xffu;
        int jrel = ch * 384 + ss * 64 + hh * 32 + grp * 8;
        f32x4 fA = *reinterpret_cast<const f32x4*>(&f2sh[jrel]);
        f32x4 fB = *reinterpret_cast<const f32x4*>(&f2sh[jrel + 4]);
        float p[8];
#pragma unroll
        for (int e = 0; e < 8; ++e) {
          float f = (e < 4 ? fA[e] : fB[e - 4]);
          float t = fmaxf(f + c1, f * 0.2f + c2);
          t = ((wb >> e) & 1u) ? t : -1.0e30f;
          p[e] = exp2f(t);
        }
        union { short8 s8; unsigned u32[4]; } au;
#pragma unroll
        for (int ep = 0; ep < 4; ++ep) {
          unsigned ue = __builtin_bit_cast(unsigned, p[2 * ep]);
          unsigned uo = __builtin_bit_cast(unsigned, p[2 * ep + 1]);
          au.u32[ep] = (ue >> 16) | (uo & 0xffff0000u);   // truncation pack
        }
#pragma unroll
        for (int n = 0; n < NF; ++n) {
          short8 b = *reinterpret_cast<const short8*>(&Vt[n * 16 + row_l][hh * 32 + grp * 8]);
          acc[n] = __builtin_amdgcn_mfma_f32_16x16x32_bf16(au.s8, b, acc[n], 0, 0, 0);
        }
      }
    }
  }

  // atomics: C/D layout col=lane&15, row=grp*4+reg
#pragma unroll
  for (int n = 0; n < NF; ++n) {
#pragma unroll
    for (int k = 0; k < 4; ++k) {
      int r = i0 + w * 16 + grp * 4 + k;
      atomicAdd(&out[(size_t)r * Ftot + vcol + n * 16 + row_l], acc[n][k]);
    }
  }
}

// ---------------------------------------------------------------- activation epilogue
// act: 0 = elu, 1 = sigmoid(elu)
__global__ __launch_bounds__(256) void act_kernel(float* __restrict__ buf, int n4, int act) {
  int idx = blockIdx.x * blockDim.x + threadIdx.x;
  if (idx >= n4) return;
  float4 v = reinterpret_cast<float4*>(buf)[idx];
  float vv[4] = {v.x, v.y, v.z, v.w};
#pragma unroll
  for (int e = 0; e < 4; ++e) {
    float x = vv[e];
    x = x > 0.0f ? x : exp2f(x * LOG2E) - 1.0f;
    if (act == 1) x = 1.0f / (1.0f + exp2f(-x * LOG2E));
    vv[e] = x;
  }
  reinterpret_cast<float4*>(buf)[idx] = make_float4(vv[0], vv[1], vv[2], vv[3]);
}

// ---------------------------------------------------------------- host
extern "C" void kernel_launch(void* const* d_in, const int* in_sizes, int n_in,
                              void* d_out, int out_size, void* d_ws, size_t ws_size,
                              hipStream_t stream) {
  const float* x     = (const float*)d_in[0];
  const int*   adj   = (const int*)d_in[1];
  const float* W1    = (const float*)d_in[2];
  const float* a1    = (const float*)d_in[3];
  const float* Wo    = (const float*)d_in[4];
  const float* ao    = (const float*)d_in[5];
  const float* W2    = (const float*)d_in[6];
  const float* a2    = (const float*)d_in[7];
  const float* Wo2   = (const float*)d_in[8];
  const float* ao2   = (const float*)d_in[9];
  const float* lin_w = (const float*)d_in[10];
  const float* lin_b = (const float*)d_in[11];
  float* out = (float*)d_out;

  float* ws = (float*)d_ws;
  unsigned int* bits = (unsigned int*)ws;            // 1,179,648 u32
  float* Wh   = ws + 1179648;                        // 6144*256
  float* bufA = Wh + 1572864;
  float* bufB = bufA + 1572864;
  float* Bcat = bufB + 1572864;                      // 65536
  float* f1   = Bcat + 65536;                        // 24576
  float* f2   = f1 + 24576;
  float* brow = f2 + 24576;
  short* WhT  = (short*)(brow + 24576);              // 6144*256 bf16

  dim3 b256(256);

  bitpack_kernel<<<N_NODES, b256, 0, stream>>>(adj, bits);

  // ================= layer 1 multi-head (H=4, Fp=64), elu concat
  repack_W_kernel<<<(4 * 256 * 64 + 255) / 256, b256, 0, stream>>>(W1, Bcat, 4, 256, 64);
  gemm_kernel<<<dim3(4, 96), b256, 0, stream>>>(x, Bcat, Wh, 256, 256, nullptr, 0);
  f1f2_kernel<<<(4 * N_NODES) / 4, b256, 0, stream>>>(Wh, a1, f1, f2, 4, 64);
  transpose_bf16_kernel<<<dim3(8, 192), b256, 0, stream>>>(Wh, WhT, 256);
  stats_kernel<<<(4 * N_NODES) / 4, b256, 0, stream>>>(f1, f2, bits, brow, 4);
  hipMemsetAsync(bufA, 0, (size_t)6144 * 256 * 4, stream);
  pv_stage_kernel<4, 2><<<dim3(1, 192, 4), b256, 0, stream>>>(f1, f2, brow, bits, WhT, bufA, 4, 64);
  act_kernel<<<dim3(1536), b256, 0, stream>>>(bufA, 6144 * 256 / 4, 0);

  // ================= out-attention 1 (H=1, Fp=256), sigmoid(elu)
  gemm_kernel<<<dim3(4, 96), b256, 0, stream>>>(bufA, Wo, Wh, 256, 256, nullptr, 0);
  f1f2_kernel<<<(N_NODES) / 4, b256, 0, stream>>>(Wh, ao, f1, f2, 1, 256);
  transpose_bf16_kernel<<<dim3(8, 192), b256, 0, stream>>>(Wh, WhT, 256);
  stats_kernel<<<(N_NODES) / 4, b256, 0, stream>>>(f1, f2, bits, brow, 1);
  hipMemsetAsync(bufB, 0, (size_t)6144 * 256 * 4, stream);
  pv_stage_kernel<8, 4><<<dim3(2, 384, 1), b256, 0, stream>>>(f1, f2, brow, bits, WhT, bufB, 1, 256);
  act_kernel<<<dim3(1536), b256, 0, stream>>>(bufB, 6144 * 256 / 4, 1);

  // ================= layer 2 multi-head (H=4, Fp=32), elu concat
  repack_W_kernel<<<(4 * 256 * 32 + 255) / 256, b256, 0, stream>>>(W2, Bcat, 4, 256, 32);
  gemm_kernel<<<dim3(2, 96), b256, 0, stream>>>(bufB, Bcat, Wh, 256, 128, nullptr, 0);
  f1f2_kernel<<<(4 * N_NODES) / 4, b256, 0, stream>>>(Wh, a2, f1, f2, 4, 32);
  transpose_bf16_kernel<<<dim3(4, 192), b256, 0, stream>>>(Wh, WhT, 128);
  stats_kernel<<<(4 * N_NODES) / 4, b256, 0, stream>>>(f1, f2, bits, brow, 4);
  hipMemsetAsync(bufA, 0, (size_t)6144 * 128 * 4, stream);
  pv_stage_kernel<2, 2><<<dim3(1, 192, 4), b256, 0, stream>>>(f1, f2, brow, bits, WhT, bufA, 4, 32);
  act_kernel<<<dim3(768), b256, 0, stream>>>(bufA, 6144 * 128 / 4, 0);

  // ================= out-attention 2 (H=1, Fp=128), sigmoid(elu)
  gemm_kernel<<<dim3(2, 96), b256, 0, stream>>>(bufA, Wo2, Wh, 128, 128, nullptr, 0);
  f1f2_kernel<<<(N_NODES) / 4, b256, 0, stream>>>(Wh, ao2, f1, f2, 1, 128);
  transpose_bf16_kernel<<<dim3(4, 192), b256, 0, stream>>>(Wh, WhT, 128);
  stats_kernel<<<(N_NODES) / 4, b256, 0, stream>>>(f1, f2, bits, brow, 1);
  hipMemsetAsync(bufB, 0, (size_t)6144 * 128 * 4, stream);
  pv_stage_kernel<8, 8><<<dim3(1, 768, 1), b256, 0, stream>>>(f1, f2, brow, bits, WhT, bufB, 1, 128);
  act_kernel<<<dim3(768), b256, 0, stream>>>(bufB, 6144 * 128 / 4, 1);

  // ================= final linear + relu
  gemm_kernel<<<dim3(6, 96), b256, 0, stream>>>(bufB, lin_w, out, 128, 379, lin_b, 1);
}

// Round 10
// 467.707 us; speedup vs baseline: 7.2302x; 1.8717x over previous
//
#include <hip/hip_runtime.h>
#include <hip/hip_bf16.h>

#define N_NODES 6144
#define MASK_WORDS 192  // 6144/32
#define LOG2E 1.44269504088896f

using short8 = __attribute__((ext_vector_type(8))) short;
using s16x4  = __attribute__((ext_vector_type(4))) short;
using f32x4  = __attribute__((ext_vector_type(4))) float;

// f32 -> bf16 bits, round-to-nearest-even
__device__ inline unsigned f2bf_u(float f) {
  unsigned u = __builtin_bit_cast(unsigned, f);
  u += 0x7fff + ((u >> 16) & 1);
  return u >> 16;
}
__device__ inline short f2bf(float f) { return (short)f2bf_u(f); }

// ---------------------------------------------------------------- bitpack
__global__ __launch_bounds__(256) void bitpack_kernel(const int* __restrict__ adj,
                                                      unsigned int* __restrict__ bits) {
  int row = blockIdx.x;
  int wave = threadIdx.x >> 6, lane = threadIdx.x & 63;
  const int* p = adj + (long)row * N_NODES;
  for (int base = wave * 64; base < N_NODES; base += 256) {
    unsigned long long m = __ballot(p[base + lane] > 0);
    if (lane == 0) {
      bits[row * MASK_WORDS + (base >> 5)] = (unsigned int)m;
      bits[row * MASK_WORDS + (base >> 5) + 1] = (unsigned int)(m >> 32);
    }
  }
}

// ---------------------------------------------------------------- W repack
// W [H][Fin][Fp] -> B [Fin][H*Fp]
__global__ __launch_bounds__(256) void repack_W_kernel(const float* __restrict__ W,
                                                       float* __restrict__ B,
                                                       int H, int Fin, int Fp) {
  int idx = blockIdx.x * blockDim.x + threadIdx.x;
  int total = H * Fin * Fp;
  if (idx >= total) return;
  int h = idx / (Fin * Fp);
  int rem = idx - h * (Fin * Fp);
  int k = rem / Fp, c = rem - k * Fp;
  B[k * (H * Fp) + h * Fp + c] = W[idx];
}

// ---------------------------------------------------------------- weight transpose+cvt
// B [K][Nc] f32 -> Bt [NcPad][K] bf16 (zero-fill cols >= Nc). grid (K/32, NcPad/32)
__global__ __launch_bounds__(256) void transpose_w_kernel(const float* __restrict__ B,
                                                          short* __restrict__ Bt,
                                                          int K, int Nc) {
  __shared__ short t[32][33];
  int k0 = blockIdx.x * 32, c0 = blockIdx.y * 32;
  int tx = threadIdx.x & 31, ty = threadIdx.x >> 5;
  for (int r = ty; r < 32; r += 8) {
    float v = (c0 + tx < Nc) ? B[(size_t)(k0 + r) * Nc + c0 + tx] : 0.0f;
    t[tx][r] = f2bf(v);
  }
  __syncthreads();
  for (int r = ty; r < 32; r += 8)
    Bt[(size_t)(c0 + r) * K + k0 + tx] = t[r][tx];
}

// ---------------------------------------------------------------- MFMA GEMM
// C[M,Nc] f32 = A[M,K] f32 @ Bt[NcPad][K] bf16 (+bias, act 1 = relu).
// Block 256 = 4 waves; tile 64x64; K-step 32; A converted to bf16 at staging.
__global__ __launch_bounds__(256) void gemm_mfma_kernel(const float* __restrict__ A,
                                                        const short* __restrict__ Bt,
                                                        float* __restrict__ C,
                                                        int K, int Nc,
                                                        const float* __restrict__ bias,
                                                        int act) {
  __shared__ short As[64][40];
  __shared__ short Bs[64][40];
  int m0 = blockIdx.y * 64, n0 = blockIdx.x * 64;
  int tid = threadIdx.x;
  int w = tid >> 6, l = tid & 63, row_l = l & 15, grp = l >> 4;

  f32x4 acc[4] = {f32x4{0,0,0,0}, f32x4{0,0,0,0}, f32x4{0,0,0,0}, f32x4{0,0,0,0}};

  for (int k0 = 0; k0 < K; k0 += 32) {
    __syncthreads();
#pragma unroll
    for (int s = 0; s < 2; ++s) {
      int idx = tid + s * 256;
      int r = idx >> 3, q = idx & 7;
      float4 v = *reinterpret_cast<const float4*>(&A[(size_t)(m0 + r) * K + k0 + q * 4]);
      s16x4 sv = {f2bf(v.x), f2bf(v.y), f2bf(v.z), f2bf(v.w)};
      *reinterpret_cast<s16x4*>(&As[r][q * 4]) = sv;
    }
    {
      int c = tid >> 2, kq = tid & 3;
      *reinterpret_cast<short8*>(&Bs[c][kq * 8]) =
          *reinterpret_cast<const short8*>(&Bt[(size_t)(n0 + c) * K + k0 + kq * 8]);
    }
    __syncthreads();
    short8 a = *reinterpret_cast<const short8*>(&As[w * 16 + row_l][grp * 8]);
#pragma unroll
    for (int n = 0; n < 4; ++n) {
      short8 b = *reinterpret_cast<const short8*>(&Bs[n * 16 + row_l][grp * 8]);
      acc[n] = __builtin_amdgcn_mfma_f32_16x16x32_bf16(a, b, acc[n], 0, 0, 0);
    }
  }

#pragma unroll
  for (int n = 0; n < 4; ++n) {
#pragma unroll
    for (int k = 0; k < 4; ++k) {
      int row = m0 + w * 16 + grp * 4 + k;
      int col = n0 + n * 16 + row_l;
      if (col < Nc) {
        float v = acc[n][k];
        if (bias) v += bias[col];
        if (act == 1) v = fmaxf(v, 0.0f);
        C[(size_t)row * Nc + col] = v;
      }
    }
  }
}

// ---------------------------------------------------------------- f1/f2 (scaled by log2 e)
__global__ __launch_bounds__(256) void f1f2_kernel(const float* __restrict__ Wh,
                                                   const float* __restrict__ a,
                                                   float* __restrict__ f1,
                                                   float* __restrict__ f2,
                                                   int H, int Fp) {
  int g = blockIdx.x * 4 + (threadIdx.x >> 6);
  int lane = threadIdx.x & 63;
  if (g >= H * N_NODES) return;
  int h = g / N_NODES, n = g - h * N_NODES;
  int Ftot = H * Fp;
  const float* row = Wh + (long)n * Ftot + h * Fp;
  const float* av1 = a + h * 2 * Fp;
  const float* av2 = av1 + Fp;
  float s1 = 0.f, s2 = 0.f;
  for (int c = lane; c < Fp; c += 64) {
    float w = row[c];
    s1 += w * av1[c];
    s2 += w * av2[c];
  }
  for (int off = 32; off > 0; off >>= 1) {
    s1 += __shfl_down(s1, off);
    s2 += __shfl_down(s2, off);
  }
  if (lane == 0) { f1[g] = s1 * LOG2E; f2[g] = s2 * LOG2E; }
}

// ---------------------------------------------------------------- per-head global max of f2
__global__ __launch_bounds__(256) void gmax_kernel(const float* __restrict__ f2s,
                                                   float* __restrict__ gmax) {
  __shared__ float red[4];
  int h = blockIdx.x;
  int tid = threadIdx.x, lane = tid & 63, w = tid >> 6;
  const float* p = f2s + h * N_NODES;
  float m = -3.0e38f;
  for (int j = tid; j < N_NODES; j += 256) m = fmaxf(m, p[j]);
  for (int off = 32; off > 0; off >>= 1) m = fmaxf(m, __shfl_xor(m, off));
  if (lane == 0) red[w] = m;
  __syncthreads();
  if (tid == 0) gmax[h] = fmaxf(fmaxf(red[0], red[1]), fmaxf(red[2], red[3]));
}

// ---------------------------------------------------------------- transpose Wh -> WhT bf16
__global__ __launch_bounds__(256) void transpose_bf16_kernel(const float* __restrict__ A,
                                                             short* __restrict__ At,
                                                             int Ftot) {
  __shared__ short t[32][33];
  int c0 = blockIdx.x * 32, n0 = blockIdx.y * 32;
  int tx = threadIdx.x & 31, ty = threadIdx.x >> 5;
  for (int r = ty; r < 32; r += 8)
    t[tx][r] = f2bf(A[(size_t)(n0 + r) * Ftot + c0 + tx]);
  __syncthreads();
  for (int r = ty; r < 32; r += 8)
    At[(size_t)(c0 + r) * N_NODES + n0 + tx] = t[r][tx];
}

// ---------------------------------------------------------------- attention PV, LDS-staged V
// P = exp2(LR(f1s_i + f2s_j) - m_i), m_i = LR(f1s_i + gmax_h) >= masked row max.
// l_i accumulated via one extra MFMA with all-ones B fragment -> atomicAdd lsum.
// Unnormalized O atomicAdd'ed; act_kernel divides by lsum and applies activation.
template<int NF, int JC>
__global__ __launch_bounds__(256)
void pv_stage_kernel(const float* __restrict__ f1s,
                     const float* __restrict__ f2s,
                     const float* __restrict__ gmax,
                     const unsigned int* __restrict__ bits,
                     const short* __restrict__ WhT,
                     float* __restrict__ out,
                     float* __restrict__ lsum,
                     int H, int Fp) {
  constexpr int CH = N_NODES / JC;
  constexpr int NCH = CH / 384;
  constexpr int COLS = NF * 16;
  static_assert(NCH * 384 == CH, "chunking");

  __shared__ float f2sh[CH];
  __shared__ short Vt[COLS][72];

  int h = blockIdx.z;
  int cb0 = blockIdx.x * COLS;
  int rb = blockIdx.y % 96;
  int jc = blockIdx.y / 96;
  int i0 = rb * 64;
  int hN = h * N_NODES, hFp = h * Fp;
  int Ftot = H * Fp;
  int tid = threadIdx.x;
  int w = tid >> 6, l = tid & 63;
  int row_l = l & 15, grp = l >> 4;

  {
    const float4* src = reinterpret_cast<const float4*>(f2s + hN + jc * CH);
    float4* dst = reinterpret_cast<float4*>(f2sh);
    for (int idx = tid; idx < CH / 4; idx += 256) dst[idx] = src[idx];
  }

  int i = i0 + w * 16 + row_l;
  float fi = f1s[hN + i];
  float gm = gmax[h];
  float mi = fmaxf(fi + gm, 0.2f * (fi + gm));
  float c1 = fi - mi;
  float c2 = 0.2f * fi - mi;
  const unsigned int* mbase = bits + (size_t)i * MASK_WORDS + jc * (CH / 32);

  int vcol = hFp + cb0;
  const short* Wbase = WhT + (size_t)vcol * N_NODES;

  const short ONE = (short)0x3F80;
  short8 ones8 = {ONE, ONE, ONE, ONE, ONE, ONE, ONE, ONE};

  f32x4 acc[NF];
#pragma unroll
  for (int n = 0; n < NF; ++n) acc[n] = f32x4{0, 0, 0, 0};
  f32x4 accl = f32x4{0, 0, 0, 0};

#pragma unroll 1
  for (int ch = 0; ch < NCH; ++ch) {
    unsigned mw[12];
    {
      const uint4* mp = reinterpret_cast<const uint4*>(mbase + ch * 12);
#pragma unroll
      for (int q = 0; q < 3; ++q) {
        uint4 m = mp[q];
        mw[q * 4 + 0] = m.x; mw[q * 4 + 1] = m.y;
        mw[q * 4 + 2] = m.z; mw[q * 4 + 3] = m.w;
      }
    }
#pragma unroll 1
    for (int ss = 0; ss < 6; ++ss) {
      int j0 = jc * CH + ch * 384 + ss * 64;
      __syncthreads();
#pragma unroll
      for (int idx = tid; idx < COLS * 8; idx += 256) {
        int c = idx >> 3, sl = idx & 7;
        *reinterpret_cast<short8*>(&Vt[c][sl * 8]) =
            *reinterpret_cast<const short8*>(Wbase + (size_t)c * N_NODES + j0 + sl * 8);
      }
      __syncthreads();
#pragma unroll
      for (int hh = 0; hh < 2; ++hh) {
        unsigned wb = (mw[ss * 2 + hh] >> (grp * 8)) & 0xffu;
        int jrel = ch * 384 + ss * 64 + hh * 32 + grp * 8;
        f32x4 fA = *reinterpret_cast<const f32x4*>(&f2sh[jrel]);
        f32x4 fB = *reinterpret_cast<const f32x4*>(&f2sh[jrel + 4]);
        float p[8];
#pragma unroll
        for (int e = 0; e < 8; ++e) {
          float f = (e < 4 ? fA[e] : fB[e - 4]);
          float t = fmaxf(f + c1, f * 0.2f + c2);
          t = ((wb >> e) & 1u) ? t : -1.0e30f;
          p[e] = exp2f(t);
        }
        union { short8 s8; unsigned u32[4]; } au;
#pragma unroll
        for (int ep = 0; ep < 4; ++ep) {
          unsigned ue = __builtin_bit_cast(unsigned, p[2 * ep]);
          unsigned uo = __builtin_bit_cast(unsigned, p[2 * ep + 1]);
          au.u32[ep] = (ue >> 16) | (uo & 0xffff0000u);
        }
#pragma unroll
        for (int n = 0; n < NF; ++n) {
          short8 b = *reinterpret_cast<const short8*>(&Vt[n * 16 + row_l][hh * 32 + grp * 8]);
          acc[n] = __builtin_amdgcn_mfma_f32_16x16x32_bf16(au.s8, b, acc[n], 0, 0, 0);
        }
        accl = __builtin_amdgcn_mfma_f32_16x16x32_bf16(au.s8, ones8, accl, 0, 0, 0);
      }
    }
  }

#pragma unroll
  for (int n = 0; n < NF; ++n) {
#pragma unroll
    for (int k = 0; k < 4; ++k) {
      int r = i0 + w * 16 + grp * 4 + k;
      atomicAdd(&out[(size_t)r * Ftot + vcol + n * 16 + row_l], acc[n][k]);
    }
  }
  if (blockIdx.x == 0 && row_l == 0) {
#pragma unroll
    for (int k = 0; k < 4; ++k)
      atomicAdd(&lsum[hN + i0 + w * 16 + grp * 4 + k], accl[k]);
  }
}

// ---------------------------------------------------------------- activation epilogue
// x = buf / lsum, then elu (act 0) or sigmoid(elu) (act 1)
__global__ __launch_bounds__(256) void act_kernel(float* __restrict__ buf,
                                                  const float* __restrict__ lsum,
                                                  int n4, int ftotShift, int fpShift, int act) {
  int idx = blockIdx.x * blockDim.x + threadIdx.x;
  if (idx >= n4) return;
  int idx4 = idx * 4;
  int r = idx4 >> ftotShift;
  int c = idx4 & ((1 << ftotShift) - 1);
  int h = c >> fpShift;
  float li = 1.0f / lsum[h * N_NODES + r];
  float4 v = reinterpret_cast<float4*>(buf)[idx];
  float vv[4] = {v.x, v.y, v.z, v.w};
#pragma unroll
  for (int e = 0; e < 4; ++e) {
    float x = vv[e] * li;
    x = x > 0.0f ? x : exp2f(x * LOG2E) - 1.0f;
    if (act == 1) x = 1.0f / (1.0f + exp2f(-x * LOG2E));
    vv[e] = x;
  }
  reinterpret_cast<float4*>(buf)[idx] = make_float4(vv[0], vv[1], vv[2], vv[3]);
}

// ---------------------------------------------------------------- host
extern "C" void kernel_launch(void* const* d_in, const int* in_sizes, int n_in,
                              void* d_out, int out_size, void* d_ws, size_t ws_size,
                              hipStream_t stream) {
  const float* x     = (const float*)d_in[0];
  const int*   adj   = (const int*)d_in[1];
  const float* W1    = (const float*)d_in[2];
  const float* a1    = (const float*)d_in[3];
  const float* Wo    = (const float*)d_in[4];
  const float* ao    = (const float*)d_in[5];
  const float* W2    = (const float*)d_in[6];
  const float* a2    = (const float*)d_in[7];
  const float* Wo2   = (const float*)d_in[8];
  const float* ao2   = (const float*)d_in[9];
  const float* lin_w = (const float*)d_in[10];
  const float* lin_b = (const float*)d_in[11];
  float* out = (float*)d_out;

  float* ws = (float*)d_ws;
  unsigned int* bits = (unsigned int*)ws;            // 1,179,648 u32
  float* Wh   = ws + 1179648;                        // 6144*256
  float* bufA = Wh + 1572864;
  float* bufB = bufA + 1572864;
  float* Bcat = bufB + 1572864;                      // 65536
  float* f1   = Bcat + 65536;                        // 24576
  float* f2   = f1 + 24576;
  float* lsum = f2 + 24576;                          // 24576
  float* gmaxb = lsum + 24576;                       // 16
  short* WhT  = (short*)(gmaxb + 16);                // 6144*256 bf16
  short* BtW  = WhT + 1572864;                       // 384*256 bf16

  dim3 b256(256);

  bitpack_kernel<<<N_NODES, b256, 0, stream>>>(adj, bits);

  // ================= layer 1 multi-head (H=4, Fp=64), elu concat
  repack_W_kernel<<<(4 * 256 * 64 + 255) / 256, b256, 0, stream>>>(W1, Bcat, 4, 256, 64);
  transpose_w_kernel<<<dim3(8, 8), b256, 0, stream>>>(Bcat, BtW, 256, 256);
  gemm_mfma_kernel<<<dim3(4, 96), b256, 0, stream>>>(x, BtW, Wh, 256, 256, nullptr, 0);
  f1f2_kernel<<<(4 * N_NODES) / 4, b256, 0, stream>>>(Wh, a1, f1, f2, 4, 64);
  gmax_kernel<<<4, b256, 0, stream>>>(f2, gmaxb);
  transpose_bf16_kernel<<<dim3(8, 192), b256, 0, stream>>>(Wh, WhT, 256);
  hipMemsetAsync(bufA, 0, (size_t)6144 * 256 * 4, stream);
  hipMemsetAsync(lsum, 0, (size_t)24576 * 4, stream);
  pv_stage_kernel<4, 2><<<dim3(1, 192, 4), b256, 0, stream>>>(f1, f2, gmaxb, bits, WhT, bufA, lsum, 4, 64);
  act_kernel<<<dim3(1536), b256, 0, stream>>>(bufA, lsum, 6144 * 256 / 4, 8, 6, 0);

  // ================= out-attention 1 (H=1, Fp=256), sigmoid(elu)
  transpose_w_kernel<<<dim3(8, 8), b256, 0, stream>>>(Wo, BtW, 256, 256);
  gemm_mfma_kernel<<<dim3(4, 96), b256, 0, stream>>>(bufA, BtW, Wh, 256, 256, nullptr, 0);
  f1f2_kernel<<<(N_NODES) / 4, b256, 0, stream>>>(Wh, ao, f1, f2, 1, 256);
  gmax_kernel<<<1, b256, 0, stream>>>(f2, gmaxb);
  transpose_bf16_kernel<<<dim3(8, 192), b256, 0, stream>>>(Wh, WhT, 256);
  hipMemsetAsync(bufB, 0, (size_t)6144 * 256 * 4, stream);
  hipMemsetAsync(lsum, 0, (size_t)24576 * 4, stream);
  pv_stage_kernel<8, 4><<<dim3(2, 384, 1), b256, 0, stream>>>(f1, f2, gmaxb, bits, WhT, bufB, lsum, 1, 256);
  act_kernel<<<dim3(1536), b256, 0, stream>>>(bufB, lsum, 6144 * 256 / 4, 8, 8, 1);

  // ================= layer 2 multi-head (H=4, Fp=32), elu concat
  repack_W_kernel<<<(4 * 256 * 32 + 255) / 256, b256, 0, stream>>>(W2, Bcat, 4, 256, 32);
  transpose_w_kernel<<<dim3(8, 4), b256, 0, stream>>>(Bcat, BtW, 256, 128);
  gemm_mfma_kernel<<<dim3(2, 96), b256, 0, stream>>>(bufB, BtW, Wh, 256, 128, nullptr, 0);
  f1f2_kernel<<<(4 * N_NODES) / 4, b256, 0, stream>>>(Wh, a2, f1, f2, 4, 32);
  gmax_kernel<<<4, b256, 0, stream>>>(f2, gmaxb);
  transpose_bf16_kernel<<<dim3(4, 192), b256, 0, stream>>>(Wh, WhT, 128);
  hipMemsetAsync(bufA, 0, (size_t)6144 * 128 * 4, stream);
  hipMemsetAsync(lsum, 0, (size_t)24576 * 4, stream);
  pv_stage_kernel<2, 2><<<dim3(1, 192, 4), b256, 0, stream>>>(f1, f2, gmaxb, bits, WhT, bufA, lsum, 4, 32);
  act_kernel<<<dim3(768), b256, 0, stream>>>(bufA, lsum, 6144 * 128 / 4, 7, 5, 0);

  // ================= out-attention 2 (H=1, Fp=128), sigmoid(elu)
  transpose_w_kernel<<<dim3(4, 4), b256, 0, stream>>>(Wo2, BtW, 128, 128);
  gemm_mfma_kernel<<<dim3(2, 96), b256, 0, stream>>>(bufA, BtW, Wh, 128, 128, nullptr, 0);
  f1f2_kernel<<<(N_NODES) / 4, b256, 0, stream>>>(Wh, ao2, f1, f2, 1, 128);
  gmax_kernel<<<1, b256, 0, stream>>>(f2, gmaxb);
  transpose_bf16_kernel<<<dim3(4, 192), b256, 0, stream>>>(Wh, WhT, 128);
  hipMemsetAsync(bufB, 0, (size_t)6144 * 128 * 4, stream);
  hipMemsetAsync(lsum, 0, (size_t)24576 * 4, stream);
  pv_stage_kernel<8, 8><<<dim3(1, 768, 1), b256, 0, stream>>>(f1, f2, gmaxb, bits, WhT, bufB, lsum, 1, 128);
  act_kernel<<<dim3(768), b256, 0, stream>>>(bufB, lsum, 6144 * 128 / 4, 7, 7, 1);

  // ================= final linear + relu
  transpose_w_kernel<<<dim3(4, 12), b256, 0, stream>>>(lin_w, BtW, 128, 379);
  gemm_mfma_kernel<<<dim3(6, 96), b256, 0, stream>>>(bufB, BtW, out, 128, 379, lin_b, 1);
}

// Round 11
// 465.528 us; speedup vs baseline: 7.2640x; 1.0047x over previous
//
#include <hip/hip_runtime.h>
#include <hip/hip_bf16.h>

#define N_NODES 6144
#define MASK_WORDS 192  // 6144/32
#define LOG2E 1.44269504088896f

using short8 = __attribute__((ext_vector_type(8))) short;
using s16x4  = __attribute__((ext_vector_type(4))) short;
using f32x4  = __attribute__((ext_vector_type(4))) float;

// f32 -> bf16 bits, round-to-nearest-even
__device__ inline unsigned f2bf_u(float f) {
  unsigned u = __builtin_bit_cast(unsigned, f);
  u += 0x7fff + ((u >> 16) & 1);
  return u >> 16;
}
__device__ inline short f2bf(float f) { return (short)f2bf_u(f); }

// ---------------------------------------------------------------- bitpack
__global__ __launch_bounds__(256) void bitpack_kernel(const int* __restrict__ adj,
                                                      unsigned int* __restrict__ bits) {
  int row = blockIdx.x;
  int wave = threadIdx.x >> 6, lane = threadIdx.x & 63;
  const int* p = adj + (long)row * N_NODES;
  for (int base = wave * 64; base < N_NODES; base += 256) {
    unsigned long long m = __ballot(p[base + lane] > 0);
    if (lane == 0) {
      bits[row * MASK_WORDS + (base >> 5)] = (unsigned int)m;
      bits[row * MASK_WORDS + (base >> 5) + 1] = (unsigned int)(m >> 32);
    }
  }
}

// ---------------------------------------------------------------- W repack
// W [H][Fin][Fp] -> B [Fin][H*Fp]
__global__ __launch_bounds__(256) void repack_W_kernel(const float* __restrict__ W,
                                                       float* __restrict__ B,
                                                       int H, int Fin, int Fp) {
  int idx = blockIdx.x * blockDim.x + threadIdx.x;
  int total = H * Fin * Fp;
  if (idx >= total) return;
  int h = idx / (Fin * Fp);
  int rem = idx - h * (Fin * Fp);
  int k = rem / Fp, c = rem - k * Fp;
  B[k * (H * Fp) + h * Fp + c] = W[idx];
}

// ---------------------------------------------------------------- weight transpose+cvt
// B [K][Nc] f32 -> Bt [NcPad][K] bf16 (zero-fill cols >= Nc). grid (K/32, NcPad/32)
__global__ __launch_bounds__(256) void transpose_w_kernel(const float* __restrict__ B,
                                                          short* __restrict__ Bt,
                                                          int K, int Nc) {
  __shared__ short t[32][33];
  int k0 = blockIdx.x * 32, c0 = blockIdx.y * 32;
  int tx = threadIdx.x & 31, ty = threadIdx.x >> 5;
  for (int r = ty; r < 32; r += 8) {
    float v = (c0 + tx < Nc) ? B[(size_t)(k0 + r) * Nc + c0 + tx] : 0.0f;
    t[tx][r] = f2bf(v);
  }
  __syncthreads();
  for (int r = ty; r < 32; r += 8)
    Bt[(size_t)(c0 + r) * K + k0 + tx] = t[r][tx];
}

// ---------------------------------------------------------------- MFMA GEMM
// C[M,Nc] f32 = A[M,K] f32 @ Bt[NcPad][K] bf16 (+bias, act 1 = relu).
__global__ __launch_bounds__(256) void gemm_mfma_kernel(const float* __restrict__ A,
                                                        const short* __restrict__ Bt,
                                                        float* __restrict__ C,
                                                        int K, int Nc,
                                                        const float* __restrict__ bias,
                                                        int act) {
  __shared__ short As[64][40];
  __shared__ short Bs[64][40];
  int m0 = blockIdx.y * 64, n0 = blockIdx.x * 64;
  int tid = threadIdx.x;
  int w = tid >> 6, l = tid & 63, row_l = l & 15, grp = l >> 4;

  f32x4 acc[4] = {f32x4{0,0,0,0}, f32x4{0,0,0,0}, f32x4{0,0,0,0}, f32x4{0,0,0,0}};

  for (int k0 = 0; k0 < K; k0 += 32) {
    __syncthreads();
#pragma unroll
    for (int s = 0; s < 2; ++s) {
      int idx = tid + s * 256;
      int r = idx >> 3, q = idx & 7;
      float4 v = *reinterpret_cast<const float4*>(&A[(size_t)(m0 + r) * K + k0 + q * 4]);
      s16x4 sv = {f2bf(v.x), f2bf(v.y), f2bf(v.z), f2bf(v.w)};
      *reinterpret_cast<s16x4*>(&As[r][q * 4]) = sv;
    }
    {
      int c = tid >> 2, kq = tid & 3;
      *reinterpret_cast<short8*>(&Bs[c][kq * 8]) =
          *reinterpret_cast<const short8*>(&Bt[(size_t)(n0 + c) * K + k0 + kq * 8]);
    }
    __syncthreads();
    short8 a = *reinterpret_cast<const short8*>(&As[w * 16 + row_l][grp * 8]);
#pragma unroll
    for (int n = 0; n < 4; ++n) {
      short8 b = *reinterpret_cast<const short8*>(&Bs[n * 16 + row_l][grp * 8]);
      acc[n] = __builtin_amdgcn_mfma_f32_16x16x32_bf16(a, b, acc[n], 0, 0, 0);
    }
  }

#pragma unroll
  for (int n = 0; n < 4; ++n) {
#pragma unroll
    for (int k = 0; k < 4; ++k) {
      int row = m0 + w * 16 + grp * 4 + k;
      int col = n0 + n * 16 + row_l;
      if (col < Nc) {
        float v = acc[n][k];
        if (bias) v += bias[col];
        if (act == 1) v = fmaxf(v, 0.0f);
        C[(size_t)row * Nc + col] = v;
      }
    }
  }
}

// ---------------------------------------------------------------- f1/f2 (scaled by log2 e)
__global__ __launch_bounds__(256) void f1f2_kernel(const float* __restrict__ Wh,
                                                   const float* __restrict__ a,
                                                   float* __restrict__ f1,
                                                   float* __restrict__ f2,
                                                   int H, int Fp) {
  int g = blockIdx.x * 4 + (threadIdx.x >> 6);
  int lane = threadIdx.x & 63;
  if (g >= H * N_NODES) return;
  int h = g / N_NODES, n = g - h * N_NODES;
  int Ftot = H * Fp;
  const float* row = Wh + (long)n * Ftot + h * Fp;
  const float* av1 = a + h * 2 * Fp;
  const float* av2 = av1 + Fp;
  float s1 = 0.f, s2 = 0.f;
  for (int c = lane; c < Fp; c += 64) {
    float w = row[c];
    s1 += w * av1[c];
    s2 += w * av2[c];
  }
  for (int off = 32; off > 0; off >>= 1) {
    s1 += __shfl_down(s1, off);
    s2 += __shfl_down(s2, off);
  }
  if (lane == 0) { f1[g] = s1 * LOG2E; f2[g] = s2 * LOG2E; }
}

// ---------------------------------------------------------------- per-head global max of f2
__global__ __launch_bounds__(256) void gmax_kernel(const float* __restrict__ f2s,
                                                   float* __restrict__ gmax) {
  __shared__ float red[4];
  int h = blockIdx.x;
  int tid = threadIdx.x, lane = tid & 63, w = tid >> 6;
  const float* p = f2s + h * N_NODES;
  float m = -3.0e38f;
  for (int j = tid; j < N_NODES; j += 256) m = fmaxf(m, p[j]);
  for (int off = 32; off > 0; off >>= 1) m = fmaxf(m, __shfl_xor(m, off));
  if (lane == 0) red[w] = m;
  __syncthreads();
  if (tid == 0) gmax[h] = fmaxf(fmaxf(red[0], red[1]), fmaxf(red[2], red[3]));
}

// ---------------------------------------------------------------- transpose Wh -> WhT bf16
__global__ __launch_bounds__(256) void transpose_bf16_kernel(const float* __restrict__ A,
                                                             short* __restrict__ At,
                                                             int Ftot) {
  __shared__ short t[32][33];
  int c0 = blockIdx.x * 32, n0 = blockIdx.y * 32;
  int tx = threadIdx.x & 31, ty = threadIdx.x >> 5;
  for (int r = ty; r < 32; r += 8)
    t[tx][r] = f2bf(A[(size_t)(n0 + r) * Ftot + c0 + tx]);
  __syncthreads();
  for (int r = ty; r < 32; r += 8)
    At[(size_t)(c0 + r) * N_NODES + n0 + tx] = t[r][tx];
}

// ---------------------------------------------------------------- attention PV, LDS-staged V
// P = exp2(LR(f1s_i + f2s_j) - m_i), m_i = LR(f1s_i + gmax_h) >= masked row max.
// l_i accumulated via one extra MFMA with all-ones B fragment -> atomicAdd lsum.
// Vt layout: linear [COLS][64] with XOR-swizzled 16B-group index (j8 ^= c&7) —
// conflict-free for both staged ds_write_b128 and fragment ds_read_b128.
template<int NF, int JC>
__global__ __launch_bounds__(256)
void pv_stage_kernel(const float* __restrict__ f1s,
                     const float* __restrict__ f2s,
                     const float* __restrict__ gmax,
                     const unsigned int* __restrict__ bits,
                     const short* __restrict__ WhT,
                     float* __restrict__ out,
                     float* __restrict__ lsum,
                     int H, int Fp) {
  constexpr int CH = N_NODES / JC;
  constexpr int NCH = CH / 384;
  constexpr int COLS = NF * 16;
  static_assert(NCH * 384 == CH, "chunking");

  __shared__ float f2sh[CH];
  __shared__ short Vt[COLS * 64];

  int h = blockIdx.z;
  int cb0 = blockIdx.x * COLS;
  int rb = blockIdx.y % 96;
  int jc = blockIdx.y / 96;
  int i0 = rb * 64;
  int hN = h * N_NODES, hFp = h * Fp;
  int Ftot = H * Fp;
  int tid = threadIdx.x;
  int w = tid >> 6, l = tid & 63;
  int row_l = l & 15, grp = l >> 4;

  {
    const float4* src = reinterpret_cast<const float4*>(f2s + hN + jc * CH);
    float4* dst = reinterpret_cast<float4*>(f2sh);
    for (int idx = tid; idx < CH / 4; idx += 256) dst[idx] = src[idx];
  }

  int i = i0 + w * 16 + row_l;
  float fi = f1s[hN + i];
  float gm = gmax[h];
  float mi = fmaxf(fi + gm, 0.2f * (fi + gm));
  float c1 = fi - mi;
  float c2 = 0.2f * fi - mi;
  const unsigned int* mbase = bits + (size_t)i * MASK_WORDS + jc * (CH / 32);

  int vcol = hFp + cb0;
  const short* Wbase = WhT + (size_t)vcol * N_NODES;

  const short ONE = (short)0x3F80;
  short8 ones8 = {ONE, ONE, ONE, ONE, ONE, ONE, ONE, ONE};

  f32x4 acc[NF];
#pragma unroll
  for (int n = 0; n < NF; ++n) acc[n] = f32x4{0, 0, 0, 0};
  f32x4 accl = f32x4{0, 0, 0, 0};

  // per-lane swizzled read offsets (shorts): c = n*16+row_l, j8' = (4hh+grp)^(row_l&7)
  int rsw = row_l & 7;

#pragma unroll 1
  for (int ch = 0; ch < NCH; ++ch) {
    unsigned mw[12];
    {
      const uint4* mp = reinterpret_cast<const uint4*>(mbase + ch * 12);
#pragma unroll
      for (int q = 0; q < 3; ++q) {
        uint4 m = mp[q];
        mw[q * 4 + 0] = m.x; mw[q * 4 + 1] = m.y;
        mw[q * 4 + 2] = m.z; mw[q * 4 + 3] = m.w;
      }
    }
#pragma unroll 1
    for (int ss = 0; ss < 6; ++ss) {
      int j0 = jc * CH + ch * 384 + ss * 64;
      __syncthreads();
#pragma unroll
      for (int idx = tid; idx < COLS * 8; idx += 256) {
        int c = idx >> 3, sl = idx & 7;
        int j8s = sl ^ (c & 7);                       // XOR swizzle
        *reinterpret_cast<short8*>(&Vt[c * 64 + j8s * 8]) =
            *reinterpret_cast<const short8*>(Wbase + (size_t)c * N_NODES + j0 + sl * 8);
      }
      __syncthreads();
#pragma unroll
      for (int hh = 0; hh < 2; ++hh) {
        unsigned wb = (mw[ss * 2 + hh] >> (grp * 8)) & 0xffu;
        int jrel = ch * 384 + ss * 64 + hh * 32 + grp * 8;
        f32x4 fA = *reinterpret_cast<const f32x4*>(&f2sh[jrel]);
        f32x4 fB = *reinterpret_cast<const f32x4*>(&f2sh[jrel + 4]);
        float p[8];
#pragma unroll
        for (int e = 0; e < 8; ++e) {
          float f = (e < 4 ? fA[e] : fB[e - 4]);
          float t = fmaxf(f + c1, f * 0.2f + c2);
          t = ((wb >> e) & 1u) ? t : -1.0e30f;
          p[e] = exp2f(t);
        }
        union { short8 s8; unsigned u32[4]; } au;
#pragma unroll
        for (int ep = 0; ep < 4; ++ep) {
          unsigned ue = __builtin_bit_cast(unsigned, p[2 * ep]);
          unsigned uo = __builtin_bit_cast(unsigned, p[2 * ep + 1]);
          au.u32[ep] = (ue >> 16) | (uo & 0xffff0000u);
        }
        int j8s = ((hh << 2) | grp) ^ rsw;
#pragma unroll
        for (int n = 0; n < NF; ++n) {
          short8 b = *reinterpret_cast<const short8*>(&Vt[(n * 16 + row_l) * 64 + j8s * 8]);
          acc[n] = __builtin_amdgcn_mfma_f32_16x16x32_bf16(au.s8, b, acc[n], 0, 0, 0);
        }
        accl = __builtin_amdgcn_mfma_f32_16x16x32_bf16(au.s8, ones8, accl, 0, 0, 0);
      }
    }
  }

#pragma unroll
  for (int n = 0; n < NF; ++n) {
#pragma unroll
    for (int k = 0; k < 4; ++k) {
      int r = i0 + w * 16 + grp * 4 + k;
      atomicAdd(&out[(size_t)r * Ftot + vcol + n * 16 + row_l], acc[n][k]);
    }
  }
  if (blockIdx.x == 0 && row_l == 0) {
#pragma unroll
    for (int k = 0; k < 4; ++k)
      atomicAdd(&lsum[hN + i0 + w * 16 + grp * 4 + k], accl[k]);
  }
}

// ---------------------------------------------------------------- activation epilogue
// x = buf / lsum, then elu (act 0) or sigmoid(elu) (act 1)
__global__ __launch_bounds__(256) void act_kernel(float* __restrict__ buf,
                                                  const float* __restrict__ lsum,
                                                  int n4, int ftotShift, int fpShift, int act) {
  int idx = blockIdx.x * blockDim.x + threadIdx.x;
  if (idx >= n4) return;
  int idx4 = idx * 4;
  int r = idx4 >> ftotShift;
  int c = idx4 & ((1 << ftotShift) - 1);
  int h = c >> fpShift;
  float li = 1.0f / lsum[h * N_NODES + r];
  float4 v = reinterpret_cast<float4*>(buf)[idx];
  float vv[4] = {v.x, v.y, v.z, v.w};
#pragma unroll
  for (int e = 0; e < 4; ++e) {
    float x = vv[e] * li;
    x = x > 0.0f ? x : exp2f(x * LOG2E) - 1.0f;
    if (act == 1) x = 1.0f / (1.0f + exp2f(-x * LOG2E));
    vv[e] = x;
  }
  reinterpret_cast<float4*>(buf)[idx] = make_float4(vv[0], vv[1], vv[2], vv[3]);
}

// ---------------------------------------------------------------- host
extern "C" void kernel_launch(void* const* d_in, const int* in_sizes, int n_in,
                              void* d_out, int out_size, void* d_ws, size_t ws_size,
                              hipStream_t stream) {
  const float* x     = (const float*)d_in[0];
  const int*   adj   = (const int*)d_in[1];
  const float* W1    = (const float*)d_in[2];
  const float* a1    = (const float*)d_in[3];
  const float* Wo    = (const float*)d_in[4];
  const float* ao    = (const float*)d_in[5];
  const float* W2    = (const float*)d_in[6];
  const float* a2    = (const float*)d_in[7];
  const float* Wo2   = (const float*)d_in[8];
  const float* ao2   = (const float*)d_in[9];
  const float* lin_w = (const float*)d_in[10];
  const float* lin_b = (const float*)d_in[11];
  float* out = (float*)d_out;

  float* ws = (float*)d_ws;
  unsigned int* bits = (unsigned int*)ws;            // 1,179,648 u32
  float* Wh   = ws + 1179648;                        // 6144*256
  float* bufA = Wh + 1572864;
  float* bufB = bufA + 1572864;
  float* Bcat = bufB + 1572864;                      // 65536
  float* f1   = Bcat + 65536;                        // 24576
  float* f2   = f1 + 24576;
  float* lsum = f2 + 24576;                          // 24576
  float* gmaxb = lsum + 24576;                       // 16
  short* WhT  = (short*)(gmaxb + 16);                // 6144*256 bf16
  short* BtW  = WhT + 1572864;                       // 384*256 bf16

  dim3 b256(256);

  bitpack_kernel<<<N_NODES, b256, 0, stream>>>(adj, bits);

  // ================= layer 1 multi-head (H=4, Fp=64), elu concat
  repack_W_kernel<<<(4 * 256 * 64 + 255) / 256, b256, 0, stream>>>(W1, Bcat, 4, 256, 64);
  transpose_w_kernel<<<dim3(8, 8), b256, 0, stream>>>(Bcat, BtW, 256, 256);
  gemm_mfma_kernel<<<dim3(4, 96), b256, 0, stream>>>(x, BtW, Wh, 256, 256, nullptr, 0);
  f1f2_kernel<<<(4 * N_NODES) / 4, b256, 0, stream>>>(Wh, a1, f1, f2, 4, 64);
  gmax_kernel<<<4, b256, 0, stream>>>(f2, gmaxb);
  transpose_bf16_kernel<<<dim3(8, 192), b256, 0, stream>>>(Wh, WhT, 256);
  hipMemsetAsync(bufA, 0, (size_t)6144 * 256 * 4, stream);
  hipMemsetAsync(lsum, 0, (size_t)24576 * 4, stream);
  pv_stage_kernel<4, 4><<<dim3(1, 384, 4), b256, 0, stream>>>(f1, f2, gmaxb, bits, WhT, bufA, lsum, 4, 64);
  act_kernel<<<dim3(1536), b256, 0, stream>>>(bufA, lsum, 6144 * 256 / 4, 8, 6, 0);

  // ================= out-attention 1 (H=1, Fp=256), sigmoid(elu)
  transpose_w_kernel<<<dim3(8, 8), b256, 0, stream>>>(Wo, BtW, 256, 256);
  gemm_mfma_kernel<<<dim3(4, 96), b256, 0, stream>>>(bufA, BtW, Wh, 256, 256, nullptr, 0);
  f1f2_kernel<<<(N_NODES) / 4, b256, 0, stream>>>(Wh, ao, f1, f2, 1, 256);
  gmax_kernel<<<1, b256, 0, stream>>>(f2, gmaxb);
  transpose_bf16_kernel<<<dim3(8, 192), b256, 0, stream>>>(Wh, WhT, 256);
  hipMemsetAsync(bufB, 0, (size_t)6144 * 256 * 4, stream);
  hipMemsetAsync(lsum, 0, (size_t)24576 * 4, stream);
  pv_stage_kernel<8, 8><<<dim3(2, 768, 1), b256, 0, stream>>>(f1, f2, gmaxb, bits, WhT, bufB, lsum, 1, 256);
  act_kernel<<<dim3(1536), b256, 0, stream>>>(bufB, lsum, 6144 * 256 / 4, 8, 8, 1);

  // ================= layer 2 multi-head (H=4, Fp=32), elu concat
  repack_W_kernel<<<(4 * 256 * 32 + 255) / 256, b256, 0, stream>>>(W2, Bcat, 4, 256, 32);
  transpose_w_kernel<<<dim3(8, 4), b256, 0, stream>>>(Bcat, BtW, 256, 128);
  gemm_mfma_kernel<<<dim3(2, 96), b256, 0, stream>>>(bufB, BtW, Wh, 256, 128, nullptr, 0);
  f1f2_kernel<<<(4 * N_NODES) / 4, b256, 0, stream>>>(Wh, a2, f1, f2, 4, 32);
  gmax_kernel<<<4, b256, 0, stream>>>(f2, gmaxb);
  transpose_bf16_kernel<<<dim3(4, 192), b256, 0, stream>>>(Wh, WhT, 128);
  hipMemsetAsync(bufA, 0, (size_t)6144 * 128 * 4, stream);
  hipMemsetAsync(lsum, 0, (size_t)24576 * 4, stream);
  pv_stage_kernel<2, 4><<<dim3(1, 384, 4), b256, 0, stream>>>(f1, f2, gmaxb, bits, WhT, bufA, lsum, 4, 32);
  act_kernel<<<dim3(768), b256, 0, stream>>>(bufA, lsum, 6144 * 128 / 4, 7, 5, 0);

  // ================= out-attention 2 (H=1, Fp=128), sigmoid(elu)
  transpose_w_kernel<<<dim3(4, 4), b256, 0, stream>>>(Wo2, BtW, 128, 128);
  gemm_mfma_kernel<<<dim3(2, 96), b256, 0, stream>>>(bufA, BtW, Wh, 128, 128, nullptr, 0);
  f1f2_kernel<<<(N_NODES) / 4, b256, 0, stream>>>(Wh, ao2, f1, f2, 1, 128);
  gmax_kernel<<<1, b256, 0, stream>>>(f2, gmaxb);
  transpose_bf16_kernel<<<dim3(4, 192), b256, 0, stream>>>(Wh, WhT, 128);
  hipMemsetAsync(bufB, 0, (size_t)6144 * 128 * 4, stream);
  hipMemsetAsync(lsum, 0, (size_t)24576 * 4, stream);
  pv_stage_kernel<8, 16><<<dim3(1, 1536, 1), b256, 0, stream>>>(f1, f2, gmaxb, bits, WhT, bufB, lsum, 1, 128);
  act_kernel<<<dim3(768), b256, 0, stream>>>(bufB, lsum, 6144 * 128 / 4, 7, 7, 1);

  // ================= final linear + relu
  transpose_w_kernel<<<dim3(4, 12), b256, 0, stream>>>(lin_w, BtW, 128, 379);
  gemm_mfma_kernel<<<dim3(6, 96), b256, 0, stream>>>(bufB, BtW, out, 128, 379, lin_b, 1);
}

// Round 12
// 444.634 us; speedup vs baseline: 7.6054x; 1.0470x over previous
//
#include <hip/hip_runtime.h>
#include <hip/hip_bf16.h>

#define N_NODES 6144
#define MASK_WORDS 192  // 6144/32
#define LOG2E 1.44269504088896f

using short8 = __attribute__((ext_vector_type(8))) short;
using s16x4  = __attribute__((ext_vector_type(4))) short;
using f32x4  = __attribute__((ext_vector_type(4))) float;

// f32 -> bf16 bits, round-to-nearest-even
__device__ inline unsigned f2bf_u(float f) {
  unsigned u = __builtin_bit_cast(unsigned, f);
  u += 0x7fff + ((u >> 16) & 1);
  return u >> 16;
}
__device__ inline short f2bf(float f) { return (short)f2bf_u(f); }

// ---------------------------------------------------------------- bitpack
__global__ __launch_bounds__(256) void bitpack_kernel(const int* __restrict__ adj,
                                                      unsigned int* __restrict__ bits) {
  int row = blockIdx.x;
  int wave = threadIdx.x >> 6, lane = threadIdx.x & 63;
  const int* p = adj + (long)row * N_NODES;
  for (int base = wave * 64; base < N_NODES; base += 256) {
    unsigned long long m = __ballot(p[base + lane] > 0);
    if (lane == 0) {
      bits[row * MASK_WORDS + (base >> 5)] = (unsigned int)m;
      bits[row * MASK_WORDS + (base >> 5) + 1] = (unsigned int)(m >> 32);
    }
  }
}

// ---------------------------------------------------------------- W repack
// W [H][Fin][Fp] -> B [Fin][H*Fp]
__global__ __launch_bounds__(256) void repack_W_kernel(const float* __restrict__ W,
                                                       float* __restrict__ B,
                                                       int H, int Fin, int Fp) {
  int idx = blockIdx.x * blockDim.x + threadIdx.x;
  int total = H * Fin * Fp;
  if (idx >= total) return;
  int h = idx / (Fin * Fp);
  int rem = idx - h * (Fin * Fp);
  int k = rem / Fp, c = rem - k * Fp;
  B[k * (H * Fp) + h * Fp + c] = W[idx];
}

// ---------------------------------------------------------------- weight transpose+cvt
// B [K][Nc] f32 -> Bt [NcPad][K] bf16 (zero-fill cols >= Nc). grid (K/32, NcPad/32)
__global__ __launch_bounds__(256) void transpose_w_kernel(const float* __restrict__ B,
                                                          short* __restrict__ Bt,
                                                          int K, int Nc) {
  __shared__ short t[32][33];
  int k0 = blockIdx.x * 32, c0 = blockIdx.y * 32;
  int tx = threadIdx.x & 31, ty = threadIdx.x >> 5;
  for (int r = ty; r < 32; r += 8) {
    float v = (c0 + tx < Nc) ? B[(size_t)(k0 + r) * Nc + c0 + tx] : 0.0f;
    t[tx][r] = f2bf(v);
  }
  __syncthreads();
  for (int r = ty; r < 32; r += 8)
    Bt[(size_t)(c0 + r) * K + k0 + tx] = t[r][tx];
}

// ---------------------------------------------------------------- MFMA GEMM
// C[M,Nc] f32 = A[M,K] f32 @ Bt[NcPad][K] bf16 (+bias, act 1 = relu).
__global__ __launch_bounds__(256) void gemm_mfma_kernel(const float* __restrict__ A,
                                                        const short* __restrict__ Bt,
                                                        float* __restrict__ C,
                                                        int K, int Nc,
                                                        const float* __restrict__ bias,
                                                        int act) {
  __shared__ short As[64][40];
  __shared__ short Bs[64][40];
  int m0 = blockIdx.y * 64, n0 = blockIdx.x * 64;
  int tid = threadIdx.x;
  int w = tid >> 6, l = tid & 63, row_l = l & 15, grp = l >> 4;

  f32x4 acc[4] = {f32x4{0,0,0,0}, f32x4{0,0,0,0}, f32x4{0,0,0,0}, f32x4{0,0,0,0}};

  for (int k0 = 0; k0 < K; k0 += 32) {
    __syncthreads();
#pragma unroll
    for (int s = 0; s < 2; ++s) {
      int idx = tid + s * 256;
      int r = idx >> 3, q = idx & 7;
      float4 v = *reinterpret_cast<const float4*>(&A[(size_t)(m0 + r) * K + k0 + q * 4]);
      s16x4 sv = {f2bf(v.x), f2bf(v.y), f2bf(v.z), f2bf(v.w)};
      *reinterpret_cast<s16x4*>(&As[r][q * 4]) = sv;
    }
    {
      int c = tid >> 2, kq = tid & 3;
      *reinterpret_cast<short8*>(&Bs[c][kq * 8]) =
          *reinterpret_cast<const short8*>(&Bt[(size_t)(n0 + c) * K + k0 + kq * 8]);
    }
    __syncthreads();
    short8 a = *reinterpret_cast<const short8*>(&As[w * 16 + row_l][grp * 8]);
#pragma unroll
    for (int n = 0; n < 4; ++n) {
      short8 b = *reinterpret_cast<const short8*>(&Bs[n * 16 + row_l][grp * 8]);
      acc[n] = __builtin_amdgcn_mfma_f32_16x16x32_bf16(a, b, acc[n], 0, 0, 0);
    }
  }

#pragma unroll
  for (int n = 0; n < 4; ++n) {
#pragma unroll
    for (int k = 0; k < 4; ++k) {
      int row = m0 + w * 16 + grp * 4 + k;
      int col = n0 + n * 16 + row_l;
      if (col < Nc) {
        float v = acc[n][k];
        if (bias) v += bias[col];
        if (act == 1) v = fmaxf(v, 0.0f);
        C[(size_t)row * Nc + col] = v;
      }
    }
  }
}

// ---------------------------------------------------------------- f1/f2 (scaled by log2 e)
__global__ __launch_bounds__(256) void f1f2_kernel(const float* __restrict__ Wh,
                                                   const float* __restrict__ a,
                                                   float* __restrict__ f1,
                                                   float* __restrict__ f2,
                                                   int H, int Fp) {
  int g = blockIdx.x * 4 + (threadIdx.x >> 6);
  int lane = threadIdx.x & 63;
  if (g >= H * N_NODES) return;
  int h = g / N_NODES, n = g - h * N_NODES;
  int Ftot = H * Fp;
  const float* row = Wh + (long)n * Ftot + h * Fp;
  const float* av1 = a + h * 2 * Fp;
  const float* av2 = av1 + Fp;
  float s1 = 0.f, s2 = 0.f;
  for (int c = lane; c < Fp; c += 64) {
    float w = row[c];
    s1 += w * av1[c];
    s2 += w * av2[c];
  }
  for (int off = 32; off > 0; off >>= 1) {
    s1 += __shfl_down(s1, off);
    s2 += __shfl_down(s2, off);
  }
  if (lane == 0) { f1[g] = s1 * LOG2E; f2[g] = s2 * LOG2E; }
}

// ---------------------------------------------------------------- per-head global max of f2
__global__ __launch_bounds__(256) void gmax_kernel(const float* __restrict__ f2s,
                                                   float* __restrict__ gmax) {
  __shared__ float red[4];
  int h = blockIdx.x;
  int tid = threadIdx.x, lane = tid & 63, w = tid >> 6;
  const float* p = f2s + h * N_NODES;
  float m = -3.0e38f;
  for (int j = tid; j < N_NODES; j += 256) m = fmaxf(m, p[j]);
  for (int off = 32; off > 0; off >>= 1) m = fmaxf(m, __shfl_xor(m, off));
  if (lane == 0) red[w] = m;
  __syncthreads();
  if (tid == 0) gmax[h] = fmaxf(fmaxf(red[0], red[1]), fmaxf(red[2], red[3]));
}

// ---------------------------------------------------------------- transpose Wh -> WhT bf16
__global__ __launch_bounds__(256) void transpose_bf16_kernel(const float* __restrict__ A,
                                                             short* __restrict__ At,
                                                             int Ftot) {
  __shared__ short t[32][33];
  int c0 = blockIdx.x * 32, n0 = blockIdx.y * 32;
  int tx = threadIdx.x & 31, ty = threadIdx.x >> 5;
  for (int r = ty; r < 32; r += 8)
    t[tx][r] = f2bf(A[(size_t)(n0 + r) * Ftot + c0 + tx]);
  __syncthreads();
  for (int r = ty; r < 32; r += 8)
    At[(size_t)(c0 + r) * N_NODES + n0 + tx] = t[r][tx];
}

// ---------------------------------------------------------------- attention PV, LDS-staged V
// P = exp2(LR(f1s_i + f2s_j) - m_i), m_i = LR(f1s_i + gmax_h) >= masked row max.
// Double-buffered Vt with per-thread REGISTER PREFETCH: stage s+1's global loads are
// issued before stage s's compute, hiding HBM/L2 latency (T14). All addresses
// (global gp[it], swizzled LDS wof[it], read offsets) precomputed and bumped by
// constants. l_i via ones-MFMA only on blockIdx.x==0 blocks.
template<int NF, int JC>
__global__ __launch_bounds__(256)
void pv_stage_kernel(const float* __restrict__ f1s,
                     const float* __restrict__ f2s,
                     const float* __restrict__ gmax,
                     const unsigned int* __restrict__ bits,
                     const short* __restrict__ WhT,
                     float* __restrict__ out,
                     float* __restrict__ lsum,
                     int H, int Fp) {
  constexpr int CH = N_NODES / JC;
  constexpr int NCH = CH / 384;
  constexpr int COLS = NF * 16;
  constexpr int NITER = (COLS * 8) / 256;      // staging iters per 64-j stage
  constexpr int NSTAGES = CH / 64;
  static_assert(NCH * 384 == CH, "chunking");

  __shared__ float f2sh[CH];
  __shared__ short Vt[2 * COLS * 64];          // double buffer

  int h = blockIdx.z;
  int cb0 = blockIdx.x * COLS;
  int rb = blockIdx.y % 96;
  int jc = blockIdx.y / 96;
  int i0 = rb * 64;
  int hN = h * N_NODES, hFp = h * Fp;
  int Ftot = H * Fp;
  int tid = threadIdx.x;
  int w = tid >> 6, l = tid & 63;
  int row_l = l & 15, grp = l >> 4;

  {
    const float4* src = reinterpret_cast<const float4*>(f2s + hN + jc * CH);
    float4* dst = reinterpret_cast<float4*>(f2sh);
    for (int idx = tid; idx < CH / 4; idx += 256) dst[idx] = src[idx];
  }

  int i = i0 + w * 16 + row_l;
  float fi = f1s[hN + i];
  float gm = gmax[h];
  float mi = fmaxf(fi + gm, 0.2f * (fi + gm));
  float c1 = fi - mi;
  float c2 = 0.2f * fi - mi;
  const unsigned int* mbase = bits + (size_t)i * MASK_WORDS + jc * (CH / 32);

  int vcol = hFp + cb0;
  const short* Wbase = WhT + (size_t)vcol * N_NODES;

  const short ONE = (short)0x3F80;
  short8 ones8 = {ONE, ONE, ONE, ONE, ONE, ONE, ONE, ONE};
  bool needL = (blockIdx.x == 0);

  // ---- precomputed staging addresses
  const short* gp[NITER];
  int wof[NITER];
#pragma unroll
  for (int it = 0; it < NITER; ++it) {
    int c = (tid >> 3) + it * 32;
    int sl = tid & 7;
    gp[it] = Wbase + (size_t)c * N_NODES + jc * CH + sl * 8;
    wof[it] = c * 64 + ((sl ^ (c & 7)) * 8);   // XOR-swizzled
  }
  // per-lane read swizzle
  int rsw = row_l & 7;

  f32x4 acc[NF];
#pragma unroll
  for (int n = 0; n < NF; ++n) acc[n] = f32x4{0, 0, 0, 0};
  f32x4 accl = f32x4{0, 0, 0, 0};

  // ---- prologue: prefetch stage 0
  short8 vreg[NITER];
#pragma unroll
  for (int it = 0; it < NITER; ++it)
    vreg[it] = *reinterpret_cast<const short8*>(gp[it]);

  int scount = 0;
#pragma unroll 1
  for (int ch = 0; ch < NCH; ++ch) {
    unsigned mw[12];
    {
      const uint4* mp = reinterpret_cast<const uint4*>(mbase + ch * 12);
#pragma unroll
      for (int q = 0; q < 3; ++q) {
        uint4 m = mp[q];
        mw[q * 4 + 0] = m.x; mw[q * 4 + 1] = m.y;
        mw[q * 4 + 2] = m.z; mw[q * 4 + 3] = m.w;
      }
    }
#pragma unroll 1
    for (int ss = 0; ss < 6; ++ss) {
      __syncthreads();                          // buf[scount&1] free
      short* vb = &Vt[(scount & 1) * (COLS * 64)];
#pragma unroll
      for (int it = 0; it < NITER; ++it)
        *reinterpret_cast<short8*>(&vb[wof[it]]) = vreg[it];
      if (scount + 1 < NSTAGES) {
#pragma unroll
        for (int it = 0; it < NITER; ++it)
          vreg[it] = *reinterpret_cast<const short8*>(gp[it] + (scount + 1) * 64);
      }
      __syncthreads();                          // buf[scount&1] ready
#pragma unroll
      for (int hh = 0; hh < 2; ++hh) {
        unsigned wb = (mw[ss * 2 + hh] >> (grp * 8)) & 0xffu;
        int jrel = ch * 384 + ss * 64 + hh * 32 + grp * 8;
        f32x4 fA = *reinterpret_cast<const f32x4*>(&f2sh[jrel]);
        f32x4 fB = *reinterpret_cast<const f32x4*>(&f2sh[jrel + 4]);
        float p[8];
#pragma unroll
        for (int e = 0; e < 8; ++e) {
          float f = (e < 4 ? fA[e] : fB[e - 4]);
          float t = fmaxf(f + c1, f * 0.2f + c2);
          t = ((wb >> e) & 1u) ? t : -1.0e30f;
          p[e] = exp2f(t);
        }
        union { short8 s8; unsigned u32[4]; } au;
#pragma unroll
        for (int ep = 0; ep < 4; ++ep) {
          unsigned ue = __builtin_bit_cast(unsigned, p[2 * ep]);
          unsigned uo = __builtin_bit_cast(unsigned, p[2 * ep + 1]);
          au.u32[ep] = (ue >> 16) | (uo & 0xffff0000u);
        }
        int j8s = ((hh << 2) | grp) ^ rsw;
#pragma unroll
        for (int n = 0; n < NF; ++n) {
          short8 b = *reinterpret_cast<const short8*>(&vb[(n * 16 + row_l) * 64 + j8s * 8]);
          acc[n] = __builtin_amdgcn_mfma_f32_16x16x32_bf16(au.s8, b, acc[n], 0, 0, 0);
        }
        if (needL)
          accl = __builtin_amdgcn_mfma_f32_16x16x32_bf16(au.s8, ones8, accl, 0, 0, 0);
      }
      ++scount;
    }
  }

#pragma unroll
  for (int n = 0; n < NF; ++n) {
#pragma unroll
    for (int k = 0; k < 4; ++k) {
      int r = i0 + w * 16 + grp * 4 + k;
      atomicAdd(&out[(size_t)r * Ftot + vcol + n * 16 + row_l], acc[n][k]);
    }
  }
  if (needL && row_l == 0) {
#pragma unroll
    for (int k = 0; k < 4; ++k)
      atomicAdd(&lsum[hN + i0 + w * 16 + grp * 4 + k], accl[k]);
  }
}

// ---------------------------------------------------------------- activation epilogue
// x = buf / lsum, then elu (act 0) or sigmoid(elu) (act 1)
__global__ __launch_bounds__(256) void act_kernel(float* __restrict__ buf,
                                                  const float* __restrict__ lsum,
                                                  int n4, int ftotShift, int fpShift, int act) {
  int idx = blockIdx.x * blockDim.x + threadIdx.x;
  if (idx >= n4) return;
  int idx4 = idx * 4;
  int r = idx4 >> ftotShift;
  int c = idx4 & ((1 << ftotShift) - 1);
  int h = c >> fpShift;
  float li = 1.0f / lsum[h * N_NODES + r];
  float4 v = reinterpret_cast<float4*>(buf)[idx];
  float vv[4] = {v.x, v.y, v.z, v.w};
#pragma unroll
  for (int e = 0; e < 4; ++e) {
    float x = vv[e] * li;
    x = x > 0.0f ? x : exp2f(x * LOG2E) - 1.0f;
    if (act == 1) x = 1.0f / (1.0f + exp2f(-x * LOG2E));
    vv[e] = x;
  }
  reinterpret_cast<float4*>(buf)[idx] = make_float4(vv[0], vv[1], vv[2], vv[3]);
}

// ---------------------------------------------------------------- host
extern "C" void kernel_launch(void* const* d_in, const int* in_sizes, int n_in,
                              void* d_out, int out_size, void* d_ws, size_t ws_size,
                              hipStream_t stream) {
  const float* x     = (const float*)d_in[0];
  const int*   adj   = (const int*)d_in[1];
  const float* W1    = (const float*)d_in[2];
  const float* a1    = (const float*)d_in[3];
  const float* Wo    = (const float*)d_in[4];
  const float* ao    = (const float*)d_in[5];
  const float* W2    = (const float*)d_in[6];
  const float* a2    = (const float*)d_in[7];
  const float* Wo2   = (const float*)d_in[8];
  const float* ao2   = (const float*)d_in[9];
  const float* lin_w = (const float*)d_in[10];
  const float* lin_b = (const float*)d_in[11];
  float* out = (float*)d_out;

  float* ws = (float*)d_ws;
  unsigned int* bits = (unsigned int*)ws;            // 1,179,648 u32
  float* Wh   = ws + 1179648;                        // 6144*256
  float* bufA = Wh + 1572864;
  float* bufB = bufA + 1572864;
  float* Bcat = bufB + 1572864;                      // 65536
  float* f1   = Bcat + 65536;                        // 24576
  float* f2   = f1 + 24576;
  float* lsum = f2 + 24576;                          // 24576
  float* gmaxb = lsum + 24576;                       // 16
  short* WhT  = (short*)(gmaxb + 16);                // 6144*256 bf16
  short* BtW  = WhT + 1572864;                       // 384*256 bf16

  dim3 b256(256);

  bitpack_kernel<<<N_NODES, b256, 0, stream>>>(adj, bits);

  // ================= layer 1 multi-head (H=4, Fp=64), elu concat
  repack_W_kernel<<<(4 * 256 * 64 + 255) / 256, b256, 0, stream>>>(W1, Bcat, 4, 256, 64);
  transpose_w_kernel<<<dim3(8, 8), b256, 0, stream>>>(Bcat, BtW, 256, 256);
  gemm_mfma_kernel<<<dim3(4, 96), b256, 0, stream>>>(x, BtW, Wh, 256, 256, nullptr, 0);
  f1f2_kernel<<<(4 * N_NODES) / 4, b256, 0, stream>>>(Wh, a1, f1, f2, 4, 64);
  gmax_kernel<<<4, b256, 0, stream>>>(f2, gmaxb);
  transpose_bf16_kernel<<<dim3(8, 192), b256, 0, stream>>>(Wh, WhT, 256);
  hipMemsetAsync(bufA, 0, (size_t)6144 * 256 * 4, stream);
  hipMemsetAsync(lsum, 0, (size_t)24576 * 4, stream);
  pv_stage_kernel<4, 4><<<dim3(1, 384, 4), b256, 0, stream>>>(f1, f2, gmaxb, bits, WhT, bufA, lsum, 4, 64);
  act_kernel<<<dim3(1536), b256, 0, stream>>>(bufA, lsum, 6144 * 256 / 4, 8, 6, 0);

  // ================= out-attention 1 (H=1, Fp=256), sigmoid(elu)
  transpose_w_kernel<<<dim3(8, 8), b256, 0, stream>>>(Wo, BtW, 256, 256);
  gemm_mfma_kernel<<<dim3(4, 96), b256, 0, stream>>>(bufA, BtW, Wh, 256, 256, nullptr, 0);
  f1f2_kernel<<<(N_NODES) / 4, b256, 0, stream>>>(Wh, ao, f1, f2, 1, 256);
  gmax_kernel<<<1, b256, 0, stream>>>(f2, gmaxb);
  transpose_bf16_kernel<<<dim3(8, 192), b256, 0, stream>>>(Wh, WhT, 256);
  hipMemsetAsync(bufB, 0, (size_t)6144 * 256 * 4, stream);
  hipMemsetAsync(lsum, 0, (size_t)24576 * 4, stream);
  pv_stage_kernel<8, 8><<<dim3(2, 768, 1), b256, 0, stream>>>(f1, f2, gmaxb, bits, WhT, bufB, lsum, 1, 256);
  act_kernel<<<dim3(1536), b256, 0, stream>>>(bufB, lsum, 6144 * 256 / 4, 8, 8, 1);

  // ================= layer 2 multi-head (H=4, Fp=32), elu concat
  repack_W_kernel<<<(4 * 256 * 32 + 255) / 256, b256, 0, stream>>>(W2, Bcat, 4, 256, 32);
  transpose_w_kernel<<<dim3(8, 4), b256, 0, stream>>>(Bcat, BtW, 256, 128);
  gemm_mfma_kernel<<<dim3(2, 96), b256, 0, stream>>>(bufB, BtW, Wh, 256, 128, nullptr, 0);
  f1f2_kernel<<<(4 * N_NODES) / 4, b256, 0, stream>>>(Wh, a2, f1, f2, 4, 32);
  gmax_kernel<<<4, b256, 0, stream>>>(f2, gmaxb);
  transpose_bf16_kernel<<<dim3(4, 192), b256, 0, stream>>>(Wh, WhT, 128);
  hipMemsetAsync(bufA, 0, (size_t)6144 * 128 * 4, stream);
  hipMemsetAsync(lsum, 0, (size_t)24576 * 4, stream);
  pv_stage_kernel<2, 4><<<dim3(1, 384, 4), b256, 0, stream>>>(f1, f2, gmaxb, bits, WhT, bufA, lsum, 4, 32);
  act_kernel<<<dim3(768), b256, 0, stream>>>(bufA, lsum, 6144 * 128 / 4, 7, 5, 0);

  // ================= out-attention 2 (H=1, Fp=128), sigmoid(elu)
  transpose_w_kernel<<<dim3(4, 4), b256, 0, stream>>>(Wo2, BtW, 128, 128);
  gemm_mfma_kernel<<<dim3(2, 96), b256, 0, stream>>>(bufA, BtW, Wh, 128, 128, nullptr, 0);
  f1f2_kernel<<<(N_NODES) / 4, b256, 0, stream>>>(Wh, ao2, f1, f2, 1, 128);
  gmax_kernel<<<1, b256, 0, stream>>>(f2, gmaxb);
  transpose_bf16_kernel<<<dim3(4, 192), b256, 0, stream>>>(Wh, WhT, 128);
  hipMemsetAsync(bufB, 0, (size_t)6144 * 128 * 4, stream);
  hipMemsetAsync(lsum, 0, (size_t)24576 * 4, stream);
  pv_stage_kernel<8, 16><<<dim3(1, 1536, 1), b256, 0, stream>>>(f1, f2, gmaxb, bits, WhT, bufB, lsum, 1, 128);
  act_kernel<<<dim3(768), b256, 0, stream>>>(bufB, lsum, 6144 * 128 / 4, 7, 7, 1);

  // ================= final linear + relu
  transpose_w_kernel<<<dim3(4, 12), b256, 0, stream>>>(lin_w, BtW, 128, 379);
  gemm_mfma_kernel<<<dim3(6, 96), b256, 0, stream>>>(bufB, BtW, out, 128, 379, lin_b, 1);
}

// Round 13
// 408.391 us; speedup vs baseline: 8.2803x; 1.0887x over previous
//
#include <hip/hip_runtime.h>
#include <hip/hip_bf16.h>

#define N_NODES 6144
#define MASK_WORDS 192  // 6144/32
#define LOG2E 1.44269504088896f

using short8 = __attribute__((ext_vector_type(8))) short;
using s16x4  = __attribute__((ext_vector_type(4))) short;
using f32x4  = __attribute__((ext_vector_type(4))) float;

// f32 -> bf16 bits, round-to-nearest-even
__device__ inline unsigned f2bf_u(float f) {
  unsigned u = __builtin_bit_cast(unsigned, f);
  u += 0x7fff + ((u >> 16) & 1);
  return u >> 16;
}
__device__ inline short f2bf(float f) { return (short)f2bf_u(f); }

// ---------------------------------------------------------------- bitpack
__global__ __launch_bounds__(256) void bitpack_kernel(const int* __restrict__ adj,
                                                      unsigned int* __restrict__ bits) {
  int row = blockIdx.x;
  int wave = threadIdx.x >> 6, lane = threadIdx.x & 63;
  const int* p = adj + (long)row * N_NODES;
  for (int base = wave * 64; base < N_NODES; base += 256) {
    unsigned long long m = __ballot(p[base + lane] > 0);
    if (lane == 0) {
      bits[row * MASK_WORDS + (base >> 5)] = (unsigned int)m;
      bits[row * MASK_WORDS + (base >> 5) + 1] = (unsigned int)(m >> 32);
    }
  }
}

// ---------------------------------------------------------------- W repack
// W [H][Fin][Fp] -> B [Fin][H*Fp]
__global__ __launch_bounds__(256) void repack_W_kernel(const float* __restrict__ W,
                                                       float* __restrict__ B,
                                                       int H, int Fin, int Fp) {
  int idx = blockIdx.x * blockDim.x + threadIdx.x;
  int total = H * Fin * Fp;
  if (idx >= total) return;
  int h = idx / (Fin * Fp);
  int rem = idx - h * (Fin * Fp);
  int k = rem / Fp, c = rem - k * Fp;
  B[k * (H * Fp) + h * Fp + c] = W[idx];
}

// ---------------------------------------------------------------- weight transpose+cvt
// B [K][Nc] f32 -> Bt [NcPad][K] bf16 (zero-fill cols >= Nc). grid (K/32, NcPad/32)
__global__ __launch_bounds__(256) void transpose_w_kernel(const float* __restrict__ B,
                                                          short* __restrict__ Bt,
                                                          int K, int Nc) {
  __shared__ short t[32][33];
  int k0 = blockIdx.x * 32, c0 = blockIdx.y * 32;
  int tx = threadIdx.x & 31, ty = threadIdx.x >> 5;
  for (int r = ty; r < 32; r += 8) {
    float v = (c0 + tx < Nc) ? B[(size_t)(k0 + r) * Nc + c0 + tx] : 0.0f;
    t[tx][r] = f2bf(v);
  }
  __syncthreads();
  for (int r = ty; r < 32; r += 8)
    Bt[(size_t)(c0 + r) * K + k0 + tx] = t[r][tx];
}

// ---------------------------------------------------------------- MFMA GEMM
// C[M,Nc] f32 = A[M,K] f32 @ Bt[NcPad][K] bf16 (+bias, act 1 = relu).
__global__ __launch_bounds__(256) void gemm_mfma_kernel(const float* __restrict__ A,
                                                        const short* __restrict__ Bt,
                                                        float* __restrict__ C,
                                                        int K, int Nc,
                                                        const float* __restrict__ bias,
                                                        int act) {
  __shared__ short As[64][40];
  __shared__ short Bs[64][40];
  int m0 = blockIdx.y * 64, n0 = blockIdx.x * 64;
  int tid = threadIdx.x;
  int w = tid >> 6, l = tid & 63, row_l = l & 15, grp = l >> 4;

  f32x4 acc[4] = {f32x4{0,0,0,0}, f32x4{0,0,0,0}, f32x4{0,0,0,0}, f32x4{0,0,0,0}};

  for (int k0 = 0; k0 < K; k0 += 32) {
    __syncthreads();
#pragma unroll
    for (int s = 0; s < 2; ++s) {
      int idx = tid + s * 256;
      int r = idx >> 3, q = idx & 7;
      float4 v = *reinterpret_cast<const float4*>(&A[(size_t)(m0 + r) * K + k0 + q * 4]);
      s16x4 sv = {f2bf(v.x), f2bf(v.y), f2bf(v.z), f2bf(v.w)};
      *reinterpret_cast<s16x4*>(&As[r][q * 4]) = sv;
    }
    {
      int c = tid >> 2, kq = tid & 3;
      *reinterpret_cast<short8*>(&Bs[c][kq * 8]) =
          *reinterpret_cast<const short8*>(&Bt[(size_t)(n0 + c) * K + k0 + kq * 8]);
    }
    __syncthreads();
    short8 a = *reinterpret_cast<const short8*>(&As[w * 16 + row_l][grp * 8]);
#pragma unroll
    for (int n = 0; n < 4; ++n) {
      short8 b = *reinterpret_cast<const short8*>(&Bs[n * 16 + row_l][grp * 8]);
      acc[n] = __builtin_amdgcn_mfma_f32_16x16x32_bf16(a, b, acc[n], 0, 0, 0);
    }
  }

#pragma unroll
  for (int n = 0; n < 4; ++n) {
#pragma unroll
    for (int k = 0; k < 4; ++k) {
      int row = m0 + w * 16 + grp * 4 + k;
      int col = n0 + n * 16 + row_l;
      if (col < Nc) {
        float v = acc[n][k];
        if (bias) v += bias[col];
        if (act == 1) v = fmaxf(v, 0.0f);
        C[(size_t)row * Nc + col] = v;
      }
    }
  }
}

// ---------------------------------------------------------------- f1/f2 (scaled by log2 e)
__global__ __launch_bounds__(256) void f1f2_kernel(const float* __restrict__ Wh,
                                                   const float* __restrict__ a,
                                                   float* __restrict__ f1,
                                                   float* __restrict__ f2,
                                                   int H, int Fp) {
  int g = blockIdx.x * 4 + (threadIdx.x >> 6);
  int lane = threadIdx.x & 63;
  if (g >= H * N_NODES) return;
  int h = g / N_NODES, n = g - h * N_NODES;
  int Ftot = H * Fp;
  const float* row = Wh + (long)n * Ftot + h * Fp;
  const float* av1 = a + h * 2 * Fp;
  const float* av2 = av1 + Fp;
  float s1 = 0.f, s2 = 0.f;
  for (int c = lane; c < Fp; c += 64) {
    float w = row[c];
    s1 += w * av1[c];
    s2 += w * av2[c];
  }
  for (int off = 32; off > 0; off >>= 1) {
    s1 += __shfl_down(s1, off);
    s2 += __shfl_down(s2, off);
  }
  if (lane == 0) { f1[g] = s1 * LOG2E; f2[g] = s2 * LOG2E; }
}

// ---------------------------------------------------------------- per-head global max of f2
__global__ __launch_bounds__(256) void gmax_kernel(const float* __restrict__ f2s,
                                                   float* __restrict__ gmax) {
  __shared__ float red[4];
  int h = blockIdx.x;
  int tid = threadIdx.x, lane = tid & 63, w = tid >> 6;
  const float* p = f2s + h * N_NODES;
  float m = -3.0e38f;
  for (int j = tid; j < N_NODES; j += 256) m = fmaxf(m, p[j]);
  for (int off = 32; off > 0; off >>= 1) m = fmaxf(m, __shfl_xor(m, off));
  if (lane == 0) red[w] = m;
  __syncthreads();
  if (tid == 0) gmax[h] = fmaxf(fmaxf(red[0], red[1]), fmaxf(red[2], red[3]));
}

// ---------------------------------------------------------------- transpose Wh -> WhT bf16
__global__ __launch_bounds__(256) void transpose_bf16_kernel(const float* __restrict__ A,
                                                             short* __restrict__ At,
                                                             int Ftot) {
  __shared__ short t[32][33];
  int c0 = blockIdx.x * 32, n0 = blockIdx.y * 32;
  int tx = threadIdx.x & 31, ty = threadIdx.x >> 5;
  for (int r = ty; r < 32; r += 8)
    t[tx][r] = f2bf(A[(size_t)(n0 + r) * Ftot + c0 + tx]);
  __syncthreads();
  for (int r = ty; r < 32; r += 8)
    At[(size_t)(c0 + r) * N_NODES + n0 + tx] = t[r][tx];
}

// ---------------------------------------------------------------- attention PV, LDS-staged V
// P = exp2(LR(f1s_i + f2s_j) - m_i), m_i = LR(f1s_i + gmax_h) >= masked row max.
// 128-j stages (half the barriers of 64-j), single Vt buffer, XOR-swizzled 16B groups
// (write sl^(c&15), read ((hh<<2)|grp)^(row_l&15)) — conflict-free both sides.
// NO output atomics: each jc writes its own partial buffer; act_kernel reduces.
// l_i via ones-MFMA on blockIdx.x==0 blocks -> atomicAdd lsum (tiny).
template<int NF, int JC>
__global__ __launch_bounds__(256)
void pv_stage_kernel(const float* __restrict__ f1s,
                     const float* __restrict__ f2s,
                     const float* __restrict__ gmax,
                     const unsigned int* __restrict__ bits,
                     const short* __restrict__ WhT,
                     float* __restrict__ pbuf,      // JC partial buffers
                     float* __restrict__ lsum,
                     int H, int Fp) {
  constexpr int CH = N_NODES / JC;
  constexpr int NCH = CH / 384;                 // 384-j chunks (12 mask words)
  constexpr int COLS = NF * 16;
  static_assert(NCH * 384 == CH, "chunking");

  __shared__ float f2sh[CH];
  __shared__ short Vt[COLS * 128];              // 128 j per stage

  int h = blockIdx.z;
  int cb0 = blockIdx.x * COLS;
  int rb = blockIdx.y % 96;
  int jc = blockIdx.y / 96;
  int i0 = rb * 64;
  int hN = h * N_NODES, hFp = h * Fp;
  int Ftot = H * Fp;
  int tid = threadIdx.x;
  int w = tid >> 6, l = tid & 63;
  int row_l = l & 15, grp = l >> 4;

  {
    const float4* src = reinterpret_cast<const float4*>(f2s + hN + jc * CH);
    float4* dst = reinterpret_cast<float4*>(f2sh);
    for (int idx = tid; idx < CH / 4; idx += 256) dst[idx] = src[idx];
  }

  int i = i0 + w * 16 + row_l;
  float fi = f1s[hN + i];
  float gm = gmax[h];
  float mi = fmaxf(fi + gm, 0.2f * (fi + gm));
  float c1 = fi - mi;
  float c2 = 0.2f * fi - mi;
  const unsigned int* mbase = bits + (size_t)i * MASK_WORDS + jc * (CH / 32);

  int vcol = hFp + cb0;
  const short* Wbase = WhT + (size_t)vcol * N_NODES;

  const short ONE = (short)0x3F80;
  short8 ones8 = {ONE, ONE, ONE, ONE, ONE, ONE, ONE, ONE};
  bool needL = (blockIdx.x == 0);

  f32x4 acc[NF];
#pragma unroll
  for (int n = 0; n < NF; ++n) acc[n] = f32x4{0, 0, 0, 0};
  f32x4 accl = f32x4{0, 0, 0, 0};

#pragma unroll 1
  for (int ch = 0; ch < NCH; ++ch) {
    unsigned mw[12];
    {
      const uint4* mp = reinterpret_cast<const uint4*>(mbase + ch * 12);
#pragma unroll
      for (int q = 0; q < 3; ++q) {
        uint4 m = mp[q];
        mw[q * 4 + 0] = m.x; mw[q * 4 + 1] = m.y;
        mw[q * 4 + 2] = m.z; mw[q * 4 + 3] = m.w;
      }
    }
#pragma unroll 1
    for (int s2 = 0; s2 < 3; ++s2) {            // three 128-j stages per chunk
      int j0 = jc * CH + ch * 384 + s2 * 128;
      __syncthreads();                          // Vt free
#pragma unroll
      for (int idx = tid; idx < COLS * 16; idx += 256) {
        int c = idx >> 4, sl = idx & 15;
        *reinterpret_cast<short8*>(&Vt[c * 128 + ((sl ^ (c & 15)) * 8)]) =
            *reinterpret_cast<const short8*>(Wbase + (size_t)c * N_NODES + j0 + sl * 8);
      }
      __syncthreads();                          // Vt ready
#pragma unroll
      for (int hh = 0; hh < 4; ++hh) {
        unsigned wb = (mw[s2 * 4 + hh] >> (grp * 8)) & 0xffu;
        int jrel = ch * 384 + s2 * 128 + hh * 32 + grp * 8;
        f32x4 fA = *reinterpret_cast<const f32x4*>(&f2sh[jrel]);
        f32x4 fB = *reinterpret_cast<const f32x4*>(&f2sh[jrel + 4]);
        float p[8];
#pragma unroll
        for (int e = 0; e < 8; ++e) {
          float f = (e < 4 ? fA[e] : fB[e - 4]);
          float t = fmaxf(f + c1, f * 0.2f + c2);
          t = ((wb >> e) & 1u) ? t : -1.0e30f;
          p[e] = exp2f(t);
        }
        union { short8 s8; unsigned u32[4]; } au;
#pragma unroll
        for (int ep = 0; ep < 4; ++ep) {
          unsigned r;
          asm("v_cvt_pk_bf16_f32 %0, %1, %2" : "=v"(r) : "v"(p[2 * ep]), "v"(p[2 * ep + 1]));
          au.u32[ep] = r;
        }
        int j8s = ((hh << 2) | grp) ^ row_l;    // row_l in 0..15
#pragma unroll
        for (int n = 0; n < NF; ++n) {
          short8 b = *reinterpret_cast<const short8*>(&Vt[(n * 16 + row_l) * 128 + j8s * 8]);
          acc[n] = __builtin_amdgcn_mfma_f32_16x16x32_bf16(au.s8, b, acc[n], 0, 0, 0);
        }
        if (needL)
          accl = __builtin_amdgcn_mfma_f32_16x16x32_bf16(au.s8, ones8, accl, 0, 0, 0);
      }
    }
  }

  // ---- plain stores into this jc's partial buffer
  float* outp = pbuf + (size_t)jc * N_NODES * Ftot;
#pragma unroll
  for (int n = 0; n < NF; ++n) {
#pragma unroll
    for (int k = 0; k < 4; ++k) {
      int r = i0 + w * 16 + grp * 4 + k;
      outp[(size_t)r * Ftot + vcol + n * 16 + row_l] = acc[n][k];
    }
  }
  if (needL && row_l == 0) {
#pragma unroll
    for (int k = 0; k < 4; ++k)
      atomicAdd(&lsum[hN + i0 + w * 16 + grp * 4 + k], accl[k]);
  }
}

// ---------------------------------------------------------------- reduce + activation
// dst = act( (sum_jc pbuf[jc]) / lsum ); act 0 = elu, 1 = sigmoid(elu)
__global__ __launch_bounds__(256) void act_kernel(float* __restrict__ dst,
                                                  const float* __restrict__ pbuf,
                                                  int njc, size_t pstride,
                                                  const float* __restrict__ lsum,
                                                  int n4, int ftotShift, int fpShift, int act) {
  int idx = blockIdx.x * blockDim.x + threadIdx.x;
  if (idx >= n4) return;
  int idx4 = idx * 4;
  int r = idx4 >> ftotShift;
  int c = idx4 & ((1 << ftotShift) - 1);
  int h = c >> fpShift;
  float li = 1.0f / lsum[h * N_NODES + r];
  float4 v = reinterpret_cast<const float4*>(pbuf)[idx];
  float vv[4] = {v.x, v.y, v.z, v.w};
  for (int q = 1; q < njc; ++q) {
    float4 u = *reinterpret_cast<const float4*>(pbuf + q * pstride + (size_t)idx4);
    vv[0] += u.x; vv[1] += u.y; vv[2] += u.z; vv[3] += u.w;
  }
#pragma unroll
  for (int e = 0; e < 4; ++e) {
    float x = vv[e] * li;
    x = x > 0.0f ? x : exp2f(x * LOG2E) - 1.0f;
    if (act == 1) x = 1.0f / (1.0f + exp2f(-x * LOG2E));
    vv[e] = x;
  }
  reinterpret_cast<float4*>(dst)[idx] = make_float4(vv[0], vv[1], vv[2], vv[3]);
}

// ---------------------------------------------------------------- host
extern "C" void kernel_launch(void* const* d_in, const int* in_sizes, int n_in,
                              void* d_out, int out_size, void* d_ws, size_t ws_size,
                              hipStream_t stream) {
  const float* x     = (const float*)d_in[0];
  const int*   adj   = (const int*)d_in[1];
  const float* W1    = (const float*)d_in[2];
  const float* a1    = (const float*)d_in[3];
  const float* Wo    = (const float*)d_in[4];
  const float* ao    = (const float*)d_in[5];
  const float* W2    = (const float*)d_in[6];
  const float* a2    = (const float*)d_in[7];
  const float* Wo2   = (const float*)d_in[8];
  const float* ao2   = (const float*)d_in[9];
  const float* lin_w = (const float*)d_in[10];
  const float* lin_b = (const float*)d_in[11];
  float* out = (float*)d_out;

  float* ws = (float*)d_ws;
  unsigned int* bits = (unsigned int*)ws;            // 1,179,648 u32
  float* Wh   = ws + 1179648;                        // 6144*256
  float* bufA = Wh + 1572864;
  float* bufB = bufA + 1572864;
  float* Bcat = bufB + 1572864;                      // 65536
  float* f1   = Bcat + 65536;                        // 24576
  float* f2   = f1 + 24576;
  float* lsum = f2 + 24576;                          // 24576
  float* gmaxb = lsum + 24576;                       // 16
  short* WhT  = (short*)(gmaxb + 16);                // 6144*256 bf16
  short* BtW  = WhT + 1572864;                       // 384*256 bf16
  float* pbuf = (float*)(BtW + 98304);               // 8 x 6144*256 f32 partials (25 MB... 4x for Ftot256)

  const size_t PS256 = (size_t)6144 * 256;           // partial stride, Ftot=256
  const size_t PS128 = (size_t)6144 * 128;

  dim3 b256(256);

  bitpack_kernel<<<N_NODES, b256, 0, stream>>>(adj, bits);

  // ================= layer 1 multi-head (H=4, Fp=64), elu concat
  repack_W_kernel<<<(4 * 256 * 64 + 255) / 256, b256, 0, stream>>>(W1, Bcat, 4, 256, 64);
  transpose_w_kernel<<<dim3(8, 8), b256, 0, stream>>>(Bcat, BtW, 256, 256);
  gemm_mfma_kernel<<<dim3(4, 96), b256, 0, stream>>>(x, BtW, Wh, 256, 256, nullptr, 0);
  f1f2_kernel<<<(4 * N_NODES) / 4, b256, 0, stream>>>(Wh, a1, f1, f2, 4, 64);
  gmax_kernel<<<4, b256, 0, stream>>>(f2, gmaxb);
  transpose_bf16_kernel<<<dim3(8, 192), b256, 0, stream>>>(Wh, WhT, 256);
  hipMemsetAsync(lsum, 0, (size_t)24576 * 4, stream);
  pv_stage_kernel<4, 4><<<dim3(1, 384, 4), b256, 0, stream>>>(f1, f2, gmaxb, bits, WhT, pbuf, lsum, 4, 64);
  act_kernel<<<dim3(1536), b256, 0, stream>>>(bufA, pbuf, 4, PS256, lsum, 6144 * 256 / 4, 8, 6, 0);

  // ================= out-attention 1 (H=1, Fp=256), sigmoid(elu)
  transpose_w_kernel<<<dim3(8, 8), b256, 0, stream>>>(Wo, BtW, 256, 256);
  gemm_mfma_kernel<<<dim3(4, 96), b256, 0, stream>>>(bufA, BtW, Wh, 256, 256, nullptr, 0);
  f1f2_kernel<<<(N_NODES) / 4, b256, 0, stream>>>(Wh, ao, f1, f2, 1, 256);
  gmax_kernel<<<1, b256, 0, stream>>>(f2, gmaxb);
  transpose_bf16_kernel<<<dim3(8, 192), b256, 0, stream>>>(Wh, WhT, 256);
  hipMemsetAsync(lsum, 0, (size_t)24576 * 4, stream);
  pv_stage_kernel<8, 4><<<dim3(2, 384, 1), b256, 0, stream>>>(f1, f2, gmaxb, bits, WhT, pbuf, lsum, 1, 256);
  act_kernel<<<dim3(1536), b256, 0, stream>>>(bufB, pbuf, 4, PS256, lsum, 6144 * 256 / 4, 8, 8, 1);

  // ================= layer 2 multi-head (H=4, Fp=32), elu concat
  repack_W_kernel<<<(4 * 256 * 32 + 255) / 256, b256, 0, stream>>>(W2, Bcat, 4, 256, 32);
  transpose_w_kernel<<<dim3(8, 4), b256, 0, stream>>>(Bcat, BtW, 256, 128);
  gemm_mfma_kernel<<<dim3(2, 96), b256, 0, stream>>>(bufB, BtW, Wh, 256, 128, nullptr, 0);
  f1f2_kernel<<<(4 * N_NODES) / 4, b256, 0, stream>>>(Wh, a2, f1, f2, 4, 32);
  gmax_kernel<<<4, b256, 0, stream>>>(f2, gmaxb);
  transpose_bf16_kernel<<<dim3(4, 192), b256, 0, stream>>>(Wh, WhT, 128);
  hipMemsetAsync(lsum, 0, (size_t)24576 * 4, stream);
  pv_stage_kernel<2, 4><<<dim3(1, 384, 4), b256, 0, stream>>>(f1, f2, gmaxb, bits, WhT, pbuf, lsum, 4, 32);
  act_kernel<<<dim3(768), b256, 0, stream>>>(bufA, pbuf, 4, PS128, lsum, 6144 * 128 / 4, 7, 5, 0);

  // ================= out-attention 2 (H=1, Fp=128), sigmoid(elu)
  transpose_w_kernel<<<dim3(4, 4), b256, 0, stream>>>(Wo2, BtW, 128, 128);
  gemm_mfma_kernel<<<dim3(2, 96), b256, 0, stream>>>(bufA, BtW, Wh, 128, 128, nullptr, 0);
  f1f2_kernel<<<(N_NODES) / 4, b256, 0, stream>>>(Wh, ao2, f1, f2, 1, 128);
  gmax_kernel<<<1, b256, 0, stream>>>(f2, gmaxb);
  transpose_bf16_kernel<<<dim3(4, 192), b256, 0, stream>>>(Wh, WhT, 128);
  hipMemsetAsync(lsum, 0, (size_t)24576 * 4, stream);
  pv_stage_kernel<8, 8><<<dim3(1, 768, 1), b256, 0, stream>>>(f1, f2, gmaxb, bits, WhT, pbuf, lsum, 1, 128);
  act_kernel<<<dim3(768), b256, 0, stream>>>(bufB, pbuf, 8, PS128, lsum, 6144 * 128 / 4, 7, 7, 1);

  // ================= final linear + relu
  transpose_w_kernel<<<dim3(4, 12), b256, 0, stream>>>(lin_w, BtW, 128, 379);
  gemm_mfma_kernel<<<dim3(6, 96), b256, 0, stream>>>(bufB, BtW, out, 128, 379, lin_b, 1);
}

// Round 14
// 369.011 us; speedup vs baseline: 9.1640x; 1.1067x over previous
//
#include <hip/hip_runtime.h>
#include <hip/hip_bf16.h>

#define N_NODES 6144
#define MASK_WORDS 192  // 6144/32
#define LOG2E 1.44269504088896f

using short8 = __attribute__((ext_vector_type(8))) short;
using s16x4  = __attribute__((ext_vector_type(4))) short;
using f32x4  = __attribute__((ext_vector_type(4))) float;

// f32 -> bf16 bits, round-to-nearest-even
__device__ inline unsigned f2bf_u(float f) {
  unsigned u = __builtin_bit_cast(unsigned, f);
  u += 0x7fff + ((u >> 16) & 1);
  return u >> 16;
}
__device__ inline short f2bf(float f) { return (short)f2bf_u(f); }

// ---------------------------------------------------------------- bitpack
__global__ __launch_bounds__(256) void bitpack_kernel(const int* __restrict__ adj,
                                                      unsigned int* __restrict__ bits) {
  int row = blockIdx.x;
  int wave = threadIdx.x >> 6, lane = threadIdx.x & 63;
  const int* p = adj + (long)row * N_NODES;
  for (int base = wave * 64; base < N_NODES; base += 256) {
    unsigned long long m = __ballot(p[base + lane] > 0);
    if (lane == 0) {
      bits[row * MASK_WORDS + (base >> 5)] = (unsigned int)m;
      bits[row * MASK_WORDS + (base >> 5) + 1] = (unsigned int)(m >> 32);
    }
  }
}

// ---------------------------------------------------------------- W repack
// W [H][Fin][Fp] -> B [Fin][H*Fp]
__global__ __launch_bounds__(256) void repack_W_kernel(const float* __restrict__ W,
                                                       float* __restrict__ B,
                                                       int H, int Fin, int Fp) {
  int idx = blockIdx.x * blockDim.x + threadIdx.x;
  int total = H * Fin * Fp;
  if (idx >= total) return;
  int h = idx / (Fin * Fp);
  int rem = idx - h * (Fin * Fp);
  int k = rem / Fp, c = rem - k * Fp;
  B[k * (H * Fp) + h * Fp + c] = W[idx];
}

// ---------------------------------------------------------------- weight transpose+cvt
// B [K][Nc] f32 -> Bt [NcPad][K] bf16 (zero-fill cols >= Nc). grid (K/32, NcPad/32)
__global__ __launch_bounds__(256) void transpose_w_kernel(const float* __restrict__ B,
                                                          short* __restrict__ Bt,
                                                          int K, int Nc) {
  __shared__ short t[32][33];
  int k0 = blockIdx.x * 32, c0 = blockIdx.y * 32;
  int tx = threadIdx.x & 31, ty = threadIdx.x >> 5;
  for (int r = ty; r < 32; r += 8) {
    float v = (c0 + tx < Nc) ? B[(size_t)(k0 + r) * Nc + c0 + tx] : 0.0f;
    t[tx][r] = f2bf(v);
  }
  __syncthreads();
  for (int r = ty; r < 32; r += 8)
    Bt[(size_t)(c0 + r) * K + k0 + tx] = t[r][tx];
}

// ---------------------------------------------------------------- MFMA GEMM
// C[M,Nc] f32 = A[M,K] f32 @ Bt[NcPad][K] bf16 (+bias, act 1 = relu).
__global__ __launch_bounds__(256) void gemm_mfma_kernel(const float* __restrict__ A,
                                                        const short* __restrict__ Bt,
                                                        float* __restrict__ C,
                                                        int K, int Nc,
                                                        const float* __restrict__ bias,
                                                        int act) {
  __shared__ short As[64][40];
  __shared__ short Bs[64][40];
  int m0 = blockIdx.y * 64, n0 = blockIdx.x * 64;
  int tid = threadIdx.x;
  int w = tid >> 6, l = tid & 63, row_l = l & 15, grp = l >> 4;

  f32x4 acc[4] = {f32x4{0,0,0,0}, f32x4{0,0,0,0}, f32x4{0,0,0,0}, f32x4{0,0,0,0}};

  for (int k0 = 0; k0 < K; k0 += 32) {
    __syncthreads();
#pragma unroll
    for (int s = 0; s < 2; ++s) {
      int idx = tid + s * 256;
      int r = idx >> 3, q = idx & 7;
      float4 v = *reinterpret_cast<const float4*>(&A[(size_t)(m0 + r) * K + k0 + q * 4]);
      s16x4 sv = {f2bf(v.x), f2bf(v.y), f2bf(v.z), f2bf(v.w)};
      *reinterpret_cast<s16x4*>(&As[r][q * 4]) = sv;
    }
    {
      int c = tid >> 2, kq = tid & 3;
      *reinterpret_cast<short8*>(&Bs[c][kq * 8]) =
          *reinterpret_cast<const short8*>(&Bt[(size_t)(n0 + c) * K + k0 + kq * 8]);
    }
    __syncthreads();
    short8 a = *reinterpret_cast<const short8*>(&As[w * 16 + row_l][grp * 8]);
#pragma unroll
    for (int n = 0; n < 4; ++n) {
      short8 b = *reinterpret_cast<const short8*>(&Bs[n * 16 + row_l][grp * 8]);
      acc[n] = __builtin_amdgcn_mfma_f32_16x16x32_bf16(a, b, acc[n], 0, 0, 0);
    }
  }

#pragma unroll
  for (int n = 0; n < 4; ++n) {
#pragma unroll
    for (int k = 0; k < 4; ++k) {
      int row = m0 + w * 16 + grp * 4 + k;
      int col = n0 + n * 16 + row_l;
      if (col < Nc) {
        float v = acc[n][k];
        if (bias) v += bias[col];
        if (act == 1) v = fmaxf(v, 0.0f);
        C[(size_t)row * Nc + col] = v;
      }
    }
  }
}

// ---------------------------------------------------------------- f1/f2 (scaled by log2 e)
__global__ __launch_bounds__(256) void f1f2_kernel(const float* __restrict__ Wh,
                                                   const float* __restrict__ a,
                                                   float* __restrict__ f1,
                                                   float* __restrict__ f2,
                                                   int H, int Fp) {
  int g = blockIdx.x * 4 + (threadIdx.x >> 6);
  int lane = threadIdx.x & 63;
  if (g >= H * N_NODES) return;
  int h = g / N_NODES, n = g - h * N_NODES;
  int Ftot = H * Fp;
  const float* row = Wh + (long)n * Ftot + h * Fp;
  const float* av1 = a + h * 2 * Fp;
  const float* av2 = av1 + Fp;
  float s1 = 0.f, s2 = 0.f;
  for (int c = lane; c < Fp; c += 64) {
    float w = row[c];
    s1 += w * av1[c];
    s2 += w * av2[c];
  }
  for (int off = 32; off > 0; off >>= 1) {
    s1 += __shfl_down(s1, off);
    s2 += __shfl_down(s2, off);
  }
  if (lane == 0) { f1[g] = s1 * LOG2E; f2[g] = s2 * LOG2E; }
}

// ---------------------------------------------------------------- per-head global max of f2
__global__ __launch_bounds__(256) void gmax_kernel(const float* __restrict__ f2s,
                                                   float* __restrict__ gmax) {
  __shared__ float red[4];
  int h = blockIdx.x;
  int tid = threadIdx.x, lane = tid & 63, w = tid >> 6;
  const float* p = f2s + h * N_NODES;
  float m = -3.0e38f;
  for (int j = tid; j < N_NODES; j += 256) m = fmaxf(m, p[j]);
  for (int off = 32; off > 0; off >>= 1) m = fmaxf(m, __shfl_xor(m, off));
  if (lane == 0) red[w] = m;
  __syncthreads();
  if (tid == 0) gmax[h] = fmaxf(fmaxf(red[0], red[1]), fmaxf(red[2], red[3]));
}

// ---------------------------------------------------------------- E/F tables
// E = exp2(f2s), F = exp2(0.2*f2s) over H*N elements (vectorized by 4)
__global__ __launch_bounds__(256) void ef_kernel(const float* __restrict__ f2s,
                                                 float* __restrict__ E,
                                                 float* __restrict__ F,
                                                 int total4) {
  int idx = blockIdx.x * blockDim.x + threadIdx.x;
  if (idx >= total4) return;
  float4 v = reinterpret_cast<const float4*>(f2s)[idx];
  float4 e, f;
  e.x = exp2f(v.x); e.y = exp2f(v.y); e.z = exp2f(v.z); e.w = exp2f(v.w);
  f.x = exp2f(0.2f * v.x); f.y = exp2f(0.2f * v.y);
  f.z = exp2f(0.2f * v.z); f.w = exp2f(0.2f * v.w);
  reinterpret_cast<float4*>(E)[idx] = e;
  reinterpret_cast<float4*>(F)[idx] = f;
}

// ---------------------------------------------------------------- transpose Wh -> WhT bf16
__global__ __launch_bounds__(256) void transpose_bf16_kernel(const float* __restrict__ A,
                                                             short* __restrict__ At,
                                                             int Ftot) {
  __shared__ short t[32][33];
  int c0 = blockIdx.x * 32, n0 = blockIdx.y * 32;
  int tx = threadIdx.x & 31, ty = threadIdx.x >> 5;
  for (int r = ty; r < 32; r += 8)
    t[tx][r] = f2bf(A[(size_t)(n0 + r) * Ftot + c0 + tx]);
  __syncthreads();
  for (int r = ty; r < 32; r += 8)
    At[(size_t)(c0 + r) * N_NODES + n0 + tx] = t[r][tx];
}

// ---------------------------------------------------------------- attention PV, LDS-staged V
// FACTORIZED P-GEN (no inner-loop exp):
//   P = max(A_i*E_j, B_i*F_j) masked, where A=exp2(f1s-mi), B=exp2(0.2*f1s-mi),
//   E=exp2(f2s), F=exp2(0.2*f2s) (precomputed tables), mi = LR(f1s+gmax) >= row max.
// 128-j stages, XOR-swizzled Vt (conflict-free write+read), partial buffers per jc,
// l_i via ones-MFMA on blockIdx.x==0 -> atomicAdd lsum.
template<int NF, int JC>
__global__ __launch_bounds__(256)
void pv_stage_kernel(const float* __restrict__ f1s,
                     const float* __restrict__ Etab,
                     const float* __restrict__ Ftab,
                     const float* __restrict__ gmax,
                     const unsigned int* __restrict__ bits,
                     const short* __restrict__ WhT,
                     float* __restrict__ pbuf,
                     float* __restrict__ lsum,
                     int H, int Fp) {
  constexpr int CH = N_NODES / JC;
  constexpr int NCH = CH / 384;
  constexpr int COLS = NF * 16;
  static_assert(NCH * 384 == CH, "chunking");

  __shared__ float efsh[2 * CH];                // E then F
  __shared__ short Vt[COLS * 128];

  int h = blockIdx.z;
  int cb0 = blockIdx.x * COLS;
  int rb = blockIdx.y % 96;
  int jc = blockIdx.y / 96;
  int i0 = rb * 64;
  int hN = h * N_NODES, hFp = h * Fp;
  int Ftot = H * Fp;
  int tid = threadIdx.x;
  int w = tid >> 6, l = tid & 63;
  int row_l = l & 15, grp = l >> 4;

  {
    const float4* srcE = reinterpret_cast<const float4*>(Etab + hN + jc * CH);
    const float4* srcF = reinterpret_cast<const float4*>(Ftab + hN + jc * CH);
    float4* dst = reinterpret_cast<float4*>(efsh);
    for (int idx = tid; idx < CH / 4; idx += 256) {
      dst[idx] = srcE[idx];
      dst[CH / 4 + idx] = srcF[idx];
    }
  }

  int i = i0 + w * 16 + row_l;
  float fi = f1s[hN + i];
  float gm = gmax[h];
  float mi = fmaxf(fi + gm, 0.2f * (fi + gm));
  float Ai = exp2f(fi - mi);
  float Bi = exp2f(0.2f * fi - mi);
  const unsigned int* mbase = bits + (size_t)i * MASK_WORDS + jc * (CH / 32);

  int vcol = hFp + cb0;
  const short* Wbase = WhT + (size_t)vcol * N_NODES;

  const short ONE = (short)0x3F80;
  short8 ones8 = {ONE, ONE, ONE, ONE, ONE, ONE, ONE, ONE};
  bool needL = (blockIdx.x == 0);

  f32x4 acc[NF];
#pragma unroll
  for (int n = 0; n < NF; ++n) acc[n] = f32x4{0, 0, 0, 0};
  f32x4 accl = f32x4{0, 0, 0, 0};

#pragma unroll 1
  for (int ch = 0; ch < NCH; ++ch) {
    unsigned mw[12];
    {
      const uint4* mp = reinterpret_cast<const uint4*>(mbase + ch * 12);
#pragma unroll
      for (int q = 0; q < 3; ++q) {
        uint4 m = mp[q];
        mw[q * 4 + 0] = m.x; mw[q * 4 + 1] = m.y;
        mw[q * 4 + 2] = m.z; mw[q * 4 + 3] = m.w;
      }
    }
#pragma unroll 1
    for (int s2 = 0; s2 < 3; ++s2) {            // three 128-j stages per chunk
      int j0 = jc * CH + ch * 384 + s2 * 128;
      __syncthreads();                          // Vt free
#pragma unroll
      for (int idx = tid; idx < COLS * 16; idx += 256) {
        int c = idx >> 4, sl = idx & 15;
        *reinterpret_cast<short8*>(&Vt[c * 128 + ((sl ^ (c & 15)) * 8)]) =
            *reinterpret_cast<const short8*>(Wbase + (size_t)c * N_NODES + j0 + sl * 8);
      }
      __syncthreads();                          // Vt ready
#pragma unroll
      for (int hh = 0; hh < 4; ++hh) {
        unsigned wb = (mw[s2 * 4 + hh] >> (grp * 8)) & 0xffu;
        int jrel = ch * 384 + s2 * 128 + hh * 32 + grp * 8;
        f32x4 eA = *reinterpret_cast<const f32x4*>(&efsh[jrel]);
        f32x4 eB = *reinterpret_cast<const f32x4*>(&efsh[jrel + 4]);
        f32x4 fA = *reinterpret_cast<const f32x4*>(&efsh[CH + jrel]);
        f32x4 fB = *reinterpret_cast<const f32x4*>(&efsh[CH + jrel + 4]);
        float p[8];
#pragma unroll
        for (int e = 0; e < 8; ++e) {
          float Ee = (e < 4 ? eA[e] : eB[e - 4]);
          float Fe = (e < 4 ? fA[e] : fB[e - 4]);
          float pe = fmaxf(Ai * Ee, Bi * Fe);
          p[e] = ((wb >> e) & 1u) ? pe : 0.0f;
        }
        union { short8 s8; unsigned u32[4]; } au;
#pragma unroll
        for (int ep = 0; ep < 4; ++ep) {
          unsigned r;
          asm("v_cvt_pk_bf16_f32 %0, %1, %2" : "=v"(r) : "v"(p[2 * ep]), "v"(p[2 * ep + 1]));
          au.u32[ep] = r;
        }
        int j8s = ((hh << 2) | grp) ^ row_l;
#pragma unroll
        for (int n = 0; n < NF; ++n) {
          short8 b = *reinterpret_cast<const short8*>(&Vt[(n * 16 + row_l) * 128 + j8s * 8]);
          acc[n] = __builtin_amdgcn_mfma_f32_16x16x32_bf16(au.s8, b, acc[n], 0, 0, 0);
        }
        if (needL)
          accl = __builtin_amdgcn_mfma_f32_16x16x32_bf16(au.s8, ones8, accl, 0, 0, 0);
      }
    }
  }

  float* outp = pbuf + (size_t)jc * N_NODES * Ftot;
#pragma unroll
  for (int n = 0; n < NF; ++n) {
#pragma unroll
    for (int k = 0; k < 4; ++k) {
      int r = i0 + w * 16 + grp * 4 + k;
      outp[(size_t)r * Ftot + vcol + n * 16 + row_l] = acc[n][k];
    }
  }
  if (needL && row_l == 0) {
#pragma unroll
    for (int k = 0; k < 4; ++k)
      atomicAdd(&lsum[hN + i0 + w * 16 + grp * 4 + k], accl[k]);
  }
}

// ---------------------------------------------------------------- reduce + activation
// dst = act( (sum_jc pbuf[jc]) / lsum ); act 0 = elu, 1 = sigmoid(elu)
__global__ __launch_bounds__(256) void act_kernel(float* __restrict__ dst,
                                                  const float* __restrict__ pbuf,
                                                  int njc, size_t pstride,
                                                  const float* __restrict__ lsum,
                                                  int n4, int ftotShift, int fpShift, int act) {
  int idx = blockIdx.x * blockDim.x + threadIdx.x;
  if (idx >= n4) return;
  int idx4 = idx * 4;
  int r = idx4 >> ftotShift;
  int c = idx4 & ((1 << ftotShift) - 1);
  int h = c >> fpShift;
  float li = 1.0f / lsum[h * N_NODES + r];
  float4 v = reinterpret_cast<const float4*>(pbuf)[idx];
  float vv[4] = {v.x, v.y, v.z, v.w};
  for (int q = 1; q < njc; ++q) {
    float4 u = *reinterpret_cast<const float4*>(pbuf + q * pstride + (size_t)idx4);
    vv[0] += u.x; vv[1] += u.y; vv[2] += u.z; vv[3] += u.w;
  }
#pragma unroll
  for (int e = 0; e < 4; ++e) {
    float x = vv[e] * li;
    x = x > 0.0f ? x : exp2f(x * LOG2E) - 1.0f;
    if (act == 1) x = 1.0f / (1.0f + exp2f(-x * LOG2E));
    vv[e] = x;
  }
  reinterpret_cast<float4*>(dst)[idx] = make_float4(vv[0], vv[1], vv[2], vv[3]);
}

// ---------------------------------------------------------------- host
extern "C" void kernel_launch(void* const* d_in, const int* in_sizes, int n_in,
                              void* d_out, int out_size, void* d_ws, size_t ws_size,
                              hipStream_t stream) {
  const float* x     = (const float*)d_in[0];
  const int*   adj   = (const int*)d_in[1];
  const float* W1    = (const float*)d_in[2];
  const float* a1    = (const float*)d_in[3];
  const float* Wo    = (const float*)d_in[4];
  const float* ao    = (const float*)d_in[5];
  const float* W2    = (const float*)d_in[6];
  const float* a2    = (const float*)d_in[7];
  const float* Wo2   = (const float*)d_in[8];
  const float* ao2   = (const float*)d_in[9];
  const float* lin_w = (const float*)d_in[10];
  const float* lin_b = (const float*)d_in[11];
  float* out = (float*)d_out;

  float* ws = (float*)d_ws;
  unsigned int* bits = (unsigned int*)ws;            // 1,179,648 u32
  float* Wh   = ws + 1179648;                        // 6144*256
  float* bufA = Wh + 1572864;
  float* bufB = bufA + 1572864;
  float* Bcat = bufB + 1572864;                      // 65536
  float* f1   = Bcat + 65536;                        // 24576
  float* f2   = f1 + 24576;
  float* lsum = f2 + 24576;                          // 24576
  float* gmaxb = lsum + 24576;                       // 16
  float* Etab = gmaxb + 16;                          // 24576
  float* Ftab = Etab + 24576;                        // 24576
  short* WhT  = (short*)(Ftab + 24576);              // 6144*256 bf16
  short* BtW  = WhT + 1572864;                       // 384*256 bf16
  float* pbuf = (float*)(BtW + 98304);               // up to 4 x 6144*256 f32 partials

  const size_t PS256 = (size_t)6144 * 256;
  const size_t PS128 = (size_t)6144 * 128;

  dim3 b256(256);

  bitpack_kernel<<<N_NODES, b256, 0, stream>>>(adj, bits);

  // ================= layer 1 multi-head (H=4, Fp=64), elu concat
  repack_W_kernel<<<(4 * 256 * 64 + 255) / 256, b256, 0, stream>>>(W1, Bcat, 4, 256, 64);
  transpose_w_kernel<<<dim3(8, 8), b256, 0, stream>>>(Bcat, BtW, 256, 256);
  gemm_mfma_kernel<<<dim3(4, 96), b256, 0, stream>>>(x, BtW, Wh, 256, 256, nullptr, 0);
  f1f2_kernel<<<(4 * N_NODES) / 4, b256, 0, stream>>>(Wh, a1, f1, f2, 4, 64);
  gmax_kernel<<<4, b256, 0, stream>>>(f2, gmaxb);
  ef_kernel<<<dim3(24), b256, 0, stream>>>(f2, Etab, Ftab, 4 * N_NODES / 4);
  transpose_bf16_kernel<<<dim3(8, 192), b256, 0, stream>>>(Wh, WhT, 256);
  hipMemsetAsync(lsum, 0, (size_t)24576 * 4, stream);
  pv_stage_kernel<4, 4><<<dim3(1, 384, 4), b256, 0, stream>>>(f1, Etab, Ftab, gmaxb, bits, WhT, pbuf, lsum, 4, 64);
  act_kernel<<<dim3(1536), b256, 0, stream>>>(bufA, pbuf, 4, PS256, lsum, 6144 * 256 / 4, 8, 6, 0);

  // ================= out-attention 1 (H=1, Fp=256), sigmoid(elu)
  transpose_w_kernel<<<dim3(8, 8), b256, 0, stream>>>(Wo, BtW, 256, 256);
  gemm_mfma_kernel<<<dim3(4, 96), b256, 0, stream>>>(bufA, BtW, Wh, 256, 256, nullptr, 0);
  f1f2_kernel<<<(N_NODES) / 4, b256, 0, stream>>>(Wh, ao, f1, f2, 1, 256);
  gmax_kernel<<<1, b256, 0, stream>>>(f2, gmaxb);
  ef_kernel<<<dim3(6), b256, 0, stream>>>(f2, Etab, Ftab, N_NODES / 4);
  transpose_bf16_kernel<<<dim3(8, 192), b256, 0, stream>>>(Wh, WhT, 256);
  hipMemsetAsync(lsum, 0, (size_t)24576 * 4, stream);
  pv_stage_kernel<8, 4><<<dim3(2, 384, 1), b256, 0, stream>>>(f1, Etab, Ftab, gmaxb, bits, WhT, pbuf, lsum, 1, 256);
  act_kernel<<<dim3(1536), b256, 0, stream>>>(bufB, pbuf, 4, PS256, lsum, 6144 * 256 / 4, 8, 8, 1);

  // ================= layer 2 multi-head (H=4, Fp=32), elu concat
  repack_W_kernel<<<(4 * 256 * 32 + 255) / 256, b256, 0, stream>>>(W2, Bcat, 4, 256, 32);
  transpose_w_kernel<<<dim3(8, 4), b256, 0, stream>>>(Bcat, BtW, 256, 128);
  gemm_mfma_kernel<<<dim3(2, 96), b256, 0, stream>>>(bufB, BtW, Wh, 256, 128, nullptr, 0);
  f1f2_kernel<<<(4 * N_NODES) / 4, b256, 0, stream>>>(Wh, a2, f1, f2, 4, 32);
  gmax_kernel<<<4, b256, 0, stream>>>(f2, gmaxb);
  ef_kernel<<<dim3(24), b256, 0, stream>>>(f2, Etab, Ftab, 4 * N_NODES / 4);
  transpose_bf16_kernel<<<dim3(4, 192), b256, 0, stream>>>(Wh, WhT, 128);
  hipMemsetAsync(lsum, 0, (size_t)24576 * 4, stream);
  pv_stage_kernel<2, 4><<<dim3(1, 384, 4), b256, 0, stream>>>(f1, Etab, Ftab, gmaxb, bits, WhT, pbuf, lsum, 4, 32);
  act_kernel<<<dim3(768), b256, 0, stream>>>(bufA, pbuf, 4, PS128, lsum, 6144 * 128 / 4, 7, 5, 0);

  // ================= out-attention 2 (H=1, Fp=128), sigmoid(elu)
  transpose_w_kernel<<<dim3(4, 4), b256, 0, stream>>>(Wo2, BtW, 128, 128);
  gemm_mfma_kernel<<<dim3(2, 96), b256, 0, stream>>>(bufA, BtW, Wh, 128, 128, nullptr, 0);
  f1f2_kernel<<<(N_NODES) / 4, b256, 0, stream>>>(Wh, ao2, f1, f2, 1, 128);
  gmax_kernel<<<1, b256, 0, stream>>>(f2, gmaxb);
  ef_kernel<<<dim3(6), b256, 0, stream>>>(f2, Etab, Ftab, N_NODES / 4);
  transpose_bf16_kernel<<<dim3(4, 192), b256, 0, stream>>>(Wh, WhT, 128);
  hipMemsetAsync(lsum, 0, (size_t)24576 * 4, stream);
  pv_stage_kernel<8, 8><<<dim3(1, 768, 1), b256, 0, stream>>>(f1, Etab, Ftab, gmaxb, bits, WhT, pbuf, lsum, 1, 128);
  act_kernel<<<dim3(768), b256, 0, stream>>>(bufB, pbuf, 8, PS128, lsum, 6144 * 128 / 4, 7, 7, 1);

  // ================= final linear + relu
  transpose_w_kernel<<<dim3(4, 12), b256, 0, stream>>>(lin_w, BtW, 128, 379);
  gemm_mfma_kernel<<<dim3(6, 96), b256, 0, stream>>>(bufB, BtW, out, 128, 379, lin_b, 1);
}

// Round 15
// 366.494 us; speedup vs baseline: 9.2269x; 1.0069x over previous
//
#include <hip/hip_runtime.h>
#include <hip/hip_bf16.h>

#define N_NODES 6144
#define MASK_WORDS 192  // 6144/32
#define LOG2E 1.44269504088896f

using short8 = __attribute__((ext_vector_type(8))) short;
using s16x4  = __attribute__((ext_vector_type(4))) short;
using f32x4  = __attribute__((ext_vector_type(4))) float;

// f32 -> bf16 bits, round-to-nearest-even
__device__ inline unsigned f2bf_u(float f) {
  unsigned u = __builtin_bit_cast(unsigned, f);
  u += 0x7fff + ((u >> 16) & 1);
  return u >> 16;
}
__device__ inline short f2bf(float f) { return (short)f2bf_u(f); }

// async global->LDS, 16B per lane; lds base must be wave-uniform
__device__ inline void glds16(const short* g, short* l) {
  __builtin_amdgcn_global_load_lds(
      (const __attribute__((address_space(1))) unsigned int*)g,
      (__attribute__((address_space(3))) unsigned int*)l, 16, 0, 0);
}

// ---------------------------------------------------------------- bitpack
__global__ __launch_bounds__(256) void bitpack_kernel(const int* __restrict__ adj,
                                                      unsigned int* __restrict__ bits) {
  int row = blockIdx.x;
  int wave = threadIdx.x >> 6, lane = threadIdx.x & 63;
  const int* p = adj + (long)row * N_NODES;
  for (int base = wave * 64; base < N_NODES; base += 256) {
    unsigned long long m = __ballot(p[base + lane] > 0);
    if (lane == 0) {
      bits[row * MASK_WORDS + (base >> 5)] = (unsigned int)m;
      bits[row * MASK_WORDS + (base >> 5) + 1] = (unsigned int)(m >> 32);
    }
  }
}

// ---------------------------------------------------------------- W repack
// W [H][Fin][Fp] -> B [Fin][H*Fp]
__global__ __launch_bounds__(256) void repack_W_kernel(const float* __restrict__ W,
                                                       float* __restrict__ B,
                                                       int H, int Fin, int Fp) {
  int idx = blockIdx.x * blockDim.x + threadIdx.x;
  int total = H * Fin * Fp;
  if (idx >= total) return;
  int h = idx / (Fin * Fp);
  int rem = idx - h * (Fin * Fp);
  int k = rem / Fp, c = rem - k * Fp;
  B[k * (H * Fp) + h * Fp + c] = W[idx];
}

// ---------------------------------------------------------------- weight transpose+cvt
// B [K][Nc] f32 -> Bt [NcPad][K] bf16 (zero-fill cols >= Nc). grid (K/32, NcPad/32)
__global__ __launch_bounds__(256) void transpose_w_kernel(const float* __restrict__ B,
                                                          short* __restrict__ Bt,
                                                          int K, int Nc) {
  __shared__ short t[32][33];
  int k0 = blockIdx.x * 32, c0 = blockIdx.y * 32;
  int tx = threadIdx.x & 31, ty = threadIdx.x >> 5;
  for (int r = ty; r < 32; r += 8) {
    float v = (c0 + tx < Nc) ? B[(size_t)(k0 + r) * Nc + c0 + tx] : 0.0f;
    t[tx][r] = f2bf(v);
  }
  __syncthreads();
  for (int r = ty; r < 32; r += 8)
    Bt[(size_t)(c0 + r) * K + k0 + tx] = t[r][tx];
}

// ---------------------------------------------------------------- MFMA GEMM
// C[M,Nc] f32 = A[M,K] f32 @ Bt[NcPad][K] bf16 (+bias, act 1 = relu).
__global__ __launch_bounds__(256) void gemm_mfma_kernel(const float* __restrict__ A,
                                                        const short* __restrict__ Bt,
                                                        float* __restrict__ C,
                                                        int K, int Nc,
                                                        const float* __restrict__ bias,
                                                        int act) {
  __shared__ short As[64][40];
  __shared__ short Bs[64][40];
  int m0 = blockIdx.y * 64, n0 = blockIdx.x * 64;
  int tid = threadIdx.x;
  int w = tid >> 6, l = tid & 63, row_l = l & 15, grp = l >> 4;

  f32x4 acc[4] = {f32x4{0,0,0,0}, f32x4{0,0,0,0}, f32x4{0,0,0,0}, f32x4{0,0,0,0}};

  for (int k0 = 0; k0 < K; k0 += 32) {
    __syncthreads();
#pragma unroll
    for (int s = 0; s < 2; ++s) {
      int idx = tid + s * 256;
      int r = idx >> 3, q = idx & 7;
      float4 v = *reinterpret_cast<const float4*>(&A[(size_t)(m0 + r) * K + k0 + q * 4]);
      s16x4 sv = {f2bf(v.x), f2bf(v.y), f2bf(v.z), f2bf(v.w)};
      *reinterpret_cast<s16x4*>(&As[r][q * 4]) = sv;
    }
    {
      int c = tid >> 2, kq = tid & 3;
      *reinterpret_cast<short8*>(&Bs[c][kq * 8]) =
          *reinterpret_cast<const short8*>(&Bt[(size_t)(n0 + c) * K + k0 + kq * 8]);
    }
    __syncthreads();
    short8 a = *reinterpret_cast<const short8*>(&As[w * 16 + row_l][grp * 8]);
#pragma unroll
    for (int n = 0; n < 4; ++n) {
      short8 b = *reinterpret_cast<const short8*>(&Bs[n * 16 + row_l][grp * 8]);
      acc[n] = __builtin_amdgcn_mfma_f32_16x16x32_bf16(a, b, acc[n], 0, 0, 0);
    }
  }

#pragma unroll
  for (int n = 0; n < 4; ++n) {
#pragma unroll
    for (int k = 0; k < 4; ++k) {
      int row = m0 + w * 16 + grp * 4 + k;
      int col = n0 + n * 16 + row_l;
      if (col < Nc) {
        float v = acc[n][k];
        if (bias) v += bias[col];
        if (act == 1) v = fmaxf(v, 0.0f);
        C[(size_t)row * Nc + col] = v;
      }
    }
  }
}

// ---------------------------------------------------------------- f1/f2 (scaled by log2 e)
__global__ __launch_bounds__(256) void f1f2_kernel(const float* __restrict__ Wh,
                                                   const float* __restrict__ a,
                                                   float* __restrict__ f1,
                                                   float* __restrict__ f2,
                                                   int H, int Fp) {
  int g = blockIdx.x * 4 + (threadIdx.x >> 6);
  int lane = threadIdx.x & 63;
  if (g >= H * N_NODES) return;
  int h = g / N_NODES, n = g - h * N_NODES;
  int Ftot = H * Fp;
  const float* row = Wh + (long)n * Ftot + h * Fp;
  const float* av1 = a + h * 2 * Fp;
  const float* av2 = av1 + Fp;
  float s1 = 0.f, s2 = 0.f;
  for (int c = lane; c < Fp; c += 64) {
    float w = row[c];
    s1 += w * av1[c];
    s2 += w * av2[c];
  }
  for (int off = 32; off > 0; off >>= 1) {
    s1 += __shfl_down(s1, off);
    s2 += __shfl_down(s2, off);
  }
  if (lane == 0) { f1[g] = s1 * LOG2E; f2[g] = s2 * LOG2E; }
}

// ---------------------------------------------------------------- per-head global max of f2
__global__ __launch_bounds__(256) void gmax_kernel(const float* __restrict__ f2s,
                                                   float* __restrict__ gmax) {
  __shared__ float red[4];
  int h = blockIdx.x;
  int tid = threadIdx.x, lane = tid & 63, w = tid >> 6;
  const float* p = f2s + h * N_NODES;
  float m = -3.0e38f;
  for (int j = tid; j < N_NODES; j += 256) m = fmaxf(m, p[j]);
  for (int off = 32; off > 0; off >>= 1) m = fmaxf(m, __shfl_xor(m, off));
  if (lane == 0) red[w] = m;
  __syncthreads();
  if (tid == 0) gmax[h] = fmaxf(fmaxf(red[0], red[1]), fmaxf(red[2], red[3]));
}

// ---------------------------------------------------------------- E/F tables
// E = exp2(f2s), F = exp2(0.2*f2s)
__global__ __launch_bounds__(256) void ef_kernel(const float* __restrict__ f2s,
                                                 float* __restrict__ E,
                                                 float* __restrict__ F,
                                                 int total4) {
  int idx = blockIdx.x * blockDim.x + threadIdx.x;
  if (idx >= total4) return;
  float4 v = reinterpret_cast<const float4*>(f2s)[idx];
  float4 e, f;
  e.x = exp2f(v.x); e.y = exp2f(v.y); e.z = exp2f(v.z); e.w = exp2f(v.w);
  f.x = exp2f(0.2f * v.x); f.y = exp2f(0.2f * v.y);
  f.z = exp2f(0.2f * v.z); f.w = exp2f(0.2f * v.w);
  reinterpret_cast<float4*>(E)[idx] = e;
  reinterpret_cast<float4*>(F)[idx] = f;
}

// ---------------------------------------------------------------- transpose Wh -> WhT bf16
__global__ __launch_bounds__(256) void transpose_bf16_kernel(const float* __restrict__ A,
                                                             short* __restrict__ At,
                                                             int Ftot) {
  __shared__ short t[32][33];
  int c0 = blockIdx.x * 32, n0 = blockIdx.y * 32;
  int tx = threadIdx.x & 31, ty = threadIdx.x >> 5;
  for (int r = ty; r < 32; r += 8)
    t[tx][r] = f2bf(A[(size_t)(n0 + r) * Ftot + c0 + tx]);
  __syncthreads();
  for (int r = ty; r < 32; r += 8)
    At[(size_t)(c0 + r) * N_NODES + n0 + tx] = t[r][tx];
}

// ---------------------------------------------------------------- attention PV
// Factorized P: P = max(Ai*E_j, Bi*F_j) masked; Ai,Bi per row, E/F tables in LDS.
// V staging: ASYNC global_load_lds into double-buffered Vt. LDS layout is linear;
// the XOR swizzle is applied to the GLOBAL source address (lane loads
// V[c][sl'^(c&15)] into linear slot (c,sl')), so ds_read stays conflict-free with
// the same j8s = ((hh<<2)|grp)^row_l read index. Loads for stage s+1 issue right
// after stage s's barrier; the s_waitcnt vmcnt(0) sits at the NEXT iteration top,
// so compute(s) hides the latency of loads(s+1).
template<int NF, int JC>
__global__ __launch_bounds__(256)
void pv_stage_kernel(const float* __restrict__ f1s,
                     const float* __restrict__ Etab,
                     const float* __restrict__ Ftab,
                     const float* __restrict__ gmax,
                     const unsigned int* __restrict__ bits,
                     const short* __restrict__ WhT,
                     float* __restrict__ pbuf,
                     float* __restrict__ lsum,
                     int H, int Fp) {
  constexpr int CH = N_NODES / JC;
  constexpr int COLS = NF * 16;
  constexpr int NS = CH / 128;              // 128-j stages
  constexpr int NITER = COLS / 16;          // glds chunks per stage (256 thr x 16B)
  static_assert(NS * 128 == CH, "chunking");

  __shared__ float efsh[2 * CH];            // E then F
  __shared__ short Vt[2 * COLS * 128];      // double buffer, linear layout

  int h = blockIdx.z;
  int cb0 = blockIdx.x * COLS;
  int rb = blockIdx.y % 96;
  int jc = blockIdx.y / 96;
  int i0 = rb * 64;
  int hN = h * N_NODES, hFp = h * Fp;
  int Ftot = H * Fp;
  int tid = threadIdx.x;
  int w = tid >> 6, l = tid & 63;
  int row_l = l & 15, grp = l >> 4;

  int vcol = hFp + cb0;
  const short* Wbase = WhT + (size_t)vcol * N_NODES;

  // pre-swizzled per-lane global offset (const across stages/chunks up to it*16 rows)
  int c0t = tid >> 4;                        // c mod 16 for this thread
  int slp = (tid & 15) ^ c0t;                // swizzled source 16B-slot
  size_t goff = (size_t)c0t * N_NODES + slp * 8 + jc * CH;

  // issue one stage's loads into buffer `bsel`
  auto issue = [&](int bsel, int j0) {
#pragma unroll
    for (int it = 0; it < NITER; ++it) {
      const short* g = Wbase + goff + (size_t)it * 16 * N_NODES + j0;
      short* lp = &Vt[bsel * (COLS * 128) + it * 2048 + w * 512];
      glds16(g, lp);
    }
  };

  issue(0, 0);                               // prefetch stage 0 (j rel to jc*CH via goff)

  {
    const float4* srcE = reinterpret_cast<const float4*>(Etab + hN + jc * CH);
    const float4* srcF = reinterpret_cast<const float4*>(Ftab + hN + jc * CH);
    float4* dst = reinterpret_cast<float4*>(efsh);
    for (int idx = tid; idx < CH / 4; idx += 256) {
      dst[idx] = srcE[idx];
      dst[CH / 4 + idx] = srcF[idx];
    }
  }

  int i = i0 + w * 16 + row_l;
  float fi = f1s[hN + i];
  float gm = gmax[h];
  float mi = fmaxf(fi + gm, 0.2f * (fi + gm));
  float Ai = exp2f(fi - mi);
  float Bi = exp2f(0.2f * fi - mi);
  const uint4* mp = reinterpret_cast<const uint4*>(bits + (size_t)i * MASK_WORDS + jc * (CH / 32));

  const short ONE = (short)0x3F80;
  short8 ones8 = {ONE, ONE, ONE, ONE, ONE, ONE, ONE, ONE};
  bool needL = (blockIdx.x == 0);

  f32x4 acc[NF];
#pragma unroll
  for (int n = 0; n < NF; ++n) acc[n] = f32x4{0, 0, 0, 0};
  f32x4 accl = f32x4{0, 0, 0, 0};

#pragma unroll 1
  for (int s = 0; s < NS; ++s) {
    asm volatile("s_waitcnt vmcnt(0)" ::: "memory");
    __builtin_amdgcn_sched_barrier(0);
    __syncthreads();                         // Vt[s&1] fully landed, everyone aligned
    if (s + 1 < NS) issue((s + 1) & 1, (s + 1) * 128);
    const short* vb = &Vt[(s & 1) * (COLS * 128)];
    uint4 mq = mp[s];
    unsigned mwa[4] = {mq.x, mq.y, mq.z, mq.w};
#pragma unroll
    for (int hh = 0; hh < 4; ++hh) {
      unsigned wb = (mwa[hh] >> (grp * 8)) & 0xffu;
      int jrel = s * 128 + hh * 32 + grp * 8;
      f32x4 eA = *reinterpret_cast<const f32x4*>(&efsh[jrel]);
      f32x4 eB = *reinterpret_cast<const f32x4*>(&efsh[jrel + 4]);
      f32x4 fA = *reinterpret_cast<const f32x4*>(&efsh[CH + jrel]);
      f32x4 fB = *reinterpret_cast<const f32x4*>(&efsh[CH + jrel + 4]);
      float p[8];
#pragma unroll
      for (int e = 0; e < 8; ++e) {
        float Ee = (e < 4 ? eA[e] : eB[e - 4]);
        float Fe = (e < 4 ? fA[e] : fB[e - 4]);
        float pe = fmaxf(Ai * Ee, Bi * Fe);
        p[e] = ((wb >> e) & 1u) ? pe : 0.0f;
      }
      union { short8 s8; unsigned u32[4]; } au;
#pragma unroll
      for (int ep = 0; ep < 4; ++ep) {
        unsigned r;
        asm("v_cvt_pk_bf16_f32 %0, %1, %2" : "=v"(r) : "v"(p[2 * ep]), "v"(p[2 * ep + 1]));
        au.u32[ep] = r;
      }
      int j8s = ((hh << 2) | grp) ^ row_l;
#pragma unroll
      for (int n = 0; n < NF; ++n) {
        short8 b = *reinterpret_cast<const short8*>(&vb[(n * 16 + row_l) * 128 + j8s * 8]);
        acc[n] = __builtin_amdgcn_mfma_f32_16x16x32_bf16(au.s8, b, acc[n], 0, 0, 0);
      }
      if (needL)
        accl = __builtin_amdgcn_mfma_f32_16x16x32_bf16(au.s8, ones8, accl, 0, 0, 0);
    }
  }

  float* outp = pbuf + (size_t)jc * N_NODES * Ftot;
#pragma unroll
  for (int n = 0; n < NF; ++n) {
#pragma unroll
    for (int k = 0; k < 4; ++k) {
      int r = i0 + w * 16 + grp * 4 + k;
      outp[(size_t)r * Ftot + vcol + n * 16 + row_l] = acc[n][k];
    }
  }
  if (needL && row_l == 0) {
#pragma unroll
    for (int k = 0; k < 4; ++k)
      atomicAdd(&lsum[hN + i0 + w * 16 + grp * 4 + k], accl[k]);
  }
}

// ---------------------------------------------------------------- reduce + activation
// dst = act( (sum_jc pbuf[jc]) / lsum ); act 0 = elu, 1 = sigmoid(elu)
__global__ __launch_bounds__(256) void act_kernel(float* __restrict__ dst,
                                                  const float* __restrict__ pbuf,
                                                  int njc, size_t pstride,
                                                  const float* __restrict__ lsum,
                                                  int n4, int ftotShift, int fpShift, int act) {
  int idx = blockIdx.x * blockDim.x + threadIdx.x;
  if (idx >= n4) return;
  int idx4 = idx * 4;
  int r = idx4 >> ftotShift;
  int c = idx4 & ((1 << ftotShift) - 1);
  int h = c >> fpShift;
  float li = 1.0f / lsum[h * N_NODES + r];
  float4 v = reinterpret_cast<const float4*>(pbuf)[idx];
  float vv[4] = {v.x, v.y, v.z, v.w};
  for (int q = 1; q < njc; ++q) {
    float4 u = *reinterpret_cast<const float4*>(pbuf + q * pstride + (size_t)idx4);
    vv[0] += u.x; vv[1] += u.y; vv[2] += u.z; vv[3] += u.w;
  }
#pragma unroll
  for (int e = 0; e < 4; ++e) {
    float x = vv[e] * li;
    x = x > 0.0f ? x : exp2f(x * LOG2E) - 1.0f;
    if (act == 1) x = 1.0f / (1.0f + exp2f(-x * LOG2E));
    vv[e] = x;
  }
  reinterpret_cast<float4*>(dst)[idx] = make_float4(vv[0], vv[1], vv[2], vv[3]);
}

// ---------------------------------------------------------------- host
extern "C" void kernel_launch(void* const* d_in, const int* in_sizes, int n_in,
                              void* d_out, int out_size, void* d_ws, size_t ws_size,
                              hipStream_t stream) {
  const float* x     = (const float*)d_in[0];
  const int*   adj   = (const int*)d_in[1];
  const float* W1    = (const float*)d_in[2];
  const float* a1    = (const float*)d_in[3];
  const float* Wo    = (const float*)d_in[4];
  const float* ao    = (const float*)d_in[5];
  const float* W2    = (const float*)d_in[6];
  const float* a2    = (const float*)d_in[7];
  const float* Wo2   = (const float*)d_in[8];
  const float* ao2   = (const float*)d_in[9];
  const float* lin_w = (const float*)d_in[10];
  const float* lin_b = (const float*)d_in[11];
  float* out = (float*)d_out;

  float* ws = (float*)d_ws;
  unsigned int* bits = (unsigned int*)ws;            // 1,179,648 u32
  float* Wh   = ws + 1179648;                        // 6144*256
  float* bufA = Wh + 1572864;
  float* bufB = bufA + 1572864;
  float* Bcat = bufB + 1572864;                      // 65536
  float* f1   = Bcat + 65536;                        // 24576
  float* f2   = f1 + 24576;
  float* lsum = f2 + 24576;                          // 24576
  float* gmaxb = lsum + 24576;                       // 16
  float* Etab = gmaxb + 16;                          // 24576
  float* Ftab = Etab + 24576;                        // 24576
  short* WhT  = (short*)(Ftab + 24576);              // 6144*256 bf16
  short* BtW  = WhT + 1572864;                       // 384*256 bf16
  float* pbuf = (float*)(BtW + 98304);               // up to 4 x 6144*256 f32 partials

  const size_t PS256 = (size_t)6144 * 256;
  const size_t PS128 = (size_t)6144 * 128;

  dim3 b256(256);

  bitpack_kernel<<<N_NODES, b256, 0, stream>>>(adj, bits);

  // ================= layer 1 multi-head (H=4, Fp=64), elu concat
  repack_W_kernel<<<(4 * 256 * 64 + 255) / 256, b256, 0, stream>>>(W1, Bcat, 4, 256, 64);
  transpose_w_kernel<<<dim3(8, 8), b256, 0, stream>>>(Bcat, BtW, 256, 256);
  gemm_mfma_kernel<<<dim3(4, 96), b256, 0, stream>>>(x, BtW, Wh, 256, 256, nullptr, 0);
  f1f2_kernel<<<(4 * N_NODES) / 4, b256, 0, stream>>>(Wh, a1, f1, f2, 4, 64);
  gmax_kernel<<<4, b256, 0, stream>>>(f2, gmaxb);
  ef_kernel<<<dim3(24), b256, 0, stream>>>(f2, Etab, Ftab, 4 * N_NODES / 4);
  transpose_bf16_kernel<<<dim3(8, 192), b256, 0, stream>>>(Wh, WhT, 256);
  hipMemsetAsync(lsum, 0, (size_t)24576 * 4, stream);
  pv_stage_kernel<4, 4><<<dim3(1, 384, 4), b256, 0, stream>>>(f1, Etab, Ftab, gmaxb, bits, WhT, pbuf, lsum, 4, 64);
  act_kernel<<<dim3(1536), b256, 0, stream>>>(bufA, pbuf, 4, PS256, lsum, 6144 * 256 / 4, 8, 6, 0);

  // ================= out-attention 1 (H=1, Fp=256), sigmoid(elu)
  transpose_w_kernel<<<dim3(8, 8), b256, 0, stream>>>(Wo, BtW, 256, 256);
  gemm_mfma_kernel<<<dim3(4, 96), b256, 0, stream>>>(bufA, BtW, Wh, 256, 256, nullptr, 0);
  f1f2_kernel<<<(N_NODES) / 4, b256, 0, stream>>>(Wh, ao, f1, f2, 1, 256);
  gmax_kernel<<<1, b256, 0, stream>>>(f2, gmaxb);
  ef_kernel<<<dim3(6), b256, 0, stream>>>(f2, Etab, Ftab, N_NODES / 4);
  transpose_bf16_kernel<<<dim3(8, 192), b256, 0, stream>>>(Wh, WhT, 256);
  hipMemsetAsync(lsum, 0, (size_t)24576 * 4, stream);
  pv_stage_kernel<8, 4><<<dim3(2, 384, 1), b256, 0, stream>>>(f1, Etab, Ftab, gmaxb, bits, WhT, pbuf, lsum, 1, 256);
  act_kernel<<<dim3(1536), b256, 0, stream>>>(bufB, pbuf, 4, PS256, lsum, 6144 * 256 / 4, 8, 8, 1);

  // ================= layer 2 multi-head (H=4, Fp=32), elu concat
  repack_W_kernel<<<(4 * 256 * 32 + 255) / 256, b256, 0, stream>>>(W2, Bcat, 4, 256, 32);
  transpose_w_kernel<<<dim3(8, 4), b256, 0, stream>>>(Bcat, BtW, 256, 128);
  gemm_mfma_kernel<<<dim3(2, 96), b256, 0, stream>>>(bufB, BtW, Wh, 256, 128, nullptr, 0);
  f1f2_kernel<<<(4 * N_NODES) / 4, b256, 0, stream>>>(Wh, a2, f1, f2, 4, 32);
  gmax_kernel<<<4, b256, 0, stream>>>(f2, gmaxb);
  ef_kernel<<<dim3(24), b256, 0, stream>>>(f2, Etab, Ftab, 4 * N_NODES / 4);
  transpose_bf16_kernel<<<dim3(4, 192), b256, 0, stream>>>(Wh, WhT, 128);
  hipMemsetAsync(lsum, 0, (size_t)24576 * 4, stream);
  pv_stage_kernel<2, 4><<<dim3(1, 384, 4), b256, 0, stream>>>(f1, Etab, Ftab, gmaxb, bits, WhT, pbuf, lsum, 4, 32);
  act_kernel<<<dim3(768), b256, 0, stream>>>(bufA, pbuf, 4, PS128, lsum, 6144 * 128 / 4, 7, 5, 0);

  // ================= out-attention 2 (H=1, Fp=128), sigmoid(elu)
  transpose_w_kernel<<<dim3(4, 4), b256, 0, stream>>>(Wo2, BtW, 128, 128);
  gemm_mfma_kernel<<<dim3(2, 96), b256, 0, stream>>>(bufA, BtW, Wh, 128, 128, nullptr, 0);
  f1f2_kernel<<<(N_NODES) / 4, b256, 0, stream>>>(Wh, ao2, f1, f2, 1, 128);
  gmax_kernel<<<1, b256, 0, stream>>>(f2, gmaxb);
  ef_kernel<<<dim3(6), b256, 0, stream>>>(f2, Etab, Ftab, N_NODES / 4);
  transpose_bf16_kernel<<<dim3(4, 192), b256, 0, stream>>>(Wh, WhT, 128);
  hipMemsetAsync(lsum, 0, (size_t)24576 * 4, stream);
  pv_stage_kernel<8, 8><<<dim3(1, 768, 1), b256, 0, stream>>>(f1, Etab, Ftab, gmaxb, bits, WhT, pbuf, lsum, 1, 128);
  act_kernel<<<dim3(768), b256, 0, stream>>>(bufB, pbuf, 8, PS128, lsum, 6144 * 128 / 4, 7, 7, 1);

  // ================= final linear + relu
  transpose_w_kernel<<<dim3(4, 12), b256, 0, stream>>>(lin_w, BtW, 128, 379);
  gemm_mfma_kernel<<<dim3(6, 96), b256, 0, stream>>>(bufB, BtW, out, 128, 379, lin_b, 1);
}

// Round 16
// 357.033 us; speedup vs baseline: 9.4714x; 1.0265x over previous
//
#include <hip/hip_runtime.h>
#include <hip/hip_bf16.h>

#define N_NODES 6144
#define MASK_WORDS 192  // 6144/32
#define LOG2E 1.44269504088896f

using short8 = __attribute__((ext_vector_type(8))) short;
using s16x4  = __attribute__((ext_vector_type(4))) short;
using f32x4  = __attribute__((ext_vector_type(4))) float;
using half2v = __attribute__((ext_vector_type(2))) _Float16;
using half8v = __attribute__((ext_vector_type(8))) _Float16;
struct Half2x4 { half2v v[4]; };

// f32 -> bf16 bits, round-to-nearest-even
__device__ inline unsigned f2bf_u(float f) {
  unsigned u = __builtin_bit_cast(unsigned, f);
  u += 0x7fff + ((u >> 16) & 1);
  return u >> 16;
}
__device__ inline short f2bf(float f) { return (short)f2bf_u(f); }

// async global->LDS, 16B per lane; lds base must be wave-uniform
__device__ inline void glds16(const short* g, short* l) {
  __builtin_amdgcn_global_load_lds(
      (const __attribute__((address_space(1))) unsigned int*)g,
      (__attribute__((address_space(3))) unsigned int*)l, 16, 0, 0);
}

// ---------------------------------------------------------------- bitpack
__global__ __launch_bounds__(256) void bitpack_kernel(const int* __restrict__ adj,
                                                      unsigned int* __restrict__ bits) {
  int row = blockIdx.x;
  int wave = threadIdx.x >> 6, lane = threadIdx.x & 63;
  const int* p = adj + (long)row * N_NODES;
  for (int base = wave * 64; base < N_NODES; base += 256) {
    unsigned long long m = __ballot(p[base + lane] > 0);
    if (lane == 0) {
      bits[row * MASK_WORDS + (base >> 5)] = (unsigned int)m;
      bits[row * MASK_WORDS + (base >> 5) + 1] = (unsigned int)(m >> 32);
    }
  }
}

// ---------------------------------------------------------------- W repack
__global__ __launch_bounds__(256) void repack_W_kernel(const float* __restrict__ W,
                                                       float* __restrict__ B,
                                                       int H, int Fin, int Fp) {
  int idx = blockIdx.x * blockDim.x + threadIdx.x;
  int total = H * Fin * Fp;
  if (idx >= total) return;
  int h = idx / (Fin * Fp);
  int rem = idx - h * (Fin * Fp);
  int k = rem / Fp, c = rem - k * Fp;
  B[k * (H * Fp) + h * Fp + c] = W[idx];
}

// ---------------------------------------------------------------- weight transpose+cvt (bf16 for GEMM)
__global__ __launch_bounds__(256) void transpose_w_kernel(const float* __restrict__ B,
                                                          short* __restrict__ Bt,
                                                          int K, int Nc) {
  __shared__ short t[32][33];
  int k0 = blockIdx.x * 32, c0 = blockIdx.y * 32;
  int tx = threadIdx.x & 31, ty = threadIdx.x >> 5;
  for (int r = ty; r < 32; r += 8) {
    float v = (c0 + tx < Nc) ? B[(size_t)(k0 + r) * Nc + c0 + tx] : 0.0f;
    t[tx][r] = f2bf(v);
  }
  __syncthreads();
  for (int r = ty; r < 32; r += 8)
    Bt[(size_t)(c0 + r) * K + k0 + tx] = t[r][tx];
}

// ---------------------------------------------------------------- MFMA GEMM (bf16)
__global__ __launch_bounds__(256) void gemm_mfma_kernel(const float* __restrict__ A,
                                                        const short* __restrict__ Bt,
                                                        float* __restrict__ C,
                                                        int K, int Nc,
                                                        const float* __restrict__ bias,
                                                        int act) {
  __shared__ short As[64][40];
  __shared__ short Bs[64][40];
  int m0 = blockIdx.y * 64, n0 = blockIdx.x * 64;
  int tid = threadIdx.x;
  int w = tid >> 6, l = tid & 63, row_l = l & 15, grp = l >> 4;

  f32x4 acc[4] = {f32x4{0,0,0,0}, f32x4{0,0,0,0}, f32x4{0,0,0,0}, f32x4{0,0,0,0}};

  for (int k0 = 0; k0 < K; k0 += 32) {
    __syncthreads();
#pragma unroll
    for (int s = 0; s < 2; ++s) {
      int idx = tid + s * 256;
      int r = idx >> 3, q = idx & 7;
      float4 v = *reinterpret_cast<const float4*>(&A[(size_t)(m0 + r) * K + k0 + q * 4]);
      s16x4 sv = {f2bf(v.x), f2bf(v.y), f2bf(v.z), f2bf(v.w)};
      *reinterpret_cast<s16x4*>(&As[r][q * 4]) = sv;
    }
    {
      int c = tid >> 2, kq = tid & 3;
      *reinterpret_cast<short8*>(&Bs[c][kq * 8]) =
          *reinterpret_cast<const short8*>(&Bt[(size_t)(n0 + c) * K + k0 + kq * 8]);
    }
    __syncthreads();
    short8 a = *reinterpret_cast<const short8*>(&As[w * 16 + row_l][grp * 8]);
#pragma unroll
    for (int n = 0; n < 4; ++n) {
      short8 b = *reinterpret_cast<const short8*>(&Bs[n * 16 + row_l][grp * 8]);
      acc[n] = __builtin_amdgcn_mfma_f32_16x16x32_bf16(a, b, acc[n], 0, 0, 0);
    }
  }

#pragma unroll
  for (int n = 0; n < 4; ++n) {
#pragma unroll
    for (int k = 0; k < 4; ++k) {
      int row = m0 + w * 16 + grp * 4 + k;
      int col = n0 + n * 16 + row_l;
      if (col < Nc) {
        float v = acc[n][k];
        if (bias) v += bias[col];
        if (act == 1) v = fmaxf(v, 0.0f);
        C[(size_t)row * Nc + col] = v;
      }
    }
  }
}

// ---------------------------------------------------------------- f1/f2 (scaled by log2 e)
__global__ __launch_bounds__(256) void f1f2_kernel(const float* __restrict__ Wh,
                                                   const float* __restrict__ a,
                                                   float* __restrict__ f1,
                                                   float* __restrict__ f2,
                                                   int H, int Fp) {
  int g = blockIdx.x * 4 + (threadIdx.x >> 6);
  int lane = threadIdx.x & 63;
  if (g >= H * N_NODES) return;
  int h = g / N_NODES, n = g - h * N_NODES;
  int Ftot = H * Fp;
  const float* row = Wh + (long)n * Ftot + h * Fp;
  const float* av1 = a + h * 2 * Fp;
  const float* av2 = av1 + Fp;
  float s1 = 0.f, s2 = 0.f;
  for (int c = lane; c < Fp; c += 64) {
    float w = row[c];
    s1 += w * av1[c];
    s2 += w * av2[c];
  }
  for (int off = 32; off > 0; off >>= 1) {
    s1 += __shfl_down(s1, off);
    s2 += __shfl_down(s2, off);
  }
  if (lane == 0) { f1[g] = s1 * LOG2E; f2[g] = s2 * LOG2E; }
}

// ---------------------------------------------------------------- per-head global max of f2
__global__ __launch_bounds__(256) void gmax_kernel(const float* __restrict__ f2s,
                                                   float* __restrict__ gmax) {
  __shared__ float red[4];
  int h = blockIdx.x;
  int tid = threadIdx.x, lane = tid & 63, w = tid >> 6;
  const float* p = f2s + h * N_NODES;
  float m = -3.0e38f;
  for (int j = tid; j < N_NODES; j += 256) m = fmaxf(m, p[j]);
  for (int off = 32; off > 0; off >>= 1) m = fmaxf(m, __shfl_xor(m, off));
  if (lane == 0) red[w] = m;
  __syncthreads();
  if (tid == 0) gmax[h] = fmaxf(fmaxf(red[0], red[1]), fmaxf(red[2], red[3]));
}

// ---------------------------------------------------------------- E/F tables (fp16, shifted by gmax)
// E' = exp2(f2s - gmax_h) <= 1, F' = exp2(0.2*(f2s - gmax_h)) <= 1
__global__ __launch_bounds__(256) void ef_kernel(const float* __restrict__ f2s,
                                                 const float* __restrict__ gmax,
                                                 _Float16* __restrict__ E,
                                                 _Float16* __restrict__ F,
                                                 int total4) {
  int idx = blockIdx.x * blockDim.x + threadIdx.x;
  if (idx >= total4) return;
  int h = (idx * 4) / N_NODES;
  float gm = gmax[h];
  float4 v = reinterpret_cast<const float4*>(f2s)[idx];
  _Float16 e[4], f[4];
  float vv[4] = {v.x, v.y, v.z, v.w};
#pragma unroll
  for (int q = 0; q < 4; ++q) {
    float d = vv[q] - gm;
    e[q] = (_Float16)exp2f(d);
    f[q] = (_Float16)exp2f(0.2f * d);
  }
  *reinterpret_cast<s16x4*>(E + idx * 4) = *reinterpret_cast<s16x4*>(e);
  *reinterpret_cast<s16x4*>(F + idx * 4) = *reinterpret_cast<s16x4*>(f);
}

// ---------------------------------------------------------------- transpose Wh -> WhT fp16
__global__ __launch_bounds__(256) void transpose_h_kernel(const float* __restrict__ A,
                                                          short* __restrict__ At,
                                                          int Ftot) {
  __shared__ short t[32][33];
  int c0 = blockIdx.x * 32, n0 = blockIdx.y * 32;
  int tx = threadIdx.x & 31, ty = threadIdx.x >> 5;
  for (int r = ty; r < 32; r += 8) {
    _Float16 hv = (_Float16)A[(size_t)(n0 + r) * Ftot + c0 + tx];
    t[tx][r] = __builtin_bit_cast(short, hv);
  }
  __syncthreads();
  for (int r = ty; r < 32; r += 8)
    At[(size_t)(c0 + r) * N_NODES + n0 + tx] = t[r][tx];
}

// ---------------------------------------------------------------- attention PV (fp16 packed)
// P = max(Ai'*E'_j, Bi'*F'_j) * mask, all fp16; MFMA f32_16x16x32_f16, f32 accum.
// 64-j stages, TRIPLE-buffered async glds, counted vmcnt(NITER), raw s_barrier
// (one per stage; loads fly across ~2 compute phases). XOR swizzle applied on the
// GLOBAL source slot (sl^(c&7)); read slot j8s = (hh*4+grp)^(row_l&7).
template<int NF, int JC>
__global__ __launch_bounds__(256)
void pv_stage_kernel(const float* __restrict__ f1s,
                     const _Float16* __restrict__ Etab,
                     const _Float16* __restrict__ Ftab,
                     const float* __restrict__ gmax,
                     const unsigned int* __restrict__ bits,
                     const short* __restrict__ WhT,
                     float* __restrict__ pbuf,
                     float* __restrict__ lsum,
                     int H, int Fp) {
  constexpr int CH = N_NODES / JC;
  constexpr int COLS = NF * 16;
  constexpr int NS = CH / 64;               // 64-j stages
  constexpr int NITER = COLS / 32;          // glds per wave per stage (256thr x 16B = 4KB)
  constexpr int STEP = COLS * 64;           // shorts per buffer
  constexpr int NCH = CH / 384;
  static_assert(NCH * 384 == CH, "chunking");

  __shared__ _Float16 Esh[CH];
  __shared__ _Float16 Fsh[CH];
  __shared__ short Vt[3 * STEP];            // triple buffer, linear

  int h = blockIdx.z;
  int cb0 = blockIdx.x * COLS;
  int rb = blockIdx.y % 96;
  int jc = blockIdx.y / 96;
  int i0 = rb * 64;
  int hN = h * N_NODES, hFp = h * Fp;
  int Ftot = H * Fp;
  int tid = threadIdx.x;
  int w = tid >> 6, l = tid & 63;
  int row_l = l & 15, grp = l >> 4;

  int vcol = hFp + cb0;
  const short* Wbase = WhT + (size_t)vcol * N_NODES;

  // stage E/F tables first (plain LDS writes), sync before any glds
  {
    const half8v* srcE = reinterpret_cast<const half8v*>(Etab + hN + jc * CH);
    const half8v* srcF = reinterpret_cast<const half8v*>(Ftab + hN + jc * CH);
    half8v* dE = reinterpret_cast<half8v*>(Esh);
    half8v* dF = reinterpret_cast<half8v*>(Fsh);
    for (int idx = tid; idx < CH / 8; idx += 256) {
      dE[idx] = srcE[idx];
      dF[idx] = srcF[idx];
    }
  }
  __syncthreads();

  // pre-swizzled per-lane global offsets per glds iter
  size_t goff[NITER];
#pragma unroll
  for (int it = 0; it < NITER; ++it) {
    int idx = tid + it * 256;
    int c = idx >> 3, sl = idx & 7;
    int slp = sl ^ (c & 7);
    goff[it] = (size_t)c * N_NODES + jc * CH + slp * 8;
  }

  auto issue = [&](int bsel, int j0) {
#pragma unroll
    for (int it = 0; it < NITER; ++it) {
      const short* g = Wbase + goff[it] + j0;
      short* lp = &Vt[bsel * STEP + it * 2048 + w * 512];
      glds16(g, lp);
    }
  };

  issue(0, 0);
  if (NS > 1) issue(1, 64);

  int i = i0 + w * 16 + row_l;
  float fi = f1s[hN + i];
  float gm = gmax[h];
  float mi = fmaxf(fi + gm, 0.2f * (fi + gm));
  _Float16 Aih = (_Float16)exp2f(fi + gm - mi);
  _Float16 Bih = (_Float16)exp2f(0.2f * (fi + gm) - mi);
  half2v Ai2 = {Aih, Aih};
  half2v Bi2 = {Bih, Bih};
  const unsigned int* mbase = bits + (size_t)i * MASK_WORDS + jc * (CH / 32);

  half8v ones8;
#pragma unroll
  for (int q = 0; q < 8; ++q) ones8[q] = (_Float16)1.0f;
  bool needL = (blockIdx.x == 0);

  f32x4 acc[NF];
#pragma unroll
  for (int n = 0; n < NF; ++n) acc[n] = f32x4{0, 0, 0, 0};
  f32x4 accl = f32x4{0, 0, 0, 0};

  int scount = 0;
#pragma unroll 1
  for (int ch = 0; ch < NCH; ++ch) {
    unsigned mw[12];
    {
      const uint4* mp = reinterpret_cast<const uint4*>(mbase + ch * 12);
#pragma unroll
      for (int q = 0; q < 3; ++q) {
        uint4 m = mp[q];
        mw[q * 4 + 0] = m.x; mw[q * 4 + 1] = m.y;
        mw[q * 4 + 2] = m.z; mw[q * 4 + 3] = m.w;
      }
    }
#pragma unroll 1
    for (int s2 = 0; s2 < 6; ++s2) {
      // wait for current stage's batch (oldest); keep next batch in flight
      if (scount + 1 == NS) {
        asm volatile("s_waitcnt vmcnt(0)" ::: "memory");
      } else if (NITER == 1) {
        asm volatile("s_waitcnt vmcnt(1)" ::: "memory");
      } else if (NITER == 2) {
        asm volatile("s_waitcnt vmcnt(2)" ::: "memory");
      } else {
        asm volatile("s_waitcnt vmcnt(4)" ::: "memory");
      }
      __builtin_amdgcn_sched_barrier(0);
      __builtin_amdgcn_s_barrier();
      if (scount + 2 < NS) issue((scount + 2) % 3, (scount + 2) * 64);
      const short* vb = &Vt[(scount % 3) * STEP];
#pragma unroll
      for (int hh = 0; hh < 2; ++hh) {
        unsigned wb = (mw[s2 * 2 + hh] >> (grp * 8)) & 0xffu;
        int jrel = scount * 64 + hh * 32 + grp * 8;
        half8v e8 = *reinterpret_cast<const half8v*>(&Esh[jrel]);
        half8v f8 = *reinterpret_cast<const half8v*>(&Fsh[jrel]);
        Half2x4 E2 = __builtin_bit_cast(Half2x4, e8);
        Half2x4 F2 = __builtin_bit_cast(Half2x4, f8);
        Half2x4 P2;
#pragma unroll
        for (int ep = 0; ep < 4; ++ep) {
          unsigned mk = (((wb >> (2 * ep)) & 1u) ? 0x3C00u : 0u) |
                        (((wb >> (2 * ep + 1)) & 1u) ? 0x3C000000u : 0u);
          half2v m2 = __builtin_bit_cast(half2v, mk);
          half2v p2 = __builtin_elementwise_max(Ai2 * E2.v[ep], Bi2 * F2.v[ep]);
          P2.v[ep] = p2 * m2;
        }
        half8v a8 = __builtin_bit_cast(half8v, P2);
        int j8s = ((hh << 2) | grp) ^ (row_l & 7);
#pragma unroll
        for (int n = 0; n < NF; ++n) {
          short8 braw = *reinterpret_cast<const short8*>(&vb[(n * 16 + row_l) * 64 + j8s * 8]);
          half8v b8 = __builtin_bit_cast(half8v, braw);
          acc[n] = __builtin_amdgcn_mfma_f32_16x16x32_f16(a8, b8, acc[n], 0, 0, 0);
        }
        if (needL)
          accl = __builtin_amdgcn_mfma_f32_16x16x32_f16(a8, ones8, accl, 0, 0, 0);
      }
      ++scount;
    }
  }

  float* outp = pbuf + (size_t)jc * N_NODES * Ftot;
#pragma unroll
  for (int n = 0; n < NF; ++n) {
#pragma unroll
    for (int k = 0; k < 4; ++k) {
      int r = i0 + w * 16 + grp * 4 + k;
      outp[(size_t)r * Ftot + vcol + n * 16 + row_l] = acc[n][k];
    }
  }
  if (needL && row_l == 0) {
#pragma unroll
    for (int k = 0; k < 4; ++k)
      atomicAdd(&lsum[hN + i0 + w * 16 + grp * 4 + k], accl[k]);
  }
}

// ---------------------------------------------------------------- reduce + activation
__global__ __launch_bounds__(256) void act_kernel(float* __restrict__ dst,
                                                  const float* __restrict__ pbuf,
                                                  int njc, size_t pstride,
                                                  const float* __restrict__ lsum,
                                                  int n4, int ftotShift, int fpShift, int act) {
  int idx = blockIdx.x * blockDim.x + threadIdx.x;
  if (idx >= n4) return;
  int idx4 = idx * 4;
  int r = idx4 >> ftotShift;
  int c = idx4 & ((1 << ftotShift) - 1);
  int h = c >> fpShift;
  float li = 1.0f / lsum[h * N_NODES + r];
  float4 v = reinterpret_cast<const float4*>(pbuf)[idx];
  float vv[4] = {v.x, v.y, v.z, v.w};
  for (int q = 1; q < njc; ++q) {
    float4 u = *reinterpret_cast<const float4*>(pbuf + q * pstride + (size_t)idx4);
    vv[0] += u.x; vv[1] += u.y; vv[2] += u.z; vv[3] += u.w;
  }
#pragma unroll
  for (int e = 0; e < 4; ++e) {
    float x = vv[e] * li;
    x = x > 0.0f ? x : exp2f(x * LOG2E) - 1.0f;
    if (act == 1) x = 1.0f / (1.0f + exp2f(-x * LOG2E));
    vv[e] = x;
  }
  reinterpret_cast<float4*>(dst)[idx] = make_float4(vv[0], vv[1], vv[2], vv[3]);
}

// ---------------------------------------------------------------- host
extern "C" void kernel_launch(void* const* d_in, const int* in_sizes, int n_in,
                              void* d_out, int out_size, void* d_ws, size_t ws_size,
                              hipStream_t stream) {
  const float* x     = (const float*)d_in[0];
  const int*   adj   = (const int*)d_in[1];
  const float* W1    = (const float*)d_in[2];
  const float* a1    = (const float*)d_in[3];
  const float* Wo    = (const float*)d_in[4];
  const float* ao    = (const float*)d_in[5];
  const float* W2    = (const float*)d_in[6];
  const float* a2    = (const float*)d_in[7];
  const float* Wo2   = (const float*)d_in[8];
  const float* ao2   = (const float*)d_in[9];
  const float* lin_w = (const float*)d_in[10];
  const float* lin_b = (const float*)d_in[11];
  float* out = (float*)d_out;

  float* ws = (float*)d_ws;
  unsigned int* bits = (unsigned int*)ws;            // 1,179,648 u32
  float* Wh   = ws + 1179648;                        // 6144*256
  float* bufA = Wh + 1572864;
  float* bufB = bufA + 1572864;
  float* Bcat = bufB + 1572864;                      // 65536
  float* f1   = Bcat + 65536;                        // 24576
  float* f2   = f1 + 24576;
  float* lsum = f2 + 24576;                          // 24576
  float* gmaxb = lsum + 24576;                       // 16
  _Float16* Etab = (_Float16*)(gmaxb + 16);          // 24576 fp16
  _Float16* Ftab = Etab + 24576;                     // 24576 fp16
  short* WhT  = (short*)(Ftab + 24576);              // 6144*256 fp16 bits
  short* BtW  = WhT + 1572864;                       // 384*256 bf16
  float* pbuf = (float*)(BtW + 98304);               // up to 4 x 6144*256 f32 partials

  const size_t PS256 = (size_t)6144 * 256;
  const size_t PS128 = (size_t)6144 * 128;

  dim3 b256(256);

  bitpack_kernel<<<N_NODES, b256, 0, stream>>>(adj, bits);

  // ================= layer 1 multi-head (H=4, Fp=64), elu concat
  repack_W_kernel<<<(4 * 256 * 64 + 255) / 256, b256, 0, stream>>>(W1, Bcat, 4, 256, 64);
  transpose_w_kernel<<<dim3(8, 8), b256, 0, stream>>>(Bcat, BtW, 256, 256);
  gemm_mfma_kernel<<<dim3(4, 96), b256, 0, stream>>>(x, BtW, Wh, 256, 256, nullptr, 0);
  f1f2_kernel<<<(4 * N_NODES) / 4, b256, 0, stream>>>(Wh, a1, f1, f2, 4, 64);
  gmax_kernel<<<4, b256, 0, stream>>>(f2, gmaxb);
  ef_kernel<<<dim3(24), b256, 0, stream>>>(f2, gmaxb, Etab, Ftab, 4 * N_NODES / 4);
  transpose_h_kernel<<<dim3(8, 192), b256, 0, stream>>>(Wh, WhT, 256);
  hipMemsetAsync(lsum, 0, (size_t)24576 * 4, stream);
  pv_stage_kernel<4, 4><<<dim3(1, 384, 4), b256, 0, stream>>>(f1, Etab, Ftab, gmaxb, bits, WhT, pbuf, lsum, 4, 64);
  act_kernel<<<dim3(1536), b256, 0, stream>>>(bufA, pbuf, 4, PS256, lsum, 6144 * 256 / 4, 8, 6, 0);

  // ================= out-attention 1 (H=1, Fp=256), sigmoid(elu)
  transpose_w_kernel<<<dim3(8, 8), b256, 0, stream>>>(Wo, BtW, 256, 256);
  gemm_mfma_kernel<<<dim3(4, 96), b256, 0, stream>>>(bufA, BtW, Wh, 256, 256, nullptr, 0);
  f1f2_kernel<<<(N_NODES) / 4, b256, 0, stream>>>(Wh, ao, f1, f2, 1, 256);
  gmax_kernel<<<1, b256, 0, stream>>>(f2, gmaxb);
  ef_kernel<<<dim3(6), b256, 0, stream>>>(f2, gmaxb, Etab, Ftab, N_NODES / 4);
  transpose_h_kernel<<<dim3(8, 192), b256, 0, stream>>>(Wh, WhT, 256);
  hipMemsetAsync(lsum, 0, (size_t)24576 * 4, stream);
  pv_stage_kernel<8, 4><<<dim3(2, 384, 1), b256, 0, stream>>>(f1, Etab, Ftab, gmaxb, bits, WhT, pbuf, lsum, 1, 256);
  act_kernel<<<dim3(1536), b256, 0, stream>>>(bufB, pbuf, 4, PS256, lsum, 6144 * 256 / 4, 8, 8, 1);

  // ================= layer 2 multi-head (H=4, Fp=32), elu concat
  repack_W_kernel<<<(4 * 256 * 32 + 255) / 256, b256, 0, stream>>>(W2, Bcat, 4, 256, 32);
  transpose_w_kernel<<<dim3(8, 4), b256, 0, stream>>>(Bcat, BtW, 256, 128);
  gemm_mfma_kernel<<<dim3(2, 96), b256, 0, stream>>>(bufB, BtW, Wh, 256, 128, nullptr, 0);
  f1f2_kernel<<<(4 * N_NODES) / 4, b256, 0, stream>>>(Wh, a2, f1, f2, 4, 32);
  gmax_kernel<<<4, b256, 0, stream>>>(f2, gmaxb);
  ef_kernel<<<dim3(24), b256, 0, stream>>>(f2, gmaxb, Etab, Ftab, 4 * N_NODES / 4);
  transpose_h_kernel<<<dim3(4, 192), b256, 0, stream>>>(Wh, WhT, 128);
  hipMemsetAsync(lsum, 0, (size_t)24576 * 4, stream);
  pv_stage_kernel<2, 4><<<dim3(1, 384, 4), b256, 0, stream>>>(f1, Etab, Ftab, gmaxb, bits, WhT, pbuf, lsum, 4, 32);
  act_kernel<<<dim3(768), b256, 0, stream>>>(bufA, pbuf, 4, PS128, lsum, 6144 * 128 / 4, 7, 5, 0);

  // ================= out-attention 2 (H=1, Fp=128), sigmoid(elu)
  transpose_w_kernel<<<dim3(4, 4), b256, 0, stream>>>(Wo2, BtW, 128, 128);
  gemm_mfma_kernel<<<dim3(2, 96), b256, 0, stream>>>(bufA, BtW, Wh, 128, 128, nullptr, 0);
  f1f2_kernel<<<(N_NODES) / 4, b256, 0, stream>>>(Wh, ao2, f1, f2, 1, 128);
  gmax_kernel<<<1, b256, 0, stream>>>(f2, gmaxb);
  ef_kernel<<<dim3(6), b256, 0, stream>>>(f2, gmaxb, Etab, Ftab, N_NODES / 4);
  transpose_h_kernel<<<dim3(4, 192), b256, 0, stream>>>(Wh, WhT, 128);
  hipMemsetAsync(lsum, 0, (size_t)24576 * 4, stream);
  pv_stage_kernel<8, 8><<<dim3(1, 768, 1), b256, 0, stream>>>(f1, Etab, Ftab, gmaxb, bits, WhT, pbuf, lsum, 1, 128);
  act_kernel<<<dim3(768), b256, 0, stream>>>(bufB, pbuf, 8, PS128, lsum, 6144 * 128 / 4, 7, 7, 1);

  // ================= final linear + relu
  transpose_w_kernel<<<dim3(4, 12), b256, 0, stream>>>(lin_w, BtW, 128, 379);
  gemm_mfma_kernel<<<dim3(6, 96), b256, 0, stream>>>(bufB, BtW, out, 128, 379, lin_b, 1);
}

// Round 17
// 350.649 us; speedup vs baseline: 9.6438x; 1.0182x over previous
//
#include <hip/hip_runtime.h>
#include <hip/hip_bf16.h>

#define N_NODES 6144
#define MASK_WORDS 192  // 6144/32
#define LOG2E 1.44269504088896f

using short8 = __attribute__((ext_vector_type(8))) short;
using s16x4  = __attribute__((ext_vector_type(4))) short;
using f32x4  = __attribute__((ext_vector_type(4))) float;
using half2v = __attribute__((ext_vector_type(2))) _Float16;
using half8v = __attribute__((ext_vector_type(8))) _Float16;
struct Half2x4 { half2v v[4]; };

// f32 -> bf16 bits, round-to-nearest-even
__device__ inline unsigned f2bf_u(float f) {
  unsigned u = __builtin_bit_cast(unsigned, f);
  u += 0x7fff + ((u >> 16) & 1);
  return u >> 16;
}
__device__ inline short f2bf(float f) { return (short)f2bf_u(f); }

// async global->LDS, 16B per lane; lds base must be wave-uniform
__device__ inline void glds16(const short* g, short* l) {
  __builtin_amdgcn_global_load_lds(
      (const __attribute__((address_space(1))) unsigned int*)g,
      (__attribute__((address_space(3))) unsigned int*)l, 16, 0, 0);
}

// ---------------------------------------------------------------- bitpack
__global__ __launch_bounds__(256) void bitpack_kernel(const int* __restrict__ adj,
                                                      unsigned int* __restrict__ bits) {
  int row = blockIdx.x;
  int wave = threadIdx.x >> 6, lane = threadIdx.x & 63;
  const int* p = adj + (long)row * N_NODES;
  for (int base = wave * 64; base < N_NODES; base += 256) {
    unsigned long long m = __ballot(p[base + lane] > 0);
    if (lane == 0) {
      bits[row * MASK_WORDS + (base >> 5)] = (unsigned int)m;
      bits[row * MASK_WORDS + (base >> 5) + 1] = (unsigned int)(m >> 32);
    }
  }
}

// ---------------------------------------------------------------- W repack
__global__ __launch_bounds__(256) void repack_W_kernel(const float* __restrict__ W,
                                                       float* __restrict__ B,
                                                       int H, int Fin, int Fp) {
  int idx = blockIdx.x * blockDim.x + threadIdx.x;
  int total = H * Fin * Fp;
  if (idx >= total) return;
  int h = idx / (Fin * Fp);
  int rem = idx - h * (Fin * Fp);
  int k = rem / Fp, c = rem - k * Fp;
  B[k * (H * Fp) + h * Fp + c] = W[idx];
}

// ---------------------------------------------------------------- weight transpose+cvt (bf16 for GEMM)
__global__ __launch_bounds__(256) void transpose_w_kernel(const float* __restrict__ B,
                                                          short* __restrict__ Bt,
                                                          int K, int Nc) {
  __shared__ short t[32][33];
  int k0 = blockIdx.x * 32, c0 = blockIdx.y * 32;
  int tx = threadIdx.x & 31, ty = threadIdx.x >> 5;
  for (int r = ty; r < 32; r += 8) {
    float v = (c0 + tx < Nc) ? B[(size_t)(k0 + r) * Nc + c0 + tx] : 0.0f;
    t[tx][r] = f2bf(v);
  }
  __syncthreads();
  for (int r = ty; r < 32; r += 8)
    Bt[(size_t)(c0 + r) * K + k0 + tx] = t[r][tx];
}

// ---------------------------------------------------------------- MFMA GEMM (bf16)
__global__ __launch_bounds__(256) void gemm_mfma_kernel(const float* __restrict__ A,
                                                        const short* __restrict__ Bt,
                                                        float* __restrict__ C,
                                                        int K, int Nc,
                                                        const float* __restrict__ bias,
                                                        int act) {
  __shared__ short As[64][40];
  __shared__ short Bs[64][40];
  int m0 = blockIdx.y * 64, n0 = blockIdx.x * 64;
  int tid = threadIdx.x;
  int w = tid >> 6, l = tid & 63, row_l = l & 15, grp = l >> 4;

  f32x4 acc[4] = {f32x4{0,0,0,0}, f32x4{0,0,0,0}, f32x4{0,0,0,0}, f32x4{0,0,0,0}};

  for (int k0 = 0; k0 < K; k0 += 32) {
    __syncthreads();
#pragma unroll
    for (int s = 0; s < 2; ++s) {
      int idx = tid + s * 256;
      int r = idx >> 3, q = idx & 7;
      float4 v = *reinterpret_cast<const float4*>(&A[(size_t)(m0 + r) * K + k0 + q * 4]);
      s16x4 sv = {f2bf(v.x), f2bf(v.y), f2bf(v.z), f2bf(v.w)};
      *reinterpret_cast<s16x4*>(&As[r][q * 4]) = sv;
    }
    {
      int c = tid >> 2, kq = tid & 3;
      *reinterpret_cast<short8*>(&Bs[c][kq * 8]) =
          *reinterpret_cast<const short8*>(&Bt[(size_t)(n0 + c) * K + k0 + kq * 8]);
    }
    __syncthreads();
    short8 a = *reinterpret_cast<const short8*>(&As[w * 16 + row_l][grp * 8]);
#pragma unroll
    for (int n = 0; n < 4; ++n) {
      short8 b = *reinterpret_cast<const short8*>(&Bs[n * 16 + row_l][grp * 8]);
      acc[n] = __builtin_amdgcn_mfma_f32_16x16x32_bf16(a, b, acc[n], 0, 0, 0);
    }
  }

#pragma unroll
  for (int n = 0; n < 4; ++n) {
#pragma unroll
    for (int k = 0; k < 4; ++k) {
      int row = m0 + w * 16 + grp * 4 + k;
      int col = n0 + n * 16 + row_l;
      if (col < Nc) {
        float v = acc[n][k];
        if (bias) v += bias[col];
        if (act == 1) v = fmaxf(v, 0.0f);
        C[(size_t)row * Nc + col] = v;
      }
    }
  }
}

// ---------------------------------------------------------------- f1/f2 (scaled by log2 e)
__global__ __launch_bounds__(256) void f1f2_kernel(const float* __restrict__ Wh,
                                                   const float* __restrict__ a,
                                                   float* __restrict__ f1,
                                                   float* __restrict__ f2,
                                                   int H, int Fp) {
  int g = blockIdx.x * 4 + (threadIdx.x >> 6);
  int lane = threadIdx.x & 63;
  if (g >= H * N_NODES) return;
  int h = g / N_NODES, n = g - h * N_NODES;
  int Ftot = H * Fp;
  const float* row = Wh + (long)n * Ftot + h * Fp;
  const float* av1 = a + h * 2 * Fp;
  const float* av2 = av1 + Fp;
  float s1 = 0.f, s2 = 0.f;
  for (int c = lane; c < Fp; c += 64) {
    float w = row[c];
    s1 += w * av1[c];
    s2 += w * av2[c];
  }
  for (int off = 32; off > 0; off >>= 1) {
    s1 += __shfl_down(s1, off);
    s2 += __shfl_down(s2, off);
  }
  if (lane == 0) { f1[g] = s1 * LOG2E; f2[g] = s2 * LOG2E; }
}

// ---------------------------------------------------------------- per-head global max of f2
__global__ __launch_bounds__(256) void gmax_kernel(const float* __restrict__ f2s,
                                                   float* __restrict__ gmax) {
  __shared__ float red[4];
  int h = blockIdx.x;
  int tid = threadIdx.x, lane = tid & 63, w = tid >> 6;
  const float* p = f2s + h * N_NODES;
  float m = -3.0e38f;
  for (int j = tid; j < N_NODES; j += 256) m = fmaxf(m, p[j]);
  for (int off = 32; off > 0; off >>= 1) m = fmaxf(m, __shfl_xor(m, off));
  if (lane == 0) red[w] = m;
  __syncthreads();
  if (tid == 0) gmax[h] = fmaxf(fmaxf(red[0], red[1]), fmaxf(red[2], red[3]));
}

// ---------------------------------------------------------------- transpose Wh -> WhT fp16
__global__ __launch_bounds__(256) void transpose_h_kernel(const float* __restrict__ A,
                                                          short* __restrict__ At,
                                                          int Ftot) {
  __shared__ short t[32][33];
  int c0 = blockIdx.x * 32, n0 = blockIdx.y * 32;
  int tx = threadIdx.x & 31, ty = threadIdx.x >> 5;
  for (int r = ty; r < 32; r += 8) {
    _Float16 hv = (_Float16)A[(size_t)(n0 + r) * Ftot + c0 + tx];
    t[tx][r] = __builtin_bit_cast(short, hv);
  }
  __syncthreads();
  for (int r = ty; r < 32; r += 8)
    At[(size_t)(c0 + r) * N_NODES + n0 + tx] = t[r][tx];
}

// ---------------------------------------------------------------- attention PV (fp16 packed)
// P = max(Ai'*E'_j, Bi'*F'_j) & Mlut[wb], all fp16; MFMA f32_16x16x32_f16.
// E/F computed IN-PROLOGUE from f2 (ef kernel fused away). Mask applied via a
// 256x16B LDS LUT (1 ds_read_b128 + 4 v_and instead of ~28 VALU).
// 64-j stages, triple-buffered async glds, counted vmcnt, raw s_barrier.
template<int NF, int JC>
__global__ __launch_bounds__(256)
void pv_stage_kernel(const float* __restrict__ f1s,
                     const float* __restrict__ f2s,
                     const float* __restrict__ gmax,
                     const unsigned int* __restrict__ bits,
                     const short* __restrict__ WhT,
                     float* __restrict__ pbuf,
                     float* __restrict__ lsum,
                     int H, int Fp) {
  constexpr int CH = N_NODES / JC;
  constexpr int COLS = NF * 16;
  constexpr int NS = CH / 64;               // 64-j stages
  constexpr int NITER = COLS / 32;          // glds per wave per stage
  constexpr int STEP = COLS * 64;           // shorts per buffer
  constexpr int NCH = CH / 384;
  static_assert(NCH * 384 == CH, "chunking");

  __shared__ _Float16 Esh[CH];
  __shared__ _Float16 Fsh[CH];
  __shared__ short Vt[3 * STEP];            // triple buffer, linear
  __shared__ uint4 Mlut[256];               // fp16-pair AND masks per byte

  int h = blockIdx.z;
  int cb0 = blockIdx.x * COLS;
  int rb = blockIdx.y % 96;
  int jc = blockIdx.y / 96;
  int i0 = rb * 64;
  int hN = h * N_NODES, hFp = h * Fp;
  int Ftot = H * Fp;
  int tid = threadIdx.x;
  int w = tid >> 6, l = tid & 63;
  int row_l = l & 15, grp = l >> 4;

  int vcol = hFp + cb0;
  const short* Wbase = WhT + (size_t)vcol * N_NODES;
  float gm = gmax[h];

  // ---- prologue: E/F from f2 (fused ef), mask LUT build
  {
    const float4* srcF2 = reinterpret_cast<const float4*>(f2s + hN + jc * CH);
    for (int idx = tid; idx < CH / 4; idx += 256) {
      float4 v = srcF2[idx];
      float vv[4] = {v.x, v.y, v.z, v.w};
      _Float16 e4[4], f4[4];
#pragma unroll
      for (int q = 0; q < 4; ++q) {
        float d = vv[q] - gm;
        e4[q] = (_Float16)exp2f(d);
        f4[q] = (_Float16)exp2f(0.2f * d);
      }
      *reinterpret_cast<s16x4*>(&Esh[idx * 4]) = *reinterpret_cast<s16x4*>(e4);
      *reinterpret_cast<s16x4*>(&Fsh[idx * 4]) = *reinterpret_cast<s16x4*>(f4);
    }
    unsigned v = tid;  // 0..255
    unsigned w0 = ((v & 1u) ? 0xFFFFu : 0u) | ((v & 2u) ? 0xFFFF0000u : 0u);
    unsigned w1 = ((v & 4u) ? 0xFFFFu : 0u) | ((v & 8u) ? 0xFFFF0000u : 0u);
    unsigned w2 = ((v & 16u) ? 0xFFFFu : 0u) | ((v & 32u) ? 0xFFFF0000u : 0u);
    unsigned w3 = ((v & 64u) ? 0xFFFFu : 0u) | ((v & 128u) ? 0xFFFF0000u : 0u);
    Mlut[v] = make_uint4(w0, w1, w2, w3);
  }
  __syncthreads();

  // pre-swizzled per-lane global offsets per glds iter
  size_t goff[NITER];
#pragma unroll
  for (int it = 0; it < NITER; ++it) {
    int idx = tid + it * 256;
    int c = idx >> 3, sl = idx & 7;
    int slp = sl ^ (c & 7);
    goff[it] = (size_t)c * N_NODES + jc * CH + slp * 8;
  }

  auto issue = [&](int bsel, int j0) {
#pragma unroll
    for (int it = 0; it < NITER; ++it) {
      const short* g = Wbase + goff[it] + j0;
      short* lp = &Vt[bsel * STEP + it * 2048 + w * 512];
      glds16(g, lp);
    }
  };

  issue(0, 0);
  if (NS > 1) issue(1, 64);

  int i = i0 + w * 16 + row_l;
  float fi = f1s[hN + i];
  float mi = fmaxf(fi + gm, 0.2f * (fi + gm));
  _Float16 Aih = (_Float16)exp2f(fi + gm - mi);
  _Float16 Bih = (_Float16)exp2f(0.2f * (fi + gm) - mi);
  half2v Ai2 = {Aih, Aih};
  half2v Bi2 = {Bih, Bih};
  const unsigned int* mbase = bits + (size_t)i * MASK_WORDS + jc * (CH / 32);

  half8v ones8;
#pragma unroll
  for (int q = 0; q < 8; ++q) ones8[q] = (_Float16)1.0f;
  bool needL = (blockIdx.x == 0);

  f32x4 acc[NF];
#pragma unroll
  for (int n = 0; n < NF; ++n) acc[n] = f32x4{0, 0, 0, 0};
  f32x4 accl = f32x4{0, 0, 0, 0};

  int scount = 0;
#pragma unroll 1
  for (int ch = 0; ch < NCH; ++ch) {
    unsigned mw[12];
    {
      const uint4* mp = reinterpret_cast<const uint4*>(mbase + ch * 12);
#pragma unroll
      for (int q = 0; q < 3; ++q) {
        uint4 m = mp[q];
        mw[q * 4 + 0] = m.x; mw[q * 4 + 1] = m.y;
        mw[q * 4 + 2] = m.z; mw[q * 4 + 3] = m.w;
      }
    }
#pragma unroll 1
    for (int s2 = 0; s2 < 6; ++s2) {
      if (scount + 1 == NS) {
        asm volatile("s_waitcnt vmcnt(0)" ::: "memory");
      } else if (NITER == 1) {
        asm volatile("s_waitcnt vmcnt(1)" ::: "memory");
      } else if (NITER == 2) {
        asm volatile("s_waitcnt vmcnt(2)" ::: "memory");
      } else {
        asm volatile("s_waitcnt vmcnt(4)" ::: "memory");
      }
      __builtin_amdgcn_sched_barrier(0);
      __builtin_amdgcn_s_barrier();
      if (scount + 2 < NS) issue((scount + 2) % 3, (scount + 2) * 64);
      const short* vb = &Vt[(scount % 3) * STEP];
#pragma unroll
      for (int hh = 0; hh < 2; ++hh) {
        unsigned wb = (mw[s2 * 2 + hh] >> (grp * 8)) & 0xffu;
        uint4 mq4 = Mlut[wb];
        unsigned mka[4] = {mq4.x, mq4.y, mq4.z, mq4.w};
        int jrel = scount * 64 + hh * 32 + grp * 8;
        half8v e8 = *reinterpret_cast<const half8v*>(&Esh[jrel]);
        half8v f8 = *reinterpret_cast<const half8v*>(&Fsh[jrel]);
        Half2x4 E2 = __builtin_bit_cast(Half2x4, e8);
        Half2x4 F2 = __builtin_bit_cast(Half2x4, f8);
        Half2x4 P2;
#pragma unroll
        for (int ep = 0; ep < 4; ++ep) {
          half2v p2 = __builtin_elementwise_max(Ai2 * E2.v[ep], Bi2 * F2.v[ep]);
          unsigned pm = __builtin_bit_cast(unsigned, p2) & mka[ep];
          P2.v[ep] = __builtin_bit_cast(half2v, pm);
        }
        half8v a8 = __builtin_bit_cast(half8v, P2);
        int j8s = ((hh << 2) | grp) ^ (row_l & 7);
#pragma unroll
        for (int n = 0; n < NF; ++n) {
          short8 braw = *reinterpret_cast<const short8*>(&vb[(n * 16 + row_l) * 64 + j8s * 8]);
          half8v b8 = __builtin_bit_cast(half8v, braw);
          acc[n] = __builtin_amdgcn_mfma_f32_16x16x32_f16(a8, b8, acc[n], 0, 0, 0);
        }
        if (needL)
          accl = __builtin_amdgcn_mfma_f32_16x16x32_f16(a8, ones8, accl, 0, 0, 0);
      }
      ++scount;
    }
  }

  float* outp = pbuf + (size_t)jc * N_NODES * Ftot;
#pragma unroll
  for (int n = 0; n < NF; ++n) {
#pragma unroll
    for (int k = 0; k < 4; ++k) {
      int r = i0 + w * 16 + grp * 4 + k;
      outp[(size_t)r * Ftot + vcol + n * 16 + row_l] = acc[n][k];
    }
  }
  if (needL && row_l == 0) {
#pragma unroll
    for (int k = 0; k < 4; ++k)
      atomicAdd(&lsum[hN + i0 + w * 16 + grp * 4 + k], accl[k]);
  }
}

// ---------------------------------------------------------------- reduce + activation
__global__ __launch_bounds__(256) void act_kernel(float* __restrict__ dst,
                                                  const float* __restrict__ pbuf,
                                                  int njc, size_t pstride,
                                                  const float* __restrict__ lsum,
                                                  int n4, int ftotShift, int fpShift, int act) {
  int idx = blockIdx.x * blockDim.x + threadIdx.x;
  if (idx >= n4) return;
  int idx4 = idx * 4;
  int r = idx4 >> ftotShift;
  int c = idx4 & ((1 << ftotShift) - 1);
  int h = c >> fpShift;
  float li = 1.0f / lsum[h * N_NODES + r];
  float4 v = reinterpret_cast<const float4*>(pbuf)[idx];
  float vv[4] = {v.x, v.y, v.z, v.w};
  for (int q = 1; q < njc; ++q) {
    float4 u = *reinterpret_cast<const float4*>(pbuf + q * pstride + (size_t)idx4);
    vv[0] += u.x; vv[1] += u.y; vv[2] += u.z; vv[3] += u.w;
  }
#pragma unroll
  for (int e = 0; e < 4; ++e) {
    float x = vv[e] * li;
    x = x > 0.0f ? x : exp2f(x * LOG2E) - 1.0f;
    if (act == 1) x = 1.0f / (1.0f + exp2f(-x * LOG2E));
    vv[e] = x;
  }
  reinterpret_cast<float4*>(dst)[idx] = make_float4(vv[0], vv[1], vv[2], vv[3]);
}

// ---------------------------------------------------------------- host
extern "C" void kernel_launch(void* const* d_in, const int* in_sizes, int n_in,
                              void* d_out, int out_size, void* d_ws, size_t ws_size,
                              hipStream_t stream) {
  const float* x     = (const float*)d_in[0];
  const int*   adj   = (const int*)d_in[1];
  const float* W1    = (const float*)d_in[2];
  const float* a1    = (const float*)d_in[3];
  const float* Wo    = (const float*)d_in[4];
  const float* ao    = (const float*)d_in[5];
  const float* W2    = (const float*)d_in[6];
  const float* a2    = (const float*)d_in[7];
  const float* Wo2   = (const float*)d_in[8];
  const float* ao2   = (const float*)d_in[9];
  const float* lin_w = (const float*)d_in[10];
  const float* lin_b = (const float*)d_in[11];
  float* out = (float*)d_out;

  float* ws = (float*)d_ws;
  unsigned int* bits = (unsigned int*)ws;            // 1,179,648 u32
  float* Wh   = ws + 1179648;                        // 6144*256
  float* bufA = Wh + 1572864;
  float* bufB = bufA + 1572864;
  float* Bcat = bufB + 1572864;                      // 65536
  float* f1   = Bcat + 65536;                        // 24576
  float* f2   = f1 + 24576;
  float* lsum = f2 + 24576;                          // 24576
  float* gmaxb = lsum + 24576;                       // 16
  short* WhT  = (short*)(gmaxb + 16);                // 6144*256 fp16 bits
  short* BtW  = WhT + 1572864;                       // 384*256 bf16
  float* pbuf = (float*)(BtW + 98304);               // up to 4 x 6144*256 f32 partials

  const size_t PS256 = (size_t)6144 * 256;
  const size_t PS128 = (size_t)6144 * 128;

  dim3 b256(256);

  bitpack_kernel<<<N_NODES, b256, 0, stream>>>(adj, bits);

  // ================= layer 1 multi-head (H=4, Fp=64), elu concat
  repack_W_kernel<<<(4 * 256 * 64 + 255) / 256, b256, 0, stream>>>(W1, Bcat, 4, 256, 64);
  transpose_w_kernel<<<dim3(8, 8), b256, 0, stream>>>(Bcat, BtW, 256, 256);
  gemm_mfma_kernel<<<dim3(4, 96), b256, 0, stream>>>(x, BtW, Wh, 256, 256, nullptr, 0);
  f1f2_kernel<<<(4 * N_NODES) / 4, b256, 0, stream>>>(Wh, a1, f1, f2, 4, 64);
  gmax_kernel<<<4, b256, 0, stream>>>(f2, gmaxb);
  transpose_h_kernel<<<dim3(8, 192), b256, 0, stream>>>(Wh, WhT, 256);
  hipMemsetAsync(lsum, 0, (size_t)24576 * 4, stream);
  pv_stage_kernel<4, 4><<<dim3(1, 384, 4), b256, 0, stream>>>(f1, f2, gmaxb, bits, WhT, pbuf, lsum, 4, 64);
  act_kernel<<<dim3(1536), b256, 0, stream>>>(bufA, pbuf, 4, PS256, lsum, 6144 * 256 / 4, 8, 6, 0);

  // ================= out-attention 1 (H=1, Fp=256), sigmoid(elu)
  transpose_w_kernel<<<dim3(8, 8), b256, 0, stream>>>(Wo, BtW, 256, 256);
  gemm_mfma_kernel<<<dim3(4, 96), b256, 0, stream>>>(bufA, BtW, Wh, 256, 256, nullptr, 0);
  f1f2_kernel<<<(N_NODES) / 4, b256, 0, stream>>>(Wh, ao, f1, f2, 1, 256);
  gmax_kernel<<<1, b256, 0, stream>>>(f2, gmaxb);
  transpose_h_kernel<<<dim3(8, 192), b256, 0, stream>>>(Wh, WhT, 256);
  hipMemsetAsync(lsum, 0, (size_t)24576 * 4, stream);
  pv_stage_kernel<8, 4><<<dim3(2, 384, 1), b256, 0, stream>>>(f1, f2, gmaxb, bits, WhT, pbuf, lsum, 1, 256);
  act_kernel<<<dim3(1536), b256, 0, stream>>>(bufB, pbuf, 4, PS256, lsum, 6144 * 256 / 4, 8, 8, 1);

  // ================= layer 2 multi-head (H=4, Fp=32), elu concat
  repack_W_kernel<<<(4 * 256 * 32 + 255) / 256, b256, 0, stream>>>(W2, Bcat, 4, 256, 32);
  transpose_w_kernel<<<dim3(8, 4), b256, 0, stream>>>(Bcat, BtW, 256, 128);
  gemm_mfma_kernel<<<dim3(2, 96), b256, 0, stream>>>(bufB, BtW, Wh, 256, 128, nullptr, 0);
  f1f2_kernel<<<(4 * N_NODES) / 4, b256, 0, stream>>>(Wh, a2, f1, f2, 4, 32);
  gmax_kernel<<<4, b256, 0, stream>>>(f2, gmaxb);
  transpose_h_kernel<<<dim3(4, 192), b256, 0, stream>>>(Wh, WhT, 128);
  hipMemsetAsync(lsum, 0, (size_t)24576 * 4, stream);
  pv_stage_kernel<2, 4><<<dim3(1, 384, 4), b256, 0, stream>>>(f1, f2, gmaxb, bits, WhT, pbuf, lsum, 4, 32);
  act_kernel<<<dim3(768), b256, 0, stream>>>(bufA, pbuf, 4, PS128, lsum, 6144 * 128 / 4, 7, 5, 0);

  // ================= out-attention 2 (H=1, Fp=128), sigmoid(elu)
  transpose_w_kernel<<<dim3(4, 4), b256, 0, stream>>>(Wo2, BtW, 128, 128);
  gemm_mfma_kernel<<<dim3(2, 96), b256, 0, stream>>>(bufA, BtW, Wh, 128, 128, nullptr, 0);
  f1f2_kernel<<<(N_NODES) / 4, b256, 0, stream>>>(Wh, ao2, f1, f2, 1, 128);
  gmax_kernel<<<1, b256, 0, stream>>>(f2, gmaxb);
  transpose_h_kernel<<<dim3(4, 192), b256, 0, stream>>>(Wh, WhT, 128);
  hipMemsetAsync(lsum, 0, (size_t)24576 * 4, stream);
  pv_stage_kernel<8, 8><<<dim3(1, 768, 1), b256, 0, stream>>>(f1, f2, gmaxb, bits, WhT, pbuf, lsum, 1, 128);
  act_kernel<<<dim3(768), b256, 0, stream>>>(bufB, pbuf, 8, PS128, lsum, 6144 * 128 / 4, 7, 7, 1);

  // ================= final linear + relu
  transpose_w_kernel<<<dim3(4, 12), b256, 0, stream>>>(lin_w, BtW, 128, 379);
  gemm_mfma_kernel<<<dim3(6, 96), b256, 0, stream>>>(bufB, BtW, out, 128, 379, lin_b, 1);
}

// Round 18
// 331.424 us; speedup vs baseline: 10.2033x; 1.0580x over previous
//
#include <hip/hip_runtime.h>
#include <hip/hip_bf16.h>

#define N_NODES 6144
#define MASK_WORDS 192  // 6144/32
#define LOG2E 1.44269504088896f

using short8 = __attribute__((ext_vector_type(8))) short;
using s16x4  = __attribute__((ext_vector_type(4))) short;
using f32x4  = __attribute__((ext_vector_type(4))) float;
using half2v = __attribute__((ext_vector_type(2))) _Float16;
using half8v = __attribute__((ext_vector_type(8))) _Float16;
struct Half2x4 { half2v v[4]; };

// f32 -> bf16 bits, round-to-nearest-even
__device__ inline unsigned f2bf_u(float f) {
  unsigned u = __builtin_bit_cast(unsigned, f);
  u += 0x7fff + ((u >> 16) & 1);
  return u >> 16;
}
__device__ inline short f2bf(float f) { return (short)f2bf_u(f); }

// async global->LDS, 16B per lane; lds base must be wave-uniform
__device__ inline void glds16(const short* g, short* l) {
  __builtin_amdgcn_global_load_lds(
      (const __attribute__((address_space(1))) unsigned int*)g,
      (__attribute__((address_space(3))) unsigned int*)l, 16, 0, 0);
}

// ---------------------------------------------------------------- bitpack
__global__ __launch_bounds__(256) void bitpack_kernel(const int* __restrict__ adj,
                                                      unsigned int* __restrict__ bits) {
  int row = blockIdx.x;
  int wave = threadIdx.x >> 6, lane = threadIdx.x & 63;
  const int* p = adj + (long)row * N_NODES;
  for (int base = wave * 64; base < N_NODES; base += 256) {
    unsigned long long m = __ballot(p[base + lane] > 0);
    if (lane == 0) {
      bits[row * MASK_WORDS + (base >> 5)] = (unsigned int)m;
      bits[row * MASK_WORDS + (base >> 5) + 1] = (unsigned int)(m >> 32);
    }
  }
}

// ---------------------------------------------------------------- W repack
__global__ __launch_bounds__(256) void repack_W_kernel(const float* __restrict__ W,
                                                       float* __restrict__ B,
                                                       int H, int Fin, int Fp) {
  int idx = blockIdx.x * blockDim.x + threadIdx.x;
  int total = H * Fin * Fp;
  if (idx >= total) return;
  int h = idx / (Fin * Fp);
  int rem = idx - h * (Fin * Fp);
  int k = rem / Fp, c = rem - k * Fp;
  B[k * (H * Fp) + h * Fp + c] = W[idx];
}

// ---------------------------------------------------------------- weight transpose+cvt (bf16)
__global__ __launch_bounds__(256) void transpose_w_kernel(const float* __restrict__ B,
                                                          short* __restrict__ Bt,
                                                          int K, int Nc) {
  __shared__ short t[32][33];
  int k0 = blockIdx.x * 32, c0 = blockIdx.y * 32;
  int tx = threadIdx.x & 31, ty = threadIdx.x >> 5;
  for (int r = ty; r < 32; r += 8) {
    float v = (c0 + tx < Nc) ? B[(size_t)(k0 + r) * Nc + c0 + tx] : 0.0f;
    t[tx][r] = f2bf(v);
  }
  __syncthreads();
  for (int r = ty; r < 32; r += 8)
    Bt[(size_t)(c0 + r) * K + k0 + tx] = t[r][tx];
}

// ---------------------------------------------------------------- MFMA GEMM (final linear only)
__global__ __launch_bounds__(256) void gemm_mfma_kernel(const float* __restrict__ A,
                                                        const short* __restrict__ Bt,
                                                        float* __restrict__ C,
                                                        int K, int Nc,
                                                        const float* __restrict__ bias,
                                                        int act) {
  __shared__ short As[64][40];
  __shared__ short Bs[64][40];
  int m0 = blockIdx.y * 64, n0 = blockIdx.x * 64;
  int tid = threadIdx.x;
  int w = tid >> 6, l = tid & 63, row_l = l & 15, grp = l >> 4;

  f32x4 acc[4] = {f32x4{0,0,0,0}, f32x4{0,0,0,0}, f32x4{0,0,0,0}, f32x4{0,0,0,0}};

  for (int k0 = 0; k0 < K; k0 += 32) {
    __syncthreads();
#pragma unroll
    for (int s = 0; s < 2; ++s) {
      int idx = tid + s * 256;
      int r = idx >> 3, q = idx & 7;
      float4 v = *reinterpret_cast<const float4*>(&A[(size_t)(m0 + r) * K + k0 + q * 4]);
      s16x4 sv = {f2bf(v.x), f2bf(v.y), f2bf(v.z), f2bf(v.w)};
      *reinterpret_cast<s16x4*>(&As[r][q * 4]) = sv;
    }
    {
      int c = tid >> 2, kq = tid & 3;
      *reinterpret_cast<short8*>(&Bs[c][kq * 8]) =
          *reinterpret_cast<const short8*>(&Bt[(size_t)(n0 + c) * K + k0 + kq * 8]);
    }
    __syncthreads();
    short8 a = *reinterpret_cast<const short8*>(&As[w * 16 + row_l][grp * 8]);
#pragma unroll
    for (int n = 0; n < 4; ++n) {
      short8 b = *reinterpret_cast<const short8*>(&Bs[n * 16 + row_l][grp * 8]);
      acc[n] = __builtin_amdgcn_mfma_f32_16x16x32_bf16(a, b, acc[n], 0, 0, 0);
    }
  }

#pragma unroll
  for (int n = 0; n < 4; ++n) {
#pragma unroll
    for (int k = 0; k < 4; ++k) {
      int row = m0 + w * 16 + grp * 4 + k;
      int col = n0 + n * 16 + row_l;
      if (col < Nc) {
        float v = acc[n][k];
        if (bias) v += bias[col];
        if (act == 1) v = fmaxf(v, 0.0f);
        C[(size_t)row * Nc + col] = v;
      }
    }
  }
}

// ---------------------------------------------------------------- attention GEMM (fused epilogue)
// C = A @ Bt (bf16 MFMA). Epilogue (no Wh f32 written):
//   * WhT[col][row] fp16 (per lane one 8B s16x4 store of 4 consecutive rows)
//   * f1/f2 partials: dot acc with avec slice, shfl-reduce over 16-lane col group,
//     atomicAdd per row (f1/f2 pre-zeroed). LOG2E folded in.
// HPB = heads spanned by this block's 64 cols (1 or 2). Nc multiple of 64.
template<int HPB>
__global__ __launch_bounds__(256)
void gemm_attn_kernel(const float* __restrict__ A,
                      const short* __restrict__ Bt,
                      const float* __restrict__ avec,
                      short* __restrict__ WhT,
                      float* __restrict__ f1,
                      float* __restrict__ f2,
                      int K, int Nc, int Fp) {
  __shared__ short As[64][40];
  __shared__ short Bs[64][40];
  int m0 = blockIdx.y * 64, n0 = blockIdx.x * 64;
  int tid = threadIdx.x;
  int w = tid >> 6, l = tid & 63, row_l = l & 15, grp = l >> 4;

  f32x4 acc[4] = {f32x4{0,0,0,0}, f32x4{0,0,0,0}, f32x4{0,0,0,0}, f32x4{0,0,0,0}};

  for (int k0 = 0; k0 < K; k0 += 32) {
    __syncthreads();
#pragma unroll
    for (int s = 0; s < 2; ++s) {
      int idx = tid + s * 256;
      int r = idx >> 3, q = idx & 7;
      float4 v = *reinterpret_cast<const float4*>(&A[(size_t)(m0 + r) * K + k0 + q * 4]);
      s16x4 sv = {f2bf(v.x), f2bf(v.y), f2bf(v.z), f2bf(v.w)};
      *reinterpret_cast<s16x4*>(&As[r][q * 4]) = sv;
    }
    {
      int c = tid >> 2, kq = tid & 3;
      *reinterpret_cast<short8*>(&Bs[c][kq * 8]) =
          *reinterpret_cast<const short8*>(&Bt[(size_t)(n0 + c) * K + k0 + kq * 8]);
    }
    __syncthreads();
    short8 a = *reinterpret_cast<const short8*>(&As[w * 16 + row_l][grp * 8]);
#pragma unroll
    for (int n = 0; n < 4; ++n) {
      short8 b = *reinterpret_cast<const short8*>(&Bs[n * 16 + row_l][grp * 8]);
      acc[n] = __builtin_amdgcn_mfma_f32_16x16x32_bf16(a, b, acc[n], 0, 0, 0);
    }
  }

  int baserow = m0 + w * 16 + grp * 4;

  // WhT fp16 transposed store
#pragma unroll
  for (int n = 0; n < 4; ++n) {
    int col = n0 + n * 16 + row_l;
    _Float16 hv[4];
#pragma unroll
    for (int k = 0; k < 4; ++k) hv[k] = (_Float16)acc[n][k];
    *reinterpret_cast<s16x4*>(&WhT[(size_t)col * N_NODES + baserow]) =
        *reinterpret_cast<s16x4*>(hv);
  }

  // f1/f2 fused partials
  constexpr int NPH = 4 / HPB;
#pragma unroll
  for (int half = 0; half < HPB; ++half) {
    int col0 = n0 + half * NPH * 16;
    int h = col0 / Fp;
    float t1[4] = {0, 0, 0, 0}, t2[4] = {0, 0, 0, 0};
#pragma unroll
    for (int nn = 0; nn < NPH; ++nn) {
      int n = half * NPH + nn;
      int col = n0 + n * 16 + row_l;
      int ci = col - h * Fp;
      float av1 = avec[h * 2 * Fp + ci] * LOG2E;
      float av2 = avec[h * 2 * Fp + Fp + ci] * LOG2E;
#pragma unroll
      for (int k = 0; k < 4; ++k) {
        t1[k] += acc[n][k] * av1;
        t2[k] += acc[n][k] * av2;
      }
    }
#pragma unroll
    for (int off = 1; off < 16; off <<= 1) {
#pragma unroll
      for (int k = 0; k < 4; ++k) {
        t1[k] += __shfl_xor(t1[k], off);
        t2[k] += __shfl_xor(t2[k], off);
      }
    }
    if (row_l == 0) {
#pragma unroll
      for (int k = 0; k < 4; ++k) {
        atomicAdd(&f1[h * N_NODES + baserow + k], t1[k]);
        atomicAdd(&f2[h * N_NODES + baserow + k], t2[k]);
      }
    }
  }
}

// ---------------------------------------------------------------- per-head global max of f2
__global__ __launch_bounds__(256) void gmax_kernel(const float* __restrict__ f2s,
                                                   float* __restrict__ gmax) {
  __shared__ float red[4];
  int h = blockIdx.x;
  int tid = threadIdx.x, lane = tid & 63, w = tid >> 6;
  const float* p = f2s + h * N_NODES;
  float m = -3.0e38f;
  for (int j = tid; j < N_NODES; j += 256) m = fmaxf(m, p[j]);
  for (int off = 32; off > 0; off >>= 1) m = fmaxf(m, __shfl_xor(m, off));
  if (lane == 0) red[w] = m;
  __syncthreads();
  if (tid == 0) gmax[h] = fmaxf(fmaxf(red[0], red[1]), fmaxf(red[2], red[3]));
}

// ---------------------------------------------------------------- attention PV (fp16 packed)
// P = max(Ai'*E'_j, Bi'*F'_j) & Mlut[wb], all fp16; MFMA f32_16x16x32_f16.
// E/F computed in-prologue from f2. Mask via 256x16B LDS LUT.
// 64-j stages, triple-buffered async glds, counted vmcnt, raw s_barrier.
template<int NF, int JC>
__global__ __launch_bounds__(256)
void pv_stage_kernel(const float* __restrict__ f1s,
                     const float* __restrict__ f2s,
                     const float* __restrict__ gmax,
                     const unsigned int* __restrict__ bits,
                     const short* __restrict__ WhT,
                     float* __restrict__ pbuf,
                     float* __restrict__ lsum,
                     int H, int Fp) {
  constexpr int CH = N_NODES / JC;
  constexpr int COLS = NF * 16;
  constexpr int NS = CH / 64;
  constexpr int NITER = COLS / 32;
  constexpr int STEP = COLS * 64;
  constexpr int NCH = CH / 384;
  static_assert(NCH * 384 == CH, "chunking");

  __shared__ _Float16 Esh[CH];
  __shared__ _Float16 Fsh[CH];
  __shared__ short Vt[3 * STEP];
  __shared__ uint4 Mlut[256];

  int h = blockIdx.z;
  int cb0 = blockIdx.x * COLS;
  int rb = blockIdx.y % 96;
  int jc = blockIdx.y / 96;
  int i0 = rb * 64;
  int hN = h * N_NODES, hFp = h * Fp;
  int Ftot = H * Fp;
  int tid = threadIdx.x;
  int w = tid >> 6, l = tid & 63;
  int row_l = l & 15, grp = l >> 4;

  int vcol = hFp + cb0;
  const short* Wbase = WhT + (size_t)vcol * N_NODES;
  float gm = gmax[h];

  {
    const float4* srcF2 = reinterpret_cast<const float4*>(f2s + hN + jc * CH);
    for (int idx = tid; idx < CH / 4; idx += 256) {
      float4 v = srcF2[idx];
      float vv[4] = {v.x, v.y, v.z, v.w};
      _Float16 e4[4], f4[4];
#pragma unroll
      for (int q = 0; q < 4; ++q) {
        float d = vv[q] - gm;
        e4[q] = (_Float16)exp2f(d);
        f4[q] = (_Float16)exp2f(0.2f * d);
      }
      *reinterpret_cast<s16x4*>(&Esh[idx * 4]) = *reinterpret_cast<s16x4*>(e4);
      *reinterpret_cast<s16x4*>(&Fsh[idx * 4]) = *reinterpret_cast<s16x4*>(f4);
    }
    unsigned v = tid;
    unsigned w0 = ((v & 1u) ? 0xFFFFu : 0u) | ((v & 2u) ? 0xFFFF0000u : 0u);
    unsigned w1 = ((v & 4u) ? 0xFFFFu : 0u) | ((v & 8u) ? 0xFFFF0000u : 0u);
    unsigned w2 = ((v & 16u) ? 0xFFFFu : 0u) | ((v & 32u) ? 0xFFFF0000u : 0u);
    unsigned w3 = ((v & 64u) ? 0xFFFFu : 0u) | ((v & 128u) ? 0xFFFF0000u : 0u);
    Mlut[v] = make_uint4(w0, w1, w2, w3);
  }
  __syncthreads();

  size_t goff[NITER];
#pragma unroll
  for (int it = 0; it < NITER; ++it) {
    int idx = tid + it * 256;
    int c = idx >> 3, sl = idx & 7;
    int slp = sl ^ (c & 7);
    goff[it] = (size_t)c * N_NODES + jc * CH + slp * 8;
  }

  auto issue = [&](int bsel, int j0) {
#pragma unroll
    for (int it = 0; it < NITER; ++it) {
      const short* g = Wbase + goff[it] + j0;
      short* lp = &Vt[bsel * STEP + it * 2048 + w * 512];
      glds16(g, lp);
    }
  };

  issue(0, 0);
  if (NS > 1) issue(1, 64);

  int i = i0 + w * 16 + row_l;
  float fi = f1s[hN + i];
  float mi = fmaxf(fi + gm, 0.2f * (fi + gm));
  _Float16 Aih = (_Float16)exp2f(fi + gm - mi);
  _Float16 Bih = (_Float16)exp2f(0.2f * (fi + gm) - mi);
  half2v Ai2 = {Aih, Aih};
  half2v Bi2 = {Bih, Bih};
  const unsigned int* mbase = bits + (size_t)i * MASK_WORDS + jc * (CH / 32);

  half8v ones8;
#pragma unroll
  for (int q = 0; q < 8; ++q) ones8[q] = (_Float16)1.0f;
  bool needL = (blockIdx.x == 0);

  f32x4 acc[NF];
#pragma unroll
  for (int n = 0; n < NF; ++n) acc[n] = f32x4{0, 0, 0, 0};
  f32x4 accl = f32x4{0, 0, 0, 0};

  int scount = 0;
#pragma unroll 1
  for (int ch = 0; ch < NCH; ++ch) {
    unsigned mw[12];
    {
      const uint4* mp = reinterpret_cast<const uint4*>(mbase + ch * 12);
#pragma unroll
      for (int q = 0; q < 3; ++q) {
        uint4 m = mp[q];
        mw[q * 4 + 0] = m.x; mw[q * 4 + 1] = m.y;
        mw[q * 4 + 2] = m.z; mw[q * 4 + 3] = m.w;
      }
    }
#pragma unroll 1
    for (int s2 = 0; s2 < 6; ++s2) {
      if (scount + 1 == NS) {
        asm volatile("s_waitcnt vmcnt(0)" ::: "memory");
      } else if (NITER == 1) {
        asm volatile("s_waitcnt vmcnt(1)" ::: "memory");
      } else if (NITER == 2) {
        asm volatile("s_waitcnt vmcnt(2)" ::: "memory");
      } else {
        asm volatile("s_waitcnt vmcnt(4)" ::: "memory");
      }
      __builtin_amdgcn_sched_barrier(0);
      __builtin_amdgcn_s_barrier();
      if (scount + 2 < NS) issue((scount + 2) % 3, (scount + 2) * 64);
      const short* vb = &Vt[(scount % 3) * STEP];
#pragma unroll
      for (int hh = 0; hh < 2; ++hh) {
        unsigned wb = (mw[s2 * 2 + hh] >> (grp * 8)) & 0xffu;
        uint4 mq4 = Mlut[wb];
        unsigned mka[4] = {mq4.x, mq4.y, mq4.z, mq4.w};
        int jrel = scount * 64 + hh * 32 + grp * 8;
        half8v e8 = *reinterpret_cast<const half8v*>(&Esh[jrel]);
        half8v f8 = *reinterpret_cast<const half8v*>(&Fsh[jrel]);
        Half2x4 E2 = __builtin_bit_cast(Half2x4, e8);
        Half2x4 F2 = __builtin_bit_cast(Half2x4, f8);
        Half2x4 P2;
#pragma unroll
        for (int ep = 0; ep < 4; ++ep) {
          half2v p2 = __builtin_elementwise_max(Ai2 * E2.v[ep], Bi2 * F2.v[ep]);
          unsigned pm = __builtin_bit_cast(unsigned, p2) & mka[ep];
          P2.v[ep] = __builtin_bit_cast(half2v, pm);
        }
        half8v a8 = __builtin_bit_cast(half8v, P2);
        int j8s = ((hh << 2) | grp) ^ (row_l & 7);
#pragma unroll
        for (int n = 0; n < NF; ++n) {
          short8 braw = *reinterpret_cast<const short8*>(&vb[(n * 16 + row_l) * 64 + j8s * 8]);
          half8v b8 = __builtin_bit_cast(half8v, braw);
          acc[n] = __builtin_amdgcn_mfma_f32_16x16x32_f16(a8, b8, acc[n], 0, 0, 0);
        }
        if (needL)
          accl = __builtin_amdgcn_mfma_f32_16x16x32_f16(a8, ones8, accl, 0, 0, 0);
      }
      ++scount;
    }
  }

  float* outp = pbuf + (size_t)jc * N_NODES * Ftot;
#pragma unroll
  for (int n = 0; n < NF; ++n) {
#pragma unroll
    for (int k = 0; k < 4; ++k) {
      int r = i0 + w * 16 + grp * 4 + k;
      outp[(size_t)r * Ftot + vcol + n * 16 + row_l] = acc[n][k];
    }
  }
  if (needL && row_l == 0) {
#pragma unroll
    for (int k = 0; k < 4; ++k)
      atomicAdd(&lsum[hN + i0 + w * 16 + grp * 4 + k], accl[k]);
  }
}

// ---------------------------------------------------------------- reduce + activation
__global__ __launch_bounds__(256) void act_kernel(float* __restrict__ dst,
                                                  const float* __restrict__ pbuf,
                                                  int njc, size_t pstride,
                                                  const float* __restrict__ lsum,
                                                  int n4, int ftotShift, int fpShift, int act) {
  int idx = blockIdx.x * blockDim.x + threadIdx.x;
  if (idx >= n4) return;
  int idx4 = idx * 4;
  int r = idx4 >> ftotShift;
  int c = idx4 & ((1 << ftotShift) - 1);
  int h = c >> fpShift;
  float li = 1.0f / lsum[h * N_NODES + r];
  float4 v = reinterpret_cast<const float4*>(pbuf)[idx];
  float vv[4] = {v.x, v.y, v.z, v.w};
  for (int q = 1; q < njc; ++q) {
    float4 u = *reinterpret_cast<const float4*>(pbuf + q * pstride + (size_t)idx4);
    vv[0] += u.x; vv[1] += u.y; vv[2] += u.z; vv[3] += u.w;
  }
#pragma unroll
  for (int e = 0; e < 4; ++e) {
    float x = vv[e] * li;
    x = x > 0.0f ? x : exp2f(x * LOG2E) - 1.0f;
    if (act == 1) x = 1.0f / (1.0f + exp2f(-x * LOG2E));
    vv[e] = x;
  }
  reinterpret_cast<float4*>(dst)[idx] = make_float4(vv[0], vv[1], vv[2], vv[3]);
}

// ---------------------------------------------------------------- host
extern "C" void kernel_launch(void* const* d_in, const int* in_sizes, int n_in,
                              void* d_out, int out_size, void* d_ws, size_t ws_size,
                              hipStream_t stream) {
  const float* x     = (const float*)d_in[0];
  const int*   adj   = (const int*)d_in[1];
  const float* W1    = (const float*)d_in[2];
  const float* a1    = (const float*)d_in[3];
  const float* Wo    = (const float*)d_in[4];
  const float* ao    = (const float*)d_in[5];
  const float* W2    = (const float*)d_in[6];
  const float* a2    = (const float*)d_in[7];
  const float* Wo2   = (const float*)d_in[8];
  const float* ao2   = (const float*)d_in[9];
  const float* lin_w = (const float*)d_in[10];
  const float* lin_b = (const float*)d_in[11];
  float* out = (float*)d_out;

  float* ws = (float*)d_ws;
  unsigned int* bits = (unsigned int*)ws;            // 1,179,648 u32
  float* bufA = ws + 1179648;                        // 6144*256
  float* bufB = bufA + 1572864;
  float* Bcat = bufB + 1572864;                      // 65536
  float* f1   = Bcat + 65536;                        // 24576
  float* f2   = f1 + 24576;                          // 24576 (contiguous with f1)
  float* lsum = f2 + 24576;                          // 24576
  float* gmaxb = lsum + 24576;                       // 16
  short* WhT  = (short*)(gmaxb + 16);                // 6144*256 fp16 bits
  short* BtW  = WhT + 1572864;                       // 384*256 bf16
  float* pbuf = (float*)(BtW + 98304);               // up to 4 x 6144*256 f32 partials

  const size_t PS256 = (size_t)6144 * 256;
  const size_t PS128 = (size_t)6144 * 128;

  dim3 b256(256);

  bitpack_kernel<<<N_NODES, b256, 0, stream>>>(adj, bits);

  // ================= layer 1 multi-head (H=4, Fp=64), elu concat
  repack_W_kernel<<<(4 * 256 * 64 + 255) / 256, b256, 0, stream>>>(W1, Bcat, 4, 256, 64);
  transpose_w_kernel<<<dim3(8, 8), b256, 0, stream>>>(Bcat, BtW, 256, 256);
  hipMemsetAsync(f1, 0, (size_t)2 * 24576 * 4, stream);
  gemm_attn_kernel<1><<<dim3(4, 96), b256, 0, stream>>>(x, BtW, a1, WhT, f1, f2, 256, 256, 64);
  gmax_kernel<<<4, b256, 0, stream>>>(f2, gmaxb);
  hipMemsetAsync(lsum, 0, (size_t)24576 * 4, stream);
  pv_stage_kernel<4, 4><<<dim3(1, 384, 4), b256, 0, stream>>>(f1, f2, gmaxb, bits, WhT, pbuf, lsum, 4, 64);
  act_kernel<<<dim3(1536), b256, 0, stream>>>(bufA, pbuf, 4, PS256, lsum, 6144 * 256 / 4, 8, 6, 0);

  // ================= out-attention 1 (H=1, Fp=256), sigmoid(elu)
  transpose_w_kernel<<<dim3(8, 8), b256, 0, stream>>>(Wo, BtW, 256, 256);
  hipMemsetAsync(f1, 0, (size_t)2 * 24576 * 4, stream);
  gemm_attn_kernel<1><<<dim3(4, 96), b256, 0, stream>>>(bufA, BtW, ao, WhT, f1, f2, 256, 256, 256);
  gmax_kernel<<<1, b256, 0, stream>>>(f2, gmaxb);
  hipMemsetAsync(lsum, 0, (size_t)24576 * 4, stream);
  pv_stage_kernel<8, 4><<<dim3(2, 384, 1), b256, 0, stream>>>(f1, f2, gmaxb, bits, WhT, pbuf, lsum, 1, 256);
  act_kernel<<<dim3(1536), b256, 0, stream>>>(bufB, pbuf, 4, PS256, lsum, 6144 * 256 / 4, 8, 8, 1);

  // ================= layer 2 multi-head (H=4, Fp=32), elu concat
  repack_W_kernel<<<(4 * 256 * 32 + 255) / 256, b256, 0, stream>>>(W2, Bcat, 4, 256, 32);
  transpose_w_kernel<<<dim3(8, 4), b256, 0, stream>>>(Bcat, BtW, 256, 128);
  hipMemsetAsync(f1, 0, (size_t)2 * 24576 * 4, stream);
  gemm_attn_kernel<2><<<dim3(2, 96), b256, 0, stream>>>(bufB, BtW, a2, WhT, f1, f2, 256, 128, 32);
  gmax_kernel<<<4, b256, 0, stream>>>(f2, gmaxb);
  hipMemsetAsync(lsum, 0, (size_t)24576 * 4, stream);
  pv_stage_kernel<2, 4><<<dim3(1, 384, 4), b256, 0, stream>>>(f1, f2, gmaxb, bits, WhT, pbuf, lsum, 4, 32);
  act_kernel<<<dim3(768), b256, 0, stream>>>(bufA, pbuf, 4, PS128, lsum, 6144 * 128 / 4, 7, 5, 0);

  // ================= out-attention 2 (H=1, Fp=128), sigmoid(elu)
  transpose_w_kernel<<<dim3(4, 4), b256, 0, stream>>>(Wo2, BtW, 128, 128);
  hipMemsetAsync(f1, 0, (size_t)2 * 24576 * 4, stream);
  gemm_attn_kernel<1><<<dim3(2, 96), b256, 0, stream>>>(bufA, BtW, ao2, WhT, f1, f2, 128, 128, 128);
  gmax_kernel<<<1, b256, 0, stream>>>(f2, gmaxb);
  hipMemsetAsync(lsum, 0, (size_t)24576 * 4, stream);
  pv_stage_kernel<8, 8><<<dim3(1, 768, 1), b256, 0, stream>>>(f1, f2, gmaxb, bits, WhT, pbuf, lsum, 1, 128);
  act_kernel<<<dim3(768), b256, 0, stream>>>(bufB, pbuf, 8, PS128, lsum, 6144 * 128 / 4, 7, 7, 1);

  // ================= final linear + relu
  transpose_w_kernel<<<dim3(4, 12), b256, 0, stream>>>(lin_w, BtW, 128, 379);
  gemm_mfma_kernel<<<dim3(6, 96), b256, 0, stream>>>(bufB, BtW, out, 128, 379, lin_b, 1);
}

// Round 19
// 301.273 us; speedup vs baseline: 11.2244x; 1.1001x over previous
//
#include <hip/hip_runtime.h>
#include <hip/hip_bf16.h>

#define N_NODES 6144
#define MASK_WORDS 192  // 6144/32
#define LOG2E 1.44269504088896f

using short8 = __attribute__((ext_vector_type(8))) short;
using s16x4  = __attribute__((ext_vector_type(4))) short;
using f32x4  = __attribute__((ext_vector_type(4))) float;
using half2v = __attribute__((ext_vector_type(2))) _Float16;
using half8v = __attribute__((ext_vector_type(8))) _Float16;
struct Half2x4 { half2v v[4]; };

// f32 -> bf16 bits, round-to-nearest-even
__device__ inline unsigned f2bf_u(float f) {
  unsigned u = __builtin_bit_cast(unsigned, f);
  u += 0x7fff + ((u >> 16) & 1);
  return u >> 16;
}
__device__ inline short f2bf(float f) { return (short)f2bf_u(f); }

// async global->LDS, 16B per lane; lds base must be wave-uniform
__device__ inline void glds16(const short* g, short* l) {
  __builtin_amdgcn_global_load_lds(
      (const __attribute__((address_space(1))) unsigned int*)g,
      (__attribute__((address_space(3))) unsigned int*)l, 16, 0, 0);
}

// ---------------------------------------------------------------- bitpack
__global__ __launch_bounds__(256) void bitpack_kernel(const int* __restrict__ adj,
                                                      unsigned int* __restrict__ bits) {
  int row = blockIdx.x;
  int wave = threadIdx.x >> 6, lane = threadIdx.x & 63;
  const int* p = adj + (long)row * N_NODES;
  for (int base = wave * 64; base < N_NODES; base += 256) {
    unsigned long long m = __ballot(p[base + lane] > 0);
    if (lane == 0) {
      bits[row * MASK_WORDS + (base >> 5)] = (unsigned int)m;
      bits[row * MASK_WORDS + (base >> 5) + 1] = (unsigned int)(m >> 32);
    }
  }
}

// ---------------------------------------------------------------- W repack
__global__ __launch_bounds__(256) void repack_W_kernel(const float* __restrict__ W,
                                                       float* __restrict__ B,
                                                       int H, int Fin, int Fp) {
  int idx = blockIdx.x * blockDim.x + threadIdx.x;
  int total = H * Fin * Fp;
  if (idx >= total) return;
  int h = idx / (Fin * Fp);
  int rem = idx - h * (Fin * Fp);
  int k = rem / Fp, c = rem - k * Fp;
  B[k * (H * Fp) + h * Fp + c] = W[idx];
}

// ---------------------------------------------------------------- weight transpose+cvt (bf16)
__global__ __launch_bounds__(256) void transpose_w_kernel(const float* __restrict__ B,
                                                          short* __restrict__ Bt,
                                                          int K, int Nc) {
  __shared__ short t[32][33];
  int k0 = blockIdx.x * 32, c0 = blockIdx.y * 32;
  int tx = threadIdx.x & 31, ty = threadIdx.x >> 5;
  for (int r = ty; r < 32; r += 8) {
    float v = (c0 + tx < Nc) ? B[(size_t)(k0 + r) * Nc + c0 + tx] : 0.0f;
    t[tx][r] = f2bf(v);
  }
  __syncthreads();
  for (int r = ty; r < 32; r += 8)
    Bt[(size_t)(c0 + r) * K + k0 + tx] = t[r][tx];
}

// ---------------------------------------------------------------- MFMA GEMM (final linear only)
__global__ __launch_bounds__(256) void gemm_mfma_kernel(const float* __restrict__ A,
                                                        const short* __restrict__ Bt,
                                                        float* __restrict__ C,
                                                        int K, int Nc,
                                                        const float* __restrict__ bias,
                                                        int act) {
  __shared__ short As[64][40];
  __shared__ short Bs[64][40];
  int m0 = blockIdx.y * 64, n0 = blockIdx.x * 64;
  int tid = threadIdx.x;
  int w = tid >> 6, l = tid & 63, row_l = l & 15, grp = l >> 4;

  f32x4 acc[4] = {f32x4{0,0,0,0}, f32x4{0,0,0,0}, f32x4{0,0,0,0}, f32x4{0,0,0,0}};

  for (int k0 = 0; k0 < K; k0 += 32) {
    __syncthreads();
#pragma unroll
    for (int s = 0; s < 2; ++s) {
      int idx = tid + s * 256;
      int r = idx >> 3, q = idx & 7;
      float4 v = *reinterpret_cast<const float4*>(&A[(size_t)(m0 + r) * K + k0 + q * 4]);
      s16x4 sv = {f2bf(v.x), f2bf(v.y), f2bf(v.z), f2bf(v.w)};
      *reinterpret_cast<s16x4*>(&As[r][q * 4]) = sv;
    }
    {
      int c = tid >> 2, kq = tid & 3;
      *reinterpret_cast<short8*>(&Bs[c][kq * 8]) =
          *reinterpret_cast<const short8*>(&Bt[(size_t)(n0 + c) * K + k0 + kq * 8]);
    }
    __syncthreads();
    short8 a = *reinterpret_cast<const short8*>(&As[w * 16 + row_l][grp * 8]);
#pragma unroll
    for (int n = 0; n < 4; ++n) {
      short8 b = *reinterpret_cast<const short8*>(&Bs[n * 16 + row_l][grp * 8]);
      acc[n] = __builtin_amdgcn_mfma_f32_16x16x32_bf16(a, b, acc[n], 0, 0, 0);
    }
  }

#pragma unroll
  for (int n = 0; n < 4; ++n) {
#pragma unroll
    for (int k = 0; k < 4; ++k) {
      int row = m0 + w * 16 + grp * 4 + k;
      int col = n0 + n * 16 + row_l;
      if (col < Nc) {
        float v = acc[n][k];
        if (bias) v += bias[col];
        if (act == 1) v = fmaxf(v, 0.0f);
        C[(size_t)row * Nc + col] = v;
      }
    }
  }
}

// ---------------------------------------------------------------- attention GEMM (fused epilogue)
// C = A @ Bt (bf16 MFMA). Epilogue: WhT fp16 transposed store + f1/f2 fused partials.
template<int HPB>
__global__ __launch_bounds__(256)
void gemm_attn_kernel(const float* __restrict__ A,
                      const short* __restrict__ Bt,
                      const float* __restrict__ avec,
                      short* __restrict__ WhT,
                      float* __restrict__ f1,
                      float* __restrict__ f2,
                      int K, int Nc, int Fp) {
  __shared__ short As[64][40];
  __shared__ short Bs[64][40];
  int m0 = blockIdx.y * 64, n0 = blockIdx.x * 64;
  int tid = threadIdx.x;
  int w = tid >> 6, l = tid & 63, row_l = l & 15, grp = l >> 4;

  f32x4 acc[4] = {f32x4{0,0,0,0}, f32x4{0,0,0,0}, f32x4{0,0,0,0}, f32x4{0,0,0,0}};

  for (int k0 = 0; k0 < K; k0 += 32) {
    __syncthreads();
#pragma unroll
    for (int s = 0; s < 2; ++s) {
      int idx = tid + s * 256;
      int r = idx >> 3, q = idx & 7;
      float4 v = *reinterpret_cast<const float4*>(&A[(size_t)(m0 + r) * K + k0 + q * 4]);
      s16x4 sv = {f2bf(v.x), f2bf(v.y), f2bf(v.z), f2bf(v.w)};
      *reinterpret_cast<s16x4*>(&As[r][q * 4]) = sv;
    }
    {
      int c = tid >> 2, kq = tid & 3;
      *reinterpret_cast<short8*>(&Bs[c][kq * 8]) =
          *reinterpret_cast<const short8*>(&Bt[(size_t)(n0 + c) * K + k0 + kq * 8]);
    }
    __syncthreads();
    short8 a = *reinterpret_cast<const short8*>(&As[w * 16 + row_l][grp * 8]);
#pragma unroll
    for (int n = 0; n < 4; ++n) {
      short8 b = *reinterpret_cast<const short8*>(&Bs[n * 16 + row_l][grp * 8]);
      acc[n] = __builtin_amdgcn_mfma_f32_16x16x32_bf16(a, b, acc[n], 0, 0, 0);
    }
  }

  int baserow = m0 + w * 16 + grp * 4;

#pragma unroll
  for (int n = 0; n < 4; ++n) {
    int col = n0 + n * 16 + row_l;
    _Float16 hv[4];
#pragma unroll
    for (int k = 0; k < 4; ++k) hv[k] = (_Float16)acc[n][k];
    *reinterpret_cast<s16x4*>(&WhT[(size_t)col * N_NODES + baserow]) =
        *reinterpret_cast<s16x4*>(hv);
  }

  constexpr int NPH = 4 / HPB;
#pragma unroll
  for (int half = 0; half < HPB; ++half) {
    int col0 = n0 + half * NPH * 16;
    int h = col0 / Fp;
    float t1[4] = {0, 0, 0, 0}, t2[4] = {0, 0, 0, 0};
#pragma unroll
    for (int nn = 0; nn < NPH; ++nn) {
      int n = half * NPH + nn;
      int col = n0 + n * 16 + row_l;
      int ci = col - h * Fp;
      float av1 = avec[h * 2 * Fp + ci] * LOG2E;
      float av2 = avec[h * 2 * Fp + Fp + ci] * LOG2E;
#pragma unroll
      for (int k = 0; k < 4; ++k) {
        t1[k] += acc[n][k] * av1;
        t2[k] += acc[n][k] * av2;
      }
    }
#pragma unroll
    for (int off = 1; off < 16; off <<= 1) {
#pragma unroll
      for (int k = 0; k < 4; ++k) {
        t1[k] += __shfl_xor(t1[k], off);
        t2[k] += __shfl_xor(t2[k], off);
      }
    }
    if (row_l == 0) {
#pragma unroll
      for (int k = 0; k < 4; ++k) {
        atomicAdd(&f1[h * N_NODES + baserow + k], t1[k]);
        atomicAdd(&f2[h * N_NODES + baserow + k], t2[k]);
      }
    }
  }
}

// ---------------------------------------------------------------- per-head global max of f2
__global__ __launch_bounds__(256) void gmax_kernel(const float* __restrict__ f2s,
                                                   float* __restrict__ gmax) {
  __shared__ float red[4];
  int h = blockIdx.x;
  int tid = threadIdx.x, lane = tid & 63, w = tid >> 6;
  const float* p = f2s + h * N_NODES;
  float m = -3.0e38f;
  for (int j = tid; j < N_NODES; j += 256) m = fmaxf(m, p[j]);
  for (int off = 32; off > 0; off >>= 1) m = fmaxf(m, __shfl_xor(m, off));
  if (lane == 0) red[w] = m;
  __syncthreads();
  if (tid == 0) gmax[h] = fmaxf(fmaxf(red[0], red[1]), fmaxf(red[2], red[3]));
}

// ---------------------------------------------------------------- attention PV (fp16 packed)
// 512 threads = 8 row-strip waves (128 rows/block): halves per-work V staging,
// prologue, and barrier count vs 64-row blocks. P = max(Ai'E'_j, Bi'F'_j) & LUT.
// 64-j stages, triple-buffered async glds (wave-uniform base), counted vmcnt.
template<int NF, int JC>
__global__ __launch_bounds__(512)
void pv_stage_kernel(const float* __restrict__ f1s,
                     const float* __restrict__ f2s,
                     const float* __restrict__ gmax,
                     const unsigned int* __restrict__ bits,
                     const short* __restrict__ WhT,
                     float* __restrict__ pbuf,
                     float* __restrict__ lsum,
                     int H, int Fp) {
  constexpr int CH = N_NODES / JC;
  constexpr int COLS = NF * 16;
  constexpr int NS = CH / 64;
  constexpr int CHUNKS = COLS * 8;           // 16B chunks per stage buffer
  constexpr int NITER = (CHUNKS + 511) / 512;
  constexpr int STEP = COLS * 64;            // shorts per buffer
  constexpr int NCH = CH / 384;
  static_assert(NCH * 384 == CH, "chunking");

  __shared__ _Float16 Esh[CH];
  __shared__ _Float16 Fsh[CH];
  __shared__ short Vt[3 * STEP];
  __shared__ uint4 Mlut[256];

  int h = blockIdx.z;
  int cb0 = blockIdx.x * COLS;
  int rb = blockIdx.y % 48;
  int jc = blockIdx.y / 48;
  int i0 = rb * 128;
  int hN = h * N_NODES, hFp = h * Fp;
  int Ftot = H * Fp;
  int tid = threadIdx.x;
  int w = tid >> 6, l = tid & 63;
  int row_l = l & 15, grp = l >> 4;

  int vcol = hFp + cb0;
  const short* Wbase = WhT + (size_t)vcol * N_NODES;
  float gm = gmax[h];

  // ---- prologue: E/F from f2, mask LUT
  {
    const float4* srcF2 = reinterpret_cast<const float4*>(f2s + hN + jc * CH);
    for (int idx = tid; idx < CH / 4; idx += 512) {
      float4 v = srcF2[idx];
      float vv[4] = {v.x, v.y, v.z, v.w};
      _Float16 e4[4], f4[4];
#pragma unroll
      for (int q = 0; q < 4; ++q) {
        float d = vv[q] - gm;
        e4[q] = (_Float16)exp2f(d);
        f4[q] = (_Float16)exp2f(0.2f * d);
      }
      *reinterpret_cast<s16x4*>(&Esh[idx * 4]) = *reinterpret_cast<s16x4*>(e4);
      *reinterpret_cast<s16x4*>(&Fsh[idx * 4]) = *reinterpret_cast<s16x4*>(f4);
    }
    if (tid < 256) {
      unsigned v = tid;
      unsigned w0 = ((v & 1u) ? 0xFFFFu : 0u) | ((v & 2u) ? 0xFFFF0000u : 0u);
      unsigned w1 = ((v & 4u) ? 0xFFFFu : 0u) | ((v & 8u) ? 0xFFFF0000u : 0u);
      unsigned w2 = ((v & 16u) ? 0xFFFFu : 0u) | ((v & 32u) ? 0xFFFF0000u : 0u);
      unsigned w3 = ((v & 64u) ? 0xFFFFu : 0u) | ((v & 128u) ? 0xFFFF0000u : 0u);
      Mlut[v] = make_uint4(w0, w1, w2, w3);
    }
  }
  __syncthreads();

  // pre-swizzled per-lane global offsets per glds iter
  size_t goff[NITER];
#pragma unroll
  for (int it = 0; it < NITER; ++it) {
    int idx = tid + it * 512;
    int c = idx >> 3, sl = idx & 7;
    int slp = sl ^ (c & 7);
    goff[it] = (size_t)(c < COLS ? c : 0) * N_NODES + jc * CH + slp * 8;
  }

  auto issue = [&](int bsel, int j0) {
#pragma unroll
    for (int it = 0; it < NITER; ++it) {
      if (it * 512 + w * 64 < CHUNKS) {
        const short* g = Wbase + goff[it] + j0;
        short* lp = &Vt[bsel * STEP + it * 4096 + w * 512];
        glds16(g, lp);
      }
    }
  };

  issue(0, 0);
  if (NS > 1) issue(1, 64);

  int i = i0 + w * 16 + row_l;
  float fi = f1s[hN + i];
  float mi = fmaxf(fi + gm, 0.2f * (fi + gm));
  _Float16 Aih = (_Float16)exp2f(fi + gm - mi);
  _Float16 Bih = (_Float16)exp2f(0.2f * (fi + gm) - mi);
  half2v Ai2 = {Aih, Aih};
  half2v Bi2 = {Bih, Bih};
  const unsigned int* mbase = bits + (size_t)i * MASK_WORDS + jc * (CH / 32);

  half8v ones8;
#pragma unroll
  for (int q = 0; q < 8; ++q) ones8[q] = (_Float16)1.0f;
  bool needL = (blockIdx.x == 0);

  f32x4 acc[NF];
#pragma unroll
  for (int n = 0; n < NF; ++n) acc[n] = f32x4{0, 0, 0, 0};
  f32x4 accl = f32x4{0, 0, 0, 0};

  int scount = 0;
#pragma unroll 1
  for (int ch = 0; ch < NCH; ++ch) {
    unsigned mw[12];
    {
      const uint4* mp = reinterpret_cast<const uint4*>(mbase + ch * 12);
#pragma unroll
      for (int q = 0; q < 3; ++q) {
        uint4 m = mp[q];
        mw[q * 4 + 0] = m.x; mw[q * 4 + 1] = m.y;
        mw[q * 4 + 2] = m.z; mw[q * 4 + 3] = m.w;
      }
    }
#pragma unroll 1
    for (int s2 = 0; s2 < 6; ++s2) {
      if (scount + 1 == NS) {
        asm volatile("s_waitcnt vmcnt(0)" ::: "memory");
      } else if (NITER == 1) {
        asm volatile("s_waitcnt vmcnt(1)" ::: "memory");
      } else {
        asm volatile("s_waitcnt vmcnt(2)" ::: "memory");
      }
      __builtin_amdgcn_sched_barrier(0);
      __builtin_amdgcn_s_barrier();
      if (scount + 2 < NS) issue((scount + 2) % 3, (scount + 2) * 64);
      const short* vb = &Vt[(scount % 3) * STEP];
#pragma unroll
      for (int hh = 0; hh < 2; ++hh) {
        unsigned wb = (mw[s2 * 2 + hh] >> (grp * 8)) & 0xffu;
        uint4 mq4 = Mlut[wb];
        unsigned mka[4] = {mq4.x, mq4.y, mq4.z, mq4.w};
        int jrel = scount * 64 + hh * 32 + grp * 8;
        half8v e8 = *reinterpret_cast<const half8v*>(&Esh[jrel]);
        half8v f8 = *reinterpret_cast<const half8v*>(&Fsh[jrel]);
        Half2x4 E2 = __builtin_bit_cast(Half2x4, e8);
        Half2x4 F2 = __builtin_bit_cast(Half2x4, f8);
        Half2x4 P2;
#pragma unroll
        for (int ep = 0; ep < 4; ++ep) {
          half2v p2 = __builtin_elementwise_max(Ai2 * E2.v[ep], Bi2 * F2.v[ep]);
          unsigned pm = __builtin_bit_cast(unsigned, p2) & mka[ep];
          P2.v[ep] = __builtin_bit_cast(half2v, pm);
        }
        half8v a8 = __builtin_bit_cast(half8v, P2);
        int j8s = ((hh << 2) | grp) ^ (row_l & 7);
#pragma unroll
        for (int n = 0; n < NF; ++n) {
          short8 braw = *reinterpret_cast<const short8*>(&vb[(n * 16 + row_l) * 64 + j8s * 8]);
          half8v b8 = __builtin_bit_cast(half8v, braw);
          acc[n] = __builtin_amdgcn_mfma_f32_16x16x32_f16(a8, b8, acc[n], 0, 0, 0);
        }
        if (needL)
          accl = __builtin_amdgcn_mfma_f32_16x16x32_f16(a8, ones8, accl, 0, 0, 0);
      }
      ++scount;
    }
  }

  float* outp = pbuf + (size_t)jc * N_NODES * Ftot;
#pragma unroll
  for (int n = 0; n < NF; ++n) {
#pragma unroll
    for (int k = 0; k < 4; ++k) {
      int r = i0 + w * 16 + grp * 4 + k;
      outp[(size_t)r * Ftot + vcol + n * 16 + row_l] = acc[n][k];
    }
  }
  if (needL && row_l == 0) {
#pragma unroll
    for (int k = 0; k < 4; ++k)
      atomicAdd(&lsum[hN + i0 + w * 16 + grp * 4 + k], accl[k]);
  }
}

// ---------------------------------------------------------------- reduce + activation
__global__ __launch_bounds__(256) void act_kernel(float* __restrict__ dst,
                                                  const float* __restrict__ pbuf,
                                                  int njc, size_t pstride,
                                                  const float* __restrict__ lsum,
                                                  int n4, int ftotShift, int fpShift, int act) {
  int idx = blockIdx.x * blockDim.x + threadIdx.x;
  if (idx >= n4) return;
  int idx4 = idx * 4;
  int r = idx4 >> ftotShift;
  int c = idx4 & ((1 << ftotShift) - 1);
  int h = c >> fpShift;
  float li = 1.0f / lsum[h * N_NODES + r];
  float4 v = reinterpret_cast<const float4*>(pbuf)[idx];
  float vv[4] = {v.x, v.y, v.z, v.w};
  for (int q = 1; q < njc; ++q) {
    float4 u = *reinterpret_cast<const float4*>(pbuf + q * pstride + (size_t)idx4);
    vv[0] += u.x; vv[1] += u.y; vv[2] += u.z; vv[3] += u.w;
  }
#pragma unroll
  for (int e = 0; e < 4; ++e) {
    float x = vv[e] * li;
    x = x > 0.0f ? x : exp2f(x * LOG2E) - 1.0f;
    if (act == 1) x = 1.0f / (1.0f + exp2f(-x * LOG2E));
    vv[e] = x;
  }
  reinterpret_cast<float4*>(dst)[idx] = make_float4(vv[0], vv[1], vv[2], vv[3]);
}

// ---------------------------------------------------------------- host
extern "C" void kernel_launch(void* const* d_in, const int* in_sizes, int n_in,
                              void* d_out, int out_size, void* d_ws, size_t ws_size,
                              hipStream_t stream) {
  const float* x     = (const float*)d_in[0];
  const int*   adj   = (const int*)d_in[1];
  const float* W1    = (const float*)d_in[2];
  const float* a1    = (const float*)d_in[3];
  const float* Wo    = (const float*)d_in[4];
  const float* ao    = (const float*)d_in[5];
  const float* W2    = (const float*)d_in[6];
  const float* a2    = (const float*)d_in[7];
  const float* Wo2   = (const float*)d_in[8];
  const float* ao2   = (const float*)d_in[9];
  const float* lin_w = (const float*)d_in[10];
  const float* lin_b = (const float*)d_in[11];
  float* out = (float*)d_out;

  float* ws = (float*)d_ws;
  unsigned int* bits = (unsigned int*)ws;            // 1,179,648 u32
  float* bufA = ws + 1179648;                        // 6144*256
  float* bufB = bufA + 1572864;
  float* Bcat = bufB + 1572864;                      // 65536
  float* f1   = Bcat + 65536;                        // 24576
  float* f2   = f1 + 24576;                          // 24576
  float* lsum = f2 + 24576;                          // 24576
  float* gmaxb = lsum + 24576;                       // 16
  short* WhT  = (short*)(gmaxb + 16);                // 6144*256 fp16 bits
  short* BtW  = WhT + 1572864;                       // 384*256 bf16
  float* pbuf = (float*)(BtW + 98304);               // partial buffers

  const size_t PS256 = (size_t)6144 * 256;
  const size_t PS128 = (size_t)6144 * 128;

  dim3 b256(256);
  dim3 b512(512);

  bitpack_kernel<<<N_NODES, b256, 0, stream>>>(adj, bits);

  // ================= layer 1 multi-head (H=4, Fp=64), elu concat
  repack_W_kernel<<<(4 * 256 * 64 + 255) / 256, b256, 0, stream>>>(W1, Bcat, 4, 256, 64);
  transpose_w_kernel<<<dim3(8, 8), b256, 0, stream>>>(Bcat, BtW, 256, 256);
  hipMemsetAsync(f1, 0, (size_t)2 * 24576 * 4, stream);
  gemm_attn_kernel<1><<<dim3(4, 96), b256, 0, stream>>>(x, BtW, a1, WhT, f1, f2, 256, 256, 64);
  gmax_kernel<<<4, b256, 0, stream>>>(f2, gmaxb);
  hipMemsetAsync(lsum, 0, (size_t)24576 * 4, stream);
  pv_stage_kernel<4, 4><<<dim3(1, 192, 4), b512, 0, stream>>>(f1, f2, gmaxb, bits, WhT, pbuf, lsum, 4, 64);
  act_kernel<<<dim3(1536), b256, 0, stream>>>(bufA, pbuf, 4, PS256, lsum, 6144 * 256 / 4, 8, 6, 0);

  // ================= out-attention 1 (H=1, Fp=256), sigmoid(elu)
  transpose_w_kernel<<<dim3(8, 8), b256, 0, stream>>>(Wo, BtW, 256, 256);
  hipMemsetAsync(f1, 0, (size_t)2 * 24576 * 4, stream);
  gemm_attn_kernel<1><<<dim3(4, 96), b256, 0, stream>>>(bufA, BtW, ao, WhT, f1, f2, 256, 256, 256);
  gmax_kernel<<<1, b256, 0, stream>>>(f2, gmaxb);
  hipMemsetAsync(lsum, 0, (size_t)24576 * 4, stream);
  pv_stage_kernel<8, 8><<<dim3(2, 384, 1), b512, 0, stream>>>(f1, f2, gmaxb, bits, WhT, pbuf, lsum, 1, 256);
  act_kernel<<<dim3(1536), b256, 0, stream>>>(bufB, pbuf, 8, PS256, lsum, 6144 * 256 / 4, 8, 8, 1);

  // ================= layer 2 multi-head (H=4, Fp=32), elu concat
  repack_W_kernel<<<(4 * 256 * 32 + 255) / 256, b256, 0, stream>>>(W2, Bcat, 4, 256, 32);
  transpose_w_kernel<<<dim3(8, 4), b256, 0, stream>>>(Bcat, BtW, 256, 128);
  hipMemsetAsync(f1, 0, (size_t)2 * 24576 * 4, stream);
  gemm_attn_kernel<2><<<dim3(2, 96), b256, 0, stream>>>(bufB, BtW, a2, WhT, f1, f2, 256, 128, 32);
  gmax_kernel<<<4, b256, 0, stream>>>(f2, gmaxb);
  hipMemsetAsync(lsum, 0, (size_t)24576 * 4, stream);
  pv_stage_kernel<2, 4><<<dim3(1, 192, 4), b512, 0, stream>>>(f1, f2, gmaxb, bits, WhT, pbuf, lsum, 4, 32);
  act_kernel<<<dim3(768), b256, 0, stream>>>(bufA, pbuf, 4, PS128, lsum, 6144 * 128 / 4, 7, 5, 0);

  // ================= out-attention 2 (H=1, Fp=128), sigmoid(elu)
  transpose_w_kernel<<<dim3(4, 4), b256, 0, stream>>>(Wo2, BtW, 128, 128);
  hipMemsetAsync(f1, 0, (size_t)2 * 24576 * 4, stream);
  gemm_attn_kernel<1><<<dim3(2, 96), b256, 0, stream>>>(bufA, BtW, ao2, WhT, f1, f2, 128, 128, 128);
  gmax_kernel<<<1, b256, 0, stream>>>(f2, gmaxb);
  hipMemsetAsync(lsum, 0, (size_t)24576 * 4, stream);
  pv_stage_kernel<8, 16><<<dim3(1, 768, 1), b512, 0, stream>>>(f1, f2, gmaxb, bits, WhT, pbuf, lsum, 1, 128);
  act_kernel<<<dim3(768), b256, 0, stream>>>(bufB, pbuf, 16, PS128, lsum, 6144 * 128 / 4, 7, 7, 1);

  // ================= final linear + relu
  transpose_w_kernel<<<dim3(4, 12), b256, 0, stream>>>(lin_w, BtW, 128, 379);
  gemm_mfma_kernel<<<dim3(6, 96), b256, 0, stream>>>(bufB, BtW, out, 128, 379, lin_b, 1);
}